// Round 4
// baseline (8454.728 us; speedup 1.0000x reference)
//
#include <hip/hip_runtime.h>
#include <math.h>

// ---------------------------------------------------------------------------
// PAE pipeline on MI355X. Round 4: fp32 inputs AND fp32 outputs.
// (Rounds 2/3 bit-identical absmax 17.36 == our f-values packed as bf16 pairs
// landing inside Output 0's fp32 region -> output buffer is float32, per the
// harness contract: "the reference's OUTPUT dtype ... else float*".)
//   B=16, IN_CH=72, T=121, FULL=240, INTER=24, EMB=8, PAD=60, L_PADDED=360
//   3840 windows, w = b*240 + n, win[c,t] = x[b,c,(n+t-60)%240]
// ---------------------------------------------------------------------------

#define INCH   72
#define TLEN   121
#define FULL   240
#define INTER  24
#define EMB    8
#define LP     360
#define NWIN   3840

// ---------------------------------------------------------------------------
// Kernel 1: per-window encoder. One block per window (3840 blocks, 256 thr).
// conv1 (72ch x 121 taps, zero-padded) -> LN(ddof=1, /(std+eps)) -> tanh ->
// conv2 -> latent -> DFT power stats (f,a,b) + fc (p).
// winp/hp zero-padded in LDS: row stride 244, valid data at [60,181),
// conv reads index i+k in [0,243] -- no bounds checks in inner loops.
// LDS ~99 KB -> 1 block/CU (correctness round; occupancy addressed later).
// ---------------------------------------------------------------------------
__global__ __launch_bounds__(256) void k_enc(
    const float* __restrict__ x,  const float* __restrict__ w1, const float* __restrict__ b1,
    const float* __restrict__ lna, const float* __restrict__ lnb,
    const float* __restrict__ w2, const float* __restrict__ b2,
    const float* __restrict__ fcw, const float* __restrict__ fcb,
    float* __restrict__ pP, float* __restrict__ pF, float* __restrict__ pA, float* __restrict__ pB,
    float* __restrict__ oLat, float* __restrict__ oP, float* __restrict__ oF,
    float* __restrict__ oA, float* __restrict__ oB)
{
    const int w   = blockIdx.x;
    const int b   = w / FULL, n = w - b * FULL;
    const int tid = threadIdx.x;

    __shared__ float winp[INCH * 244];   // zero-padded window (70.3 KB)
    __shared__ float hp[INTER * 244];    // zero-padded h (23.4 KB)
    __shared__ float lat[EMB * 122];     // latent (3.9 KB)
    __shared__ float2 tw[121];           // cos/sin(2*pi*m/121)
    __shared__ float lnM[INTER], lnI[INTER];
    __shared__ float S0[8], S1[8], vv[16], bm[8];

    // --- stage window (zero outside t in [0,121)), zero hp, trig table ---
    for (int idx = tid; idx < INCH * 244; idx += 256) {
        int c = idx / 244, jj = idx - c * 244;
        int j = jj - 60;                       // window-local t
        float v = 0.0f;
        if (j >= 0 && j < TLEN) {
            int q = n + j - 60;                // circular index into x
            q += (q < 0) ? FULL : 0;
            q -= (q >= FULL) ? FULL : 0;
            v = x[(b * INCH + c) * FULL + q];
        }
        winp[idx] = v;
    }
    for (int idx = tid; idx < INTER * 244; idx += 256) hp[idx] = 0.0f;
    if (tid < TLEN) {
        float s, c;
        sincosf(6.2831853071795864f * (float)tid / 121.0f, &s, &c);
        tw[tid] = make_float2(c, s);
    }
    if (tid < 8) { S0[tid] = 0.0f; S1[tid] = 0.0f; }
    __syncthreads();

    // --- conv1: thread = (it,ot); o = ot*3+oo (24 outs), i = 4*ite+ii ---
    const int it = tid & 31, ot = tid >> 5;
    const int ite = (it < 31) ? it : 30;       // it==31 out of range; clamp (masked)
    float acc[3][4];
#pragma unroll
    for (int a_ = 0; a_ < 3; ++a_)
#pragma unroll
        for (int b_ = 0; b_ < 4; ++b_) acc[a_][b_] = 0.0f;

    for (int c = 0; c < INCH; ++c) {
        const float* wr0 = w1 + ((ot * 3 + 0) * INCH + c) * TLEN;
        const float* wr1 = w1 + ((ot * 3 + 1) * INCH + c) * TLEN;
        const float* wr2 = w1 + ((ot * 3 + 2) * INCH + c) * TLEN;
        const float* xr  = &winp[c * 244 + 4 * ite];
        for (int k = 0; k < TLEN; ++k) {
            float w0 = wr0[k], w1v = wr1[k], w2v = wr2[k];
            float x0 = xr[k], x1 = xr[k + 1], x2 = xr[k + 2], x3 = xr[k + 3];
            acc[0][0] += w0 * x0;  acc[0][1] += w0 * x1;  acc[0][2] += w0 * x2;  acc[0][3] += w0 * x3;
            acc[1][0] += w1v * x0; acc[1][1] += w1v * x1; acc[1][2] += w1v * x2; acc[1][3] += w1v * x3;
            acc[2][0] += w2v * x0; acc[2][1] += w2v * x1; acc[2][2] += w2v * x2; acc[2][3] += w2v * x3;
        }
    }
#pragma unroll
    for (int oo = 0; oo < 3; ++oo) {
        int o = ot * 3 + oo;
        float bias = b1[o];
#pragma unroll
        for (int ii = 0; ii < 4; ++ii) {
            int i = 4 * ite + ii;
            if (it < 31 && i < TLEN) hp[o * 244 + 60 + i] = acc[oo][ii] + bias;
        }
    }
    __syncthreads();

    // --- LayerNorm over t (ddof=1), /(std+1e-5), *alpha + beta, tanh ---
    if (tid < INTER) {
        float s = 0.0f, s2 = 0.0f;
        for (int i = 0; i < TLEN; ++i) { float v = hp[tid * 244 + 60 + i]; s += v; s2 += v * v; }
        float mean = s * (1.0f / 121.0f);
        float var  = fmaxf((s2 - s * mean) * (1.0f / 120.0f), 0.0f);   // ddof=1
        lnM[tid] = mean;
        lnI[tid] = 1.0f / (sqrtf(var) + 1e-5f);                        // (std + eps)
    }
    __syncthreads();
    for (int idx = tid; idx < INTER * TLEN; idx += 256) {
        int o = idx / TLEN, i = idx - o * TLEN;
        float v = hp[o * 244 + 60 + i];
        v = (v - lnM[o]) * lnI[o] * lna[i] + lnb[i];
        hp[o * 244 + 60 + i] = tanhf(v);
    }
    __syncthreads();

    // --- conv2: e = ot (8 outs), i = 4*ite+ii ---
    {
        const int e = ot;
        float a2[4] = {0.0f, 0.0f, 0.0f, 0.0f};
        for (int c = 0; c < INTER; ++c) {
            const float* wr = w2 + (e * INTER + c) * TLEN;
            const float* hr = &hp[c * 244 + 4 * ite];
            for (int k = 0; k < TLEN; ++k) {
                float wv = wr[k];
                a2[0] += wv * hr[k];     a2[1] += wv * hr[k + 1];
                a2[2] += wv * hr[k + 2]; a2[3] += wv * hr[k + 3];
            }
        }
        float bias = b2[e];
#pragma unroll
        for (int ii = 0; ii < 4; ++ii) {
            int i = 4 * ite + ii;
            if (it < 31 && i < TLEN) lat[e * 122 + i] = a2[ii] + bias;
        }
    }
    __syncthreads();

    // --- DFT bins 1..60: power sums for f and a ---
    for (int q = tid; q < 480; q += 256) {
        int e_ = q / 60, k = q - e_ * 60 + 1;
        float re = 0.0f, im = 0.0f;
        int m = 0;
        for (int t = 0; t < TLEN; ++t) {
            float v = lat[e_ * 122 + t];
            float2 cs = tw[m];
            re += v * cs.x;
            im -= v * cs.y;
            m += k; m -= (m >= 121) ? 121 : 0;   // m = k*t mod 121
        }
        float pw = re * re + im * im;
        atomicAdd(&S0[e_], pw);
        atomicAdd(&S1[e_], pw * (0.5f * (float)k));  // FREQS[k-1] = k/2 exactly
    }
    // --- fc: v[e][kk] = sum_t lat * fc_w + fc_b ---
    if (tid < 16) {
        int e_ = tid >> 1, kk = tid & 1;
        float accv = fcb[e_ * 2 + kk];
        const float* fr = fcw + (e_ * 2 + kk) * TLEN;
        for (int t = 0; t < TLEN; ++t) accv += lat[e_ * 122 + t] * fr[t];
        vv[tid] = accv;
    }
    // --- b = mean(latent) ---
    if (tid >= 32 && tid < 40) {
        int e_ = tid - 32;
        float s = 0.0f;
        for (int t = 0; t < TLEN; ++t) s += lat[e_ * 122 + t];
        bm[e_] = s * (1.0f / 121.0f);
    }
    __syncthreads();

    if (tid < 8) {
        int e_ = tid;
        float fv = S1[e_] / S0[e_];
        float av = 2.0f * sqrtf(S0[e_]) * (1.0f / 121.0f);
        float pv = atan2f(vv[2 * e_ + 1], vv[2 * e_]) * 0.15915494309189535f; // /(2*pi)
        float bv = bm[e_];
        int gi = w * 8 + e_;
        pP[gi] = pv; pF[gi] = fv; pA[gi] = av; pB[gi] = bv;
        if (n == 0) {
            oP[b * 8 + e_] = pv;
            oF[b * 8 + e_] = fv;
            oA[b * 8 + e_] = av;
            oB[b * 8 + e_] = bv;
        }
    }
    if (n == 0) {
        for (int idx = tid; idx < EMB * TLEN; idx += 256) {
            int e_ = idx / TLEN, i = idx - e_ * TLEN;
            oLat[(b * EMB + e_) * TLEN + i] = lat[e_ * 122 + i];
        }
    }
}

// ---------------------------------------------------------------------------
// Kernel 2: sinusoid resynthesis + overlap-add, gather form (no atomics).
// signal[b,e,u] = (1/weights[u]) * sum_{n=max(0,u-120)}^{min(239,u)}
//                 a*sin(2pi*(f*ARGS[u-n]+p)) + b ; weights = overlap count
// ---------------------------------------------------------------------------
__global__ __launch_bounds__(256) void k_signal(
    const float* __restrict__ pP, const float* __restrict__ pF,
    const float* __restrict__ pA, const float* __restrict__ pB,
    float* __restrict__ sig, float* __restrict__ oSig)
{
    const int blk = blockIdx.x;
    const int b = blk >> 3, e = blk & 7;
    const int tid = threadIdx.x;
    __shared__ float sp[FULL], sf[FULL], sa[FULL], sb[FULL];
    for (int nn = tid; nn < FULL; nn += 256) {
        int gi = (b * FULL + nn) * 8 + e;
        sp[nn] = pP[gi]; sf[nn] = pF[gi]; sa[nn] = pA[gi]; sb[nn] = pB[gi];
    }
    __syncthreads();
    for (int u = tid; u < LP; u += 256) {
        int nlo = (u - 120 > 0) ? (u - 120) : 0;
        int nhi = (u < 239) ? u : 239;
        float s = 0.0f;
        for (int nn = nlo; nn <= nhi; ++nn) {
            float tt = (float)(u - nn);
            float z = sf[nn] * (tt * (1.0f / 60.0f) - 1.0f) + sp[nn]; // revolutions
            z -= floorf(z);                                          // periodic reduction
            s += sa[nn] * sinf(6.2831853071795864f * z) + sb[nn];
        }
        float wgt = (u < TLEN) ? (float)(u + 1) : ((u > 239) ? (float)(LP - u) : 121.0f);
        float val = s / wgt;
        sig[(b * EMB + e) * LP + u] = val;
        if (u < TLEN) oSig[(b * EMB + e) * TLEN + u] = val;
    }
}

// ---------------------------------------------------------------------------
// Kernel 3: decoder conv1 (yc -> d) + BatchNorm partial sums (atomics).
// ycpad[c][m] = sig[b,c,m] for m in [60,300) (== yc zero-padded), else 0.
// d[o,i] = bias + sum_{c,k} w[o,c,k]*ycpad[c][i+k]   (i+k in [0,360) < 364)
// ---------------------------------------------------------------------------
__global__ __launch_bounds__(256) void k_dec1(
    const float* __restrict__ sig, const float* __restrict__ dw1, const float* __restrict__ db1,
    float* __restrict__ dbuf, float* __restrict__ bns)
{
    const int b = blockIdx.x / 3, og = blockIdx.x % 3;
    const int tid = threadIdx.x;
    __shared__ float ycp[EMB * 364];
    for (int idx = tid; idx < EMB * 364; idx += 256) {
        int c = idx / 364, q = idx - c * 364;
        float v = 0.0f;
        if (q >= 60 && q < 300) v = sig[(b * EMB + c) * LP + q];
        ycp[idx] = v;
    }
    __syncthreads();
    const int it = tid & 31, ol = tid >> 5;
    const int o = og * 8 + ol;
    const float bias = db1[o];
    float s = 0.0f, s2 = 0.0f;
    for (int g = 0; g < 8; ++g) {
        int i = it + 32 * g;
        if (i < FULL) {
            float accv = bias;
            for (int c = 0; c < EMB; ++c) {
                const float* wr = dw1 + (o * EMB + c) * TLEN;
                const float* yr = &ycp[c * 364 + i];
                for (int k = 0; k < TLEN; ++k) accv += wr[k] * yr[k];
            }
            dbuf[(b * INTER + o) * FULL + i] = accv;
            s += accv; s2 += accv * accv;
        }
    }
    for (int d = 16; d > 0; d >>= 1) { s += __shfl_down(s, d, 32); s2 += __shfl_down(s2, d, 32); }
    if (it == 0) { atomicAdd(&bns[o], s); atomicAdd(&bns[24 + o], s2); }
}

// ---------------------------------------------------------------------------
// Kernel 4: BatchNorm apply (biased var, 1/sqrt(v+eps)) + tanh + dec conv2.
// ---------------------------------------------------------------------------
__global__ __launch_bounds__(256) void k_dec2(
    const float* __restrict__ dbuf, const float* __restrict__ bns,
    const float* __restrict__ gma, const float* __restrict__ bta,
    const float* __restrict__ dw2, const float* __restrict__ db2,
    float* __restrict__ oY, float* __restrict__ oYp)
{
    const int b = blockIdx.x / 9, ocg = blockIdx.x % 9;
    const int tid = threadIdx.x;
    __shared__ float ddp[INTER * 364];
    __shared__ float scl[INTER], sft[INTER];
    if (tid < INTER) {
        float m  = bns[tid] * (1.0f / 3840.0f);
        float v  = bns[24 + tid] * (1.0f / 3840.0f) - m * m;   // biased var
        float rs = rsqrtf(fmaxf(v, 0.0f) + 1e-5f);
        float g  = gma[tid];
        scl[tid] = rs * g;
        sft[tid] = bta[tid] - m * rs * g;
    }
    __syncthreads();
    for (int idx = tid; idx < INTER * 364; idx += 256) {
        int c = idx / 364, q = idx - c * 364;
        float v = 0.0f;
        if (q >= 60 && q < 300) {
            float dv = dbuf[(b * INTER + c) * FULL + (q - 60)];
            v = tanhf(dv * scl[c] + sft[c]);
        }
        ddp[idx] = v;
    }
    __syncthreads();
    const int it = tid & 31, ol = tid >> 5;
    const int oc = ocg * 8 + ol;
    const float bias = db2[oc];
    for (int g = 0; g < 8; ++g) {
        int i = it + 32 * g;
        if (i < FULL) {
            float accv = bias;
            for (int c = 0; c < INTER; ++c) {
                const float* wr = dw2 + (oc * INTER + c) * TLEN;
                const float* dr = &ddp[c * 364 + i];
                for (int k = 0; k < TLEN; ++k) accv += wr[k] * dr[k];
            }
            oY[(b * INCH + oc) * FULL + i] = accv;
            if (i < TLEN) oYp[(b * INCH + oc) * TLEN + i] = accv;
        }
    }
}

// ---------------------------------------------------------------------------
extern "C" void kernel_launch(void* const* d_in, const int* in_sizes, int n_in,
                              void* d_out, int out_size, void* d_ws, size_t ws_size,
                              hipStream_t stream)
{
    const float* x   = (const float*)d_in[0];
    const float* w1  = (const float*)d_in[1];
    const float* b1  = (const float*)d_in[2];
    const float* lna = (const float*)d_in[3];
    const float* lnb = (const float*)d_in[4];
    const float* w2  = (const float*)d_in[5];
    const float* b2  = (const float*)d_in[6];
    const float* fcw = (const float*)d_in[7];
    const float* fcb = (const float*)d_in[8];
    const float* dw1 = (const float*)d_in[9];
    const float* db1 = (const float*)d_in[10];
    const float* gma = (const float*)d_in[11];
    const float* bta = (const float*)d_in[12];
    const float* dw2 = (const float*)d_in[13];
    const float* db2 = (const float*)d_in[14];

    // Output layout (flat fp32, reference return order):
    float* out  = (float*)d_out;
    float* oY   = out;                 // [16][72][240] = 276480
    float* oLat = out + 276480;        // [16][8][121]  = 15488
    float* oSig = out + 291968;        // [16][8][121]  = 15488
    float* oP   = out + 307456;        // [16][8][1]    = 128
    float* oF   = out + 307584;
    float* oA   = out + 307712;
    float* oB   = out + 307840;
    float* oYp  = out + 307968;        // [16][72][121] = 139392  (end 447360)

    // Workspace (fp32, 676 KB total):
    //   region A floats [0,122880): pP/pF/pA/pB during k_enc+k_signal,
    //   then dbuf (92160) overlaid during k_dec1/k_dec2 (temporally disjoint).
    float* ws   = (float*)d_ws;
    float* pP   = ws;                 // 30720
    float* pF   = pP + 30720;
    float* pA   = pF + 30720;
    float* pB   = pA + 30720;
    float* dbuf = ws;                 // overlay on region A (92160 <= 122880)
    float* sig  = ws + 122880;        // 46080
    float* bns  = sig + 46080;        // 48, memset each call

    hipMemsetAsync(bns, 0, 48 * sizeof(float), stream);
    k_enc<<<NWIN, 256, 0, stream>>>(x, w1, b1, lna, lnb, w2, b2, fcw, fcb,
                                    pP, pF, pA, pB, oLat, oP, oF, oA, oB);
    k_signal<<<128, 256, 0, stream>>>(pP, pF, pA, pB, sig, oSig);
    k_dec1<<<48, 256, 0, stream>>>(sig, dw1, db1, dbuf, bns);
    k_dec2<<<144, 256, 0, stream>>>(dbuf, bns, gma, bta, dw2, db2, oY, oYp);
}

// Round 5
// 2530.563 us; speedup vs baseline: 3.3410x; 3.3410x over previous
//
#include <hip/hip_runtime.h>
#include <math.h>

// ---------------------------------------------------------------------------
// PAE pipeline on MI355X. Round 5: conv1/conv2 of the encoder on MFMA bf16.
//   fp32 in / fp32 out. 3840 window-blocks; per block:
//   winp (bf16, zero-padded ypad rows) -> MFMA conv1 (A=pre-swizzled weights
//   from ws, staged per channel; B=window via per-lane u16 gathers) -> LN ->
//   tanh -> bf16 hpad -> MFMA conv2 -> fp32 latent -> DFT/fc/b epilogues.
//   k_signal / k_dec1 / k_dec2 unchanged from round 4.
// ---------------------------------------------------------------------------

#define INCH   72
#define TLEN   121
#define FULL   240
#define INTER  24
#define EMB    8
#define LP     360
#define NWIN   3840

typedef __attribute__((ext_vector_type(8)))  short s16x8;
typedef __attribute__((ext_vector_type(16))) float f32x16;

// fp32 -> bf16 (RNE) as raw ushort
__device__ __forceinline__ unsigned short f2bf(float f) {
    unsigned u = __float_as_uint(f);
    unsigned r = ((u >> 16) & 1u) + 0x7FFFu;
    return (unsigned short)((u + r) >> 16);
}

// ---------------------------------------------------------------------------
// Weight pre-swizzle kernels (once per launch; shared by all 3840 blocks).
// w1s[c][kc][lane][j] = w1[o=lane&31][c][kk=kc*16+(lane>>5)*8+j], 0-padded.
// ---------------------------------------------------------------------------
__global__ __launch_bounds__(256) void k_prep_w1(const float* __restrict__ w1,
                                                 short* __restrict__ w1s) {
    int idx = blockIdx.x * 256 + threadIdx.x;           // < 72*8*64*8 = 294912
    int j = idx & 7, ln = (idx >> 3) & 63, kc = (idx >> 9) & 7, c = idx >> 12;
    int o = ln & 31, kk = kc * 16 + (ln >> 5) * 8 + j;
    float v = (o < INTER && kk < TLEN) ? w1[(o * INCH + c) * TLEN + kk] : 0.0f;
    w1s[idx] = (short)f2bf(v);
}
__global__ __launch_bounds__(256) void k_prep_w2(const float* __restrict__ w2,
                                                 short* __restrict__ w2s) {
    int idx = blockIdx.x * 256 + threadIdx.x;           // < 24*8*64*8 = 98304
    int j = idx & 7, ln = (idx >> 3) & 63, kc = (idx >> 9) & 7, c = idx >> 12;
    int o = ln & 31, kk = kc * 16 + (ln >> 5) * 8 + j;
    float v = (o < EMB && kk < TLEN) ? w2[(o * INTER + c) * TLEN + kk] : 0.0f;
    w2s[idx] = (short)f2bf(v);
}

// ---------------------------------------------------------------------------
// Kernel 1: per-window encoder, MFMA version. 3840 blocks x 256 threads.
// LDS ~71 KB -> 2 blocks/CU.
// ---------------------------------------------------------------------------
__global__ __launch_bounds__(256) void k_enc(
    const float* __restrict__ x,  const short* __restrict__ w1s, const float* __restrict__ b1,
    const float* __restrict__ lna, const float* __restrict__ lnb,
    const short* __restrict__ w2s, const float* __restrict__ b2,
    const float* __restrict__ fcw, const float* __restrict__ fcb,
    float* __restrict__ pP, float* __restrict__ pF, float* __restrict__ pA, float* __restrict__ pB,
    float* __restrict__ oLat, float* __restrict__ oP, float* __restrict__ oF,
    float* __restrict__ oA, float* __restrict__ oB)
{
    const int w   = blockIdx.x;
    const int b   = w / FULL, n = w - b * FULL;
    const int tid = threadIdx.x;
    const int lane = tid & 63, wid = tid >> 6;

    __shared__ __align__(16) short winp[INCH * 256];   // 36864 B (ypad rows)
    __shared__ __align__(16) short aw[2][4096];        // 16384 B (A dbuf)
    __shared__ __align__(16) short hpad[INTER * 256];  // 12288 B
    __shared__ float lat[EMB * 122];                   // 3904 B
    __shared__ float2 tw[121];
    __shared__ float lnM[INTER], lnI[INTER];
    __shared__ float S0[8], S1[8], vv[16], bm[8];
    float* hp = (float*)winp;                          // overlay after conv1

    // --- stage zero-padded window (bf16), zero hpad, trig, S init ---
    for (int idx = tid; idx < INCH * 256; idx += 256) {
        int c = idx >> 8, s = idx & 255;
        unsigned short v = 0;
        if (s >= 60 && s < 181) {
            int q = n + s - 120;
            q += (q < 0) ? FULL : 0;
            q -= (q >= FULL) ? FULL : 0;
            v = f2bf(x[(b * INCH + c) * FULL + q]);
        }
        winp[idx] = (short)v;
    }
    for (int idx = tid; idx < INTER * 256; idx += 256) hpad[idx] = 0;
    if (tid < TLEN) {
        float s, c;
        sincosf(6.2831853071795864f * (float)tid / 121.0f, &s, &c);
        tw[tid] = make_float2(c, s);
    }
    if (tid < 8) { S0[tid] = 0.0f; S1[tid] = 0.0f; }

    // prefetch A chunk for channel 0
    uint4 p0 = *(const uint4*)(w1s + tid * 16);
    uint4 p1 = *(const uint4*)(w1s + tid * 16 + 8);
    __syncthreads();

    const int i0 = wid * 32;            // this wave's i-tile base
    const int nn = lane & 31, hh = lane >> 5;

    // --- conv1 MFMA: D[o=32, i=128] over K = 72ch x 128 ---
    f32x16 acc;
#pragma unroll
    for (int r = 0; r < 16; ++r) acc[r] = 0.0f;

    for (int c = 0; c < INCH; ++c) {
        const int buf = c & 1;
        *(uint4*)(&aw[buf][tid * 16])     = p0;
        *(uint4*)(&aw[buf][tid * 16 + 8]) = p1;
        if (c < INCH - 1) {
            p0 = *(const uint4*)(w1s + (c + 1) * 4096 + tid * 16);
            p1 = *(const uint4*)(w1s + (c + 1) * 4096 + tid * 16 + 8);
        }
        __syncthreads();
        const short* bbase = winp + c * 256 + i0 + nn + hh * 8;
        const short* abase = &aw[buf][lane * 8];
#pragma unroll
        for (int kc = 0; kc < 8; ++kc) {
            s16x8 af = *(const s16x8*)(abase + kc * 512);
            s16x8 bf;
#pragma unroll
            for (int j = 0; j < 8; ++j) bf[j] = bbase[kc * 16 + j];
            acc = __builtin_amdgcn_mfma_f32_32x32x16_bf16(af, bf, acc, 0, 0, 0);
        }
    }
    __syncthreads();   // all conv1 MFMA done; winp region now reusable as hp

    // --- conv1 epilogue: C frags -> hp[o*122+i] (+bias) ---
    {
        const int i = i0 + nn;
#pragma unroll
        for (int r = 0; r < 16; ++r) {
            int o = (r & 3) + 8 * (r >> 2) + 4 * hh;
            if (o < INTER && i < TLEN) hp[o * 122 + i] = acc[r] + b1[o];
        }
    }
    __syncthreads();

    // --- LayerNorm (ddof=1, /(std+1e-5)) stats ---
    if (tid < INTER) {
        float s = 0.0f, s2 = 0.0f;
        for (int i = 0; i < TLEN; ++i) { float v = hp[tid * 122 + i]; s += v; s2 += v * v; }
        float mean = s * (1.0f / 121.0f);
        float var  = fmaxf((s2 - s * mean) * (1.0f / 120.0f), 0.0f);
        lnM[tid] = mean;
        lnI[tid] = 1.0f / (sqrtf(var) + 1e-5f);
    }
    __syncthreads();
    for (int idx = tid; idx < INTER * TLEN; idx += 256) {
        int o = idx / TLEN, i = idx - o * TLEN;
        float v = (hp[o * 122 + i] - lnM[o]) * lnI[o] * lna[i] + lnb[i];
        hpad[o * 256 + 60 + i] = (short)f2bf(tanhf(v));
    }
    // prefetch w2 chunk for channel 0
    p0 = *(const uint4*)(w2s + tid * 16);
    p1 = *(const uint4*)(w2s + tid * 16 + 8);
    __syncthreads();   // hpad ready

    // --- conv2 MFMA: D[e=32(8 valid), i=128] over K = 24ch x 128 ---
    f32x16 acc2;
#pragma unroll
    for (int r = 0; r < 16; ++r) acc2[r] = 0.0f;

    for (int c = 0; c < INTER; ++c) {
        const int buf = c & 1;
        *(uint4*)(&aw[buf][tid * 16])     = p0;
        *(uint4*)(&aw[buf][tid * 16 + 8]) = p1;
        if (c < INTER - 1) {
            p0 = *(const uint4*)(w2s + (c + 1) * 4096 + tid * 16);
            p1 = *(const uint4*)(w2s + (c + 1) * 4096 + tid * 16 + 8);
        }
        __syncthreads();
        const short* bbase = hpad + c * 256 + i0 + nn + hh * 8;
        const short* abase = &aw[buf][lane * 8];
#pragma unroll
        for (int kc = 0; kc < 8; ++kc) {
            s16x8 af = *(const s16x8*)(abase + kc * 512);
            s16x8 bf;
#pragma unroll
            for (int j = 0; j < 8; ++j) bf[j] = bbase[kc * 16 + j];
            acc2 = __builtin_amdgcn_mfma_f32_32x32x16_bf16(af, bf, acc2, 0, 0, 0);
        }
    }
    __syncthreads();

    // --- conv2 epilogue: rows e<8 live in regs 0..3 (e = (r&3)+4*hh) ---
    {
        const int i = i0 + nn;
#pragma unroll
        for (int r = 0; r < 4; ++r) {
            int e = r + 4 * hh;
            if (i < TLEN) lat[e * 122 + i] = acc2[r] + b2[e];
        }
    }
    __syncthreads();

    // --- DFT bins 1..60: power sums for f and a ---
    for (int q = tid; q < 480; q += 256) {
        int e_ = q / 60, k = q - e_ * 60 + 1;
        float re = 0.0f, im = 0.0f;
        int m = 0;
        for (int t = 0; t < TLEN; ++t) {
            float v = lat[e_ * 122 + t];
            float2 cs = tw[m];
            re += v * cs.x;
            im -= v * cs.y;
            m += k; m -= (m >= 121) ? 121 : 0;
        }
        float pw = re * re + im * im;
        atomicAdd(&S0[e_], pw);
        atomicAdd(&S1[e_], pw * (0.5f * (float)k));   // FREQS[k-1] = k/2
    }
    // --- fc ---
    if (tid < 16) {
        int e_ = tid >> 1, kk = tid & 1;
        float accv = fcb[e_ * 2 + kk];
        const float* fr = fcw + (e_ * 2 + kk) * TLEN;
        for (int t = 0; t < TLEN; ++t) accv += lat[e_ * 122 + t] * fr[t];
        vv[tid] = accv;
    }
    // --- b = mean(latent) ---
    if (tid >= 32 && tid < 40) {
        int e_ = tid - 32;
        float s = 0.0f;
        for (int t = 0; t < TLEN; ++t) s += lat[e_ * 122 + t];
        bm[e_] = s * (1.0f / 121.0f);
    }
    __syncthreads();

    if (tid < 8) {
        int e_ = tid;
        float fv = S1[e_] / S0[e_];
        float av = 2.0f * sqrtf(S0[e_]) * (1.0f / 121.0f);
        float pv = atan2f(vv[2 * e_ + 1], vv[2 * e_]) * 0.15915494309189535f;
        float bv = bm[e_];
        int gi = w * 8 + e_;
        pP[gi] = pv; pF[gi] = fv; pA[gi] = av; pB[gi] = bv;
        if (n == 0) {
            oP[b * 8 + e_] = pv;
            oF[b * 8 + e_] = fv;
            oA[b * 8 + e_] = av;
            oB[b * 8 + e_] = bv;
        }
    }
    if (n == 0) {
        for (int idx = tid; idx < EMB * TLEN; idx += 256) {
            int e_ = idx / TLEN, i = idx - e_ * TLEN;
            oLat[(b * EMB + e_) * TLEN + i] = lat[e_ * 122 + i];
        }
    }
}

// ---------------------------------------------------------------------------
// Kernel 2: sinusoid resynthesis + overlap-add, gather form (no atomics).
// ---------------------------------------------------------------------------
__global__ __launch_bounds__(256) void k_signal(
    const float* __restrict__ pP, const float* __restrict__ pF,
    const float* __restrict__ pA, const float* __restrict__ pB,
    float* __restrict__ sig, float* __restrict__ oSig)
{
    const int blk = blockIdx.x;
    const int b = blk >> 3, e = blk & 7;
    const int tid = threadIdx.x;
    __shared__ float sp[FULL], sf[FULL], sa[FULL], sb[FULL];
    for (int nn = tid; nn < FULL; nn += 256) {
        int gi = (b * FULL + nn) * 8 + e;
        sp[nn] = pP[gi]; sf[nn] = pF[gi]; sa[nn] = pA[gi]; sb[nn] = pB[gi];
    }
    __syncthreads();
    for (int u = tid; u < LP; u += 256) {
        int nlo = (u - 120 > 0) ? (u - 120) : 0;
        int nhi = (u < 239) ? u : 239;
        float s = 0.0f;
        for (int nn = nlo; nn <= nhi; ++nn) {
            float tt = (float)(u - nn);
            float z = sf[nn] * (tt * (1.0f / 60.0f) - 1.0f) + sp[nn];
            z -= floorf(z);
            s += sa[nn] * sinf(6.2831853071795864f * z) + sb[nn];
        }
        float wgt = (u < TLEN) ? (float)(u + 1) : ((u > 239) ? (float)(LP - u) : 121.0f);
        float val = s / wgt;
        sig[(b * EMB + e) * LP + u] = val;
        if (u < TLEN) oSig[(b * EMB + e) * TLEN + u] = val;
    }
}

// ---------------------------------------------------------------------------
// Kernel 3: decoder conv1 + BatchNorm partial sums.
// ---------------------------------------------------------------------------
__global__ __launch_bounds__(256) void k_dec1(
    const float* __restrict__ sig, const float* __restrict__ dw1, const float* __restrict__ db1,
    float* __restrict__ dbuf, float* __restrict__ bns)
{
    const int b = blockIdx.x / 3, og = blockIdx.x % 3;
    const int tid = threadIdx.x;
    __shared__ float ycp[EMB * 364];
    for (int idx = tid; idx < EMB * 364; idx += 256) {
        int c = idx / 364, q = idx - c * 364;
        float v = 0.0f;
        if (q >= 60 && q < 300) v = sig[(b * EMB + c) * LP + q];
        ycp[idx] = v;
    }
    __syncthreads();
    const int it = tid & 31, ol = tid >> 5;
    const int o = og * 8 + ol;
    const float bias = db1[o];
    float s = 0.0f, s2 = 0.0f;
    for (int g = 0; g < 8; ++g) {
        int i = it + 32 * g;
        if (i < FULL) {
            float accv = bias;
            for (int c = 0; c < EMB; ++c) {
                const float* wr = dw1 + (o * EMB + c) * TLEN;
                const float* yr = &ycp[c * 364 + i];
                for (int k = 0; k < TLEN; ++k) accv += wr[k] * yr[k];
            }
            dbuf[(b * INTER + o) * FULL + i] = accv;
            s += accv; s2 += accv * accv;
        }
    }
    for (int d = 16; d > 0; d >>= 1) { s += __shfl_down(s, d, 32); s2 += __shfl_down(s2, d, 32); }
    if (it == 0) { atomicAdd(&bns[o], s); atomicAdd(&bns[24 + o], s2); }
}

// ---------------------------------------------------------------------------
// Kernel 4: BatchNorm apply + tanh + decoder conv2.
// ---------------------------------------------------------------------------
__global__ __launch_bounds__(256) void k_dec2(
    const float* __restrict__ dbuf, const float* __restrict__ bns,
    const float* __restrict__ gma, const float* __restrict__ bta,
    const float* __restrict__ dw2, const float* __restrict__ db2,
    float* __restrict__ oY, float* __restrict__ oYp)
{
    const int b = blockIdx.x / 9, ocg = blockIdx.x % 9;
    const int tid = threadIdx.x;
    __shared__ float ddp[INTER * 364];
    __shared__ float scl[INTER], sft[INTER];
    if (tid < INTER) {
        float m  = bns[tid] * (1.0f / 3840.0f);
        float v  = bns[24 + tid] * (1.0f / 3840.0f) - m * m;
        float rs = rsqrtf(fmaxf(v, 0.0f) + 1e-5f);
        float g  = gma[tid];
        scl[tid] = rs * g;
        sft[tid] = bta[tid] - m * rs * g;
    }
    __syncthreads();
    for (int idx = tid; idx < INTER * 364; idx += 256) {
        int c = idx / 364, q = idx - c * 364;
        float v = 0.0f;
        if (q >= 60 && q < 300) {
            float dv = dbuf[(b * INTER + c) * FULL + (q - 60)];
            v = tanhf(dv * scl[c] + sft[c]);
        }
        ddp[idx] = v;
    }
    __syncthreads();
    const int it = tid & 31, ol = tid >> 5;
    const int oc = ocg * 8 + ol;
    const float bias = db2[oc];
    for (int g = 0; g < 8; ++g) {
        int i = it + 32 * g;
        if (i < FULL) {
            float accv = bias;
            for (int c = 0; c < INTER; ++c) {
                const float* wr = dw2 + (oc * INTER + c) * TLEN;
                const float* dr = &ddp[c * 364 + i];
                for (int k = 0; k < TLEN; ++k) accv += wr[k] * dr[k];
            }
            oY[(b * INCH + oc) * FULL + i] = accv;
            if (i < TLEN) oYp[(b * INCH + oc) * TLEN + i] = accv;
        }
    }
}

// ---------------------------------------------------------------------------
extern "C" void kernel_launch(void* const* d_in, const int* in_sizes, int n_in,
                              void* d_out, int out_size, void* d_ws, size_t ws_size,
                              hipStream_t stream)
{
    const float* x   = (const float*)d_in[0];
    const float* w1  = (const float*)d_in[1];
    const float* b1  = (const float*)d_in[2];
    const float* lna = (const float*)d_in[3];
    const float* lnb = (const float*)d_in[4];
    const float* w2  = (const float*)d_in[5];
    const float* b2  = (const float*)d_in[6];
    const float* fcw = (const float*)d_in[7];
    const float* fcb = (const float*)d_in[8];
    const float* dw1 = (const float*)d_in[9];
    const float* db1 = (const float*)d_in[10];
    const float* gma = (const float*)d_in[11];
    const float* bta = (const float*)d_in[12];
    const float* dw2 = (const float*)d_in[13];
    const float* db2 = (const float*)d_in[14];

    // Output layout (flat fp32, reference return order):
    float* out  = (float*)d_out;
    float* oY   = out;                 // [16][72][240] = 276480
    float* oLat = out + 276480;        // [16][8][121]  = 15488
    float* oSig = out + 291968;        // [16][8][121]  = 15488
    float* oP   = out + 307456;        // [16][8][1]
    float* oF   = out + 307584;
    float* oA   = out + 307712;
    float* oB   = out + 307840;
    float* oYp  = out + 307968;        // [16][72][121] = 139392

    // Workspace: swizzled bf16 weights first, then fp32 intermediates (~1.43MB)
    short* w1s  = (short*)d_ws;        // 294912 shorts
    short* w2s  = w1s + 294912;        // 98304 shorts  (end = 786432 B)
    float* fb   = (float*)d_ws + 196608;
    float* pP   = fb;                  // 30720
    float* pF   = pP + 30720;
    float* pA   = pF + 30720;
    float* pB   = pA + 30720;
    float* dbuf = fb;                  // overlay on params (temporally disjoint)
    float* sig  = fb + 122880;         // 46080
    float* bns  = sig + 46080;         // 48

    hipMemsetAsync(bns, 0, 48 * sizeof(float), stream);
    k_prep_w1<<<1152, 256, 0, stream>>>(w1, w1s);
    k_prep_w2<<<384, 256, 0, stream>>>(w2, w2s);
    k_enc<<<NWIN, 256, 0, stream>>>(x, w1s, b1, lna, lnb, w2s, b2, fcw, fcb,
                                    pP, pF, pA, pB, oLat, oP, oF, oA, oB);
    k_signal<<<128, 256, 0, stream>>>(pP, pF, pA, pB, sig, oSig);
    k_dec1<<<48, 256, 0, stream>>>(sig, dw1, db1, dbuf, bns);
    k_dec2<<<144, 256, 0, stream>>>(dbuf, bns, gma, bta, dw2, db2, oY, oYp);
}

// Round 6
// 1553.359 us; speedup vs baseline: 5.4429x; 1.6291x over previous
//
#include <hip/hip_runtime.h>
#include <math.h>

// ---------------------------------------------------------------------------
// PAE pipeline on MI355X. Round 6: conv1 via prefix-sum trick.
//   h[n,o,i] = R[min(121,181-i)][s] - R[max(0,60-i)][s],  s=(n+i-120)%240,
//   R = exclusive prefix over taps m of Q[o,m,s] = sum_c w1[o,c,m]*x[c,(s+m)%240].
//   Q/R cost: 803 M MAC total (vs 73 G MAC naive per-window conv1).
//   conv2 stays per-window MFMA bf16 (round-5 verified code, unchanged).
//   R needs 45 MB ws -> host-side branch on ws_size (fallback = round-5 path).
// ---------------------------------------------------------------------------

#define INCH   72
#define TLEN   121
#define FULL   240
#define INTER  24
#define EMB    8
#define LP     360
#define NWIN   3840

typedef __attribute__((ext_vector_type(8)))  short s16x8;
typedef __attribute__((ext_vector_type(16))) float f32x16;

// fp32 -> bf16 (RNE) as raw ushort
__device__ __forceinline__ unsigned short f2bf(float f) {
    unsigned u = __float_as_uint(f);
    unsigned r = ((u >> 16) & 1u) + 0x7FFFu;
    return (unsigned short)((u + r) >> 16);
}

// ---------------------------------------------------------------------------
// Weight pre-swizzle kernels (once per launch).
// ---------------------------------------------------------------------------
__global__ __launch_bounds__(256) void k_prep_w1(const float* __restrict__ w1,
                                                 short* __restrict__ w1s) {
    int idx = blockIdx.x * 256 + threadIdx.x;           // < 72*8*64*8 = 294912
    int j = idx & 7, ln = (idx >> 3) & 63, kc = (idx >> 9) & 7, c = idx >> 12;
    int o = ln & 31, kk = kc * 16 + (ln >> 5) * 8 + j;
    float v = (o < INTER && kk < TLEN) ? w1[(o * INCH + c) * TLEN + kk] : 0.0f;
    w1s[idx] = (short)f2bf(v);
}
__global__ __launch_bounds__(256) void k_prep_w2(const float* __restrict__ w2,
                                                 short* __restrict__ w2s) {
    int idx = blockIdx.x * 256 + threadIdx.x;           // < 24*8*64*8 = 98304
    int j = idx & 7, ln = (idx >> 3) & 63, kc = (idx >> 9) & 7, c = idx >> 12;
    int o = ln & 31, kk = kc * 16 + (ln >> 5) * 8 + j;
    float v = (o < EMB && kk < TLEN) ? w2[(o * INTER + c) * TLEN + kk] : 0.0f;
    w2s[idx] = (short)f2bf(v);
}

// ---------------------------------------------------------------------------
// k_qr: Q + exclusive prefix R, fused. Block = (b,o) (384 blocks).
// Thread s (0..239) walks taps m sequentially:
//   Q = sum_c w1[o,c,m]*xs[c,(s+m)%240];  R[m+1][s] = R[m][s] + Q; R[0]=0.
// x[b] staged to LDS (69 KB); w1 reads are wave-uniform (scalar/broadcast).
// ---------------------------------------------------------------------------
__global__ __launch_bounds__(256) void k_qr(
    const float* __restrict__ x, const float* __restrict__ w1,
    float* __restrict__ R)
{
    const int blk = blockIdx.x;          // b*24 + o
    const int b = blk / INTER, o = blk - b * INTER;
    const int tid = threadIdx.x;
    __shared__ float xs[INCH * FULL];    // 69120 B
    for (int idx = tid; idx < INCH * FULL; idx += 256)
        xs[idx] = x[b * INCH * FULL + idx];
    __syncthreads();
    if (tid >= FULL) return;             // no further barriers below
    const int s = tid;
    const float* wq = w1 + o * (INCH * TLEN);
    float* Rb = R + (size_t)blk * (122 * FULL);
    Rb[s] = 0.0f;                        // mi = 0 (exclusive prefix base)
    float P = 0.0f;
    for (int m = 0; m < TLEN; ++m) {
        int idxm = s + m;
        idxm -= (idxm >= FULL) ? FULL : 0;
        float q = 0.0f;
        for (int c = 0; c < INCH; ++c)
            q += wq[c * TLEN + m] * xs[c * FULL + idxm];
        P += q;
        Rb[(m + 1) * FULL + s] = P;
    }
}

// ---------------------------------------------------------------------------
// k_enc_pref: encoder with conv1 replaced by R-gather. 3840 blocks x 256 thr.
// LDS ~45.6 KB -> 3 blocks/CU. conv2/LN/DFT/fc identical to round-5 k_enc.
// ---------------------------------------------------------------------------
__global__ __launch_bounds__(256) void k_enc_pref(
    const float* __restrict__ R,  const float* __restrict__ b1,
    const float* __restrict__ lna, const float* __restrict__ lnb,
    const short* __restrict__ w2s, const float* __restrict__ b2,
    const float* __restrict__ fcw, const float* __restrict__ fcb,
    float* __restrict__ pP, float* __restrict__ pF, float* __restrict__ pA, float* __restrict__ pB,
    float* __restrict__ oLat, float* __restrict__ oP, float* __restrict__ oF,
    float* __restrict__ oA, float* __restrict__ oB)
{
    const int w   = blockIdx.x;
    const int b   = w / FULL, n = w - b * FULL;
    const int tid = threadIdx.x;
    const int lane = tid & 63, wid = tid >> 6;

    __shared__ __align__(16) short aw[2][4096];        // 16384 B (A dbuf)
    __shared__ __align__(16) short hpad[INTER * 256];  // 12288 B
    __shared__ float hp[INTER * 122];                  // 11712 B
    __shared__ float lat[EMB * 122];                   // 3904 B
    __shared__ float2 tw[121];
    __shared__ float lnM[INTER], lnI[INTER];
    __shared__ float S0[8], S1[8], vv[16], bm[8];

    for (int idx = tid; idx < INTER * 256; idx += 256) hpad[idx] = 0;
    if (tid < TLEN) {
        float s, c;
        sincosf(6.2831853071795864f * (float)tid / 121.0f, &s, &c);
        tw[tid] = make_float2(c, s);
    }
    if (tid < 8) { S0[tid] = 0.0f; S1[tid] = 0.0f; }

    // --- conv1 result via prefix-sum gather ---
    const float* Rb = R + (size_t)(b * INTER) * (122 * FULL);
    for (int idx = tid; idx < INTER * TLEN; idx += 256) {
        int o = idx / TLEN, i = idx - o * TLEN;
        int st = n + i - 120;
        st += (st < 0) ? FULL : 0;                     // (n+i-120) mod 240
        int up = (i <= 60) ? 121 : (181 - i);          // m_hi + 1
        int lo = (i <= 60) ? (60 - i) : 0;             // m_lo
        const float* Ro = Rb + (size_t)o * (122 * FULL);
        hp[o * 122 + i] = Ro[up * FULL + st] - Ro[lo * FULL + st] + b1[o];
    }
    __syncthreads();

    // --- LayerNorm (ddof=1, /(std+1e-5)) stats ---
    if (tid < INTER) {
        float s = 0.0f, s2 = 0.0f;
        for (int i = 0; i < TLEN; ++i) { float v = hp[tid * 122 + i]; s += v; s2 += v * v; }
        float mean = s * (1.0f / 121.0f);
        float var  = fmaxf((s2 - s * mean) * (1.0f / 120.0f), 0.0f);
        lnM[tid] = mean;
        lnI[tid] = 1.0f / (sqrtf(var) + 1e-5f);
    }
    __syncthreads();
    for (int idx = tid; idx < INTER * TLEN; idx += 256) {
        int o = idx / TLEN, i = idx - o * TLEN;
        float v = (hp[o * 122 + i] - lnM[o]) * lnI[o] * lna[i] + lnb[i];
        hpad[o * 256 + 60 + i] = (short)f2bf(tanhf(v));
    }
    // prefetch w2 chunk for channel 0
    uint4 p0 = *(const uint4*)(w2s + tid * 16);
    uint4 p1 = *(const uint4*)(w2s + tid * 16 + 8);
    __syncthreads();   // hpad ready

    const int i0 = wid * 32;
    const int nn = lane & 31, hh = lane >> 5;

    // --- conv2 MFMA: D[e=32(8 valid), i=128] over K = 24ch x 128 ---
    f32x16 acc2;
#pragma unroll
    for (int r = 0; r < 16; ++r) acc2[r] = 0.0f;

    for (int c = 0; c < INTER; ++c) {
        const int buf = c & 1;
        *(uint4*)(&aw[buf][tid * 16])     = p0;
        *(uint4*)(&aw[buf][tid * 16 + 8]) = p1;
        if (c < INTER - 1) {
            p0 = *(const uint4*)(w2s + (c + 1) * 4096 + tid * 16);
            p1 = *(const uint4*)(w2s + (c + 1) * 4096 + tid * 16 + 8);
        }
        __syncthreads();
        const short* bbase = hpad + c * 256 + i0 + nn + hh * 8;
        const short* abase = &aw[buf][lane * 8];
#pragma unroll
        for (int kc = 0; kc < 8; ++kc) {
            s16x8 af = *(const s16x8*)(abase + kc * 512);
            s16x8 bf;
#pragma unroll
            for (int j = 0; j < 8; ++j) bf[j] = bbase[kc * 16 + j];
            acc2 = __builtin_amdgcn_mfma_f32_32x32x16_bf16(af, bf, acc2, 0, 0, 0);
        }
        __syncthreads();
    }

    // --- conv2 epilogue: rows e<8 live in regs 0..3 (e = (r&3)+4*hh) ---
    {
        const int i = i0 + nn;
#pragma unroll
        for (int r = 0; r < 4; ++r) {
            int e = r + 4 * hh;
            if (i < TLEN) lat[e * 122 + i] = acc2[r] + b2[e];
        }
    }
    __syncthreads();

    // --- DFT bins 1..60: power sums for f and a ---
    for (int q = tid; q < 480; q += 256) {
        int e_ = q / 60, k = q - e_ * 60 + 1;
        float re = 0.0f, im = 0.0f;
        int m = 0;
        for (int t = 0; t < TLEN; ++t) {
            float v = lat[e_ * 122 + t];
            float2 cs = tw[m];
            re += v * cs.x;
            im -= v * cs.y;
            m += k; m -= (m >= 121) ? 121 : 0;
        }
        float pw = re * re + im * im;
        atomicAdd(&S0[e_], pw);
        atomicAdd(&S1[e_], pw * (0.5f * (float)k));   // FREQS[k-1] = k/2
    }
    // --- fc ---
    if (tid < 16) {
        int e_ = tid >> 1, kk = tid & 1;
        float accv = fcb[e_ * 2 + kk];
        const float* fr = fcw + (e_ * 2 + kk) * TLEN;
        for (int t = 0; t < TLEN; ++t) accv += lat[e_ * 122 + t] * fr[t];
        vv[tid] = accv;
    }
    // --- b = mean(latent) ---
    if (tid >= 32 && tid < 40) {
        int e_ = tid - 32;
        float s = 0.0f;
        for (int t = 0; t < TLEN; ++t) s += lat[e_ * 122 + t];
        bm[e_] = s * (1.0f / 121.0f);
    }
    __syncthreads();

    if (tid < 8) {
        int e_ = tid;
        float fv = S1[e_] / S0[e_];
        float av = 2.0f * sqrtf(S0[e_]) * (1.0f / 121.0f);
        float pv = atan2f(vv[2 * e_ + 1], vv[2 * e_]) * 0.15915494309189535f;
        float bv = bm[e_];
        int gi = w * 8 + e_;
        pP[gi] = pv; pF[gi] = fv; pA[gi] = av; pB[gi] = bv;
        if (n == 0) {
            oP[b * 8 + e_] = pv;
            oF[b * 8 + e_] = fv;
            oA[b * 8 + e_] = av;
            oB[b * 8 + e_] = bv;
        }
    }
    if (n == 0) {
        for (int idx = tid; idx < EMB * TLEN; idx += 256) {
            int e_ = idx / TLEN, i = idx - e_ * TLEN;
            oLat[(b * EMB + e_) * TLEN + i] = lat[e_ * 122 + i];
        }
    }
}

// ---------------------------------------------------------------------------
// FALLBACK: round-5 full per-window encoder (used when ws_size too small).
// ---------------------------------------------------------------------------
__global__ __launch_bounds__(256) void k_enc(
    const float* __restrict__ x,  const short* __restrict__ w1s, const float* __restrict__ b1,
    const float* __restrict__ lna, const float* __restrict__ lnb,
    const short* __restrict__ w2s, const float* __restrict__ b2,
    const float* __restrict__ fcw, const float* __restrict__ fcb,
    float* __restrict__ pP, float* __restrict__ pF, float* __restrict__ pA, float* __restrict__ pB,
    float* __restrict__ oLat, float* __restrict__ oP, float* __restrict__ oF,
    float* __restrict__ oA, float* __restrict__ oB)
{
    const int w   = blockIdx.x;
    const int b   = w / FULL, n = w - b * FULL;
    const int tid = threadIdx.x;
    const int lane = tid & 63, wid = tid >> 6;

    __shared__ __align__(16) short winp[INCH * 256];
    __shared__ __align__(16) short aw[2][4096];
    __shared__ __align__(16) short hpad[INTER * 256];
    __shared__ float lat[EMB * 122];
    __shared__ float2 tw[121];
    __shared__ float lnM[INTER], lnI[INTER];
    __shared__ float S0[8], S1[8], vv[16], bm[8];
    float* hp = (float*)winp;

    for (int idx = tid; idx < INCH * 256; idx += 256) {
        int c = idx >> 8, s = idx & 255;
        unsigned short v = 0;
        if (s >= 60 && s < 181) {
            int q = n + s - 120;
            q += (q < 0) ? FULL : 0;
            q -= (q >= FULL) ? FULL : 0;
            v = f2bf(x[(b * INCH + c) * FULL + q]);
        }
        winp[idx] = (short)v;
    }
    for (int idx = tid; idx < INTER * 256; idx += 256) hpad[idx] = 0;
    if (tid < TLEN) {
        float s, c;
        sincosf(6.2831853071795864f * (float)tid / 121.0f, &s, &c);
        tw[tid] = make_float2(c, s);
    }
    if (tid < 8) { S0[tid] = 0.0f; S1[tid] = 0.0f; }

    uint4 p0 = *(const uint4*)(w1s + tid * 16);
    uint4 p1 = *(const uint4*)(w1s + tid * 16 + 8);
    __syncthreads();

    const int i0 = wid * 32;
    const int nn = lane & 31, hh = lane >> 5;

    f32x16 acc;
#pragma unroll
    for (int r = 0; r < 16; ++r) acc[r] = 0.0f;

    for (int c = 0; c < INCH; ++c) {
        const int buf = c & 1;
        *(uint4*)(&aw[buf][tid * 16])     = p0;
        *(uint4*)(&aw[buf][tid * 16 + 8]) = p1;
        if (c < INCH - 1) {
            p0 = *(const uint4*)(w1s + (c + 1) * 4096 + tid * 16);
            p1 = *(const uint4*)(w1s + (c + 1) * 4096 + tid * 16 + 8);
        }
        __syncthreads();
        const short* bbase = winp + c * 256 + i0 + nn + hh * 8;
        const short* abase = &aw[buf][lane * 8];
#pragma unroll
        for (int kc = 0; kc < 8; ++kc) {
            s16x8 af = *(const s16x8*)(abase + kc * 512);
            s16x8 bf;
#pragma unroll
            for (int j = 0; j < 8; ++j) bf[j] = bbase[kc * 16 + j];
            acc = __builtin_amdgcn_mfma_f32_32x32x16_bf16(af, bf, acc, 0, 0, 0);
        }
    }
    __syncthreads();

    {
        const int i = i0 + nn;
#pragma unroll
        for (int r = 0; r < 16; ++r) {
            int o = (r & 3) + 8 * (r >> 2) + 4 * hh;
            if (o < INTER && i < TLEN) hp[o * 122 + i] = acc[r] + b1[o];
        }
    }
    __syncthreads();

    if (tid < INTER) {
        float s = 0.0f, s2 = 0.0f;
        for (int i = 0; i < TLEN; ++i) { float v = hp[tid * 122 + i]; s += v; s2 += v * v; }
        float mean = s * (1.0f / 121.0f);
        float var  = fmaxf((s2 - s * mean) * (1.0f / 120.0f), 0.0f);
        lnM[tid] = mean;
        lnI[tid] = 1.0f / (sqrtf(var) + 1e-5f);
    }
    __syncthreads();
    for (int idx = tid; idx < INTER * TLEN; idx += 256) {
        int o = idx / TLEN, i = idx - o * TLEN;
        float v = (hp[o * 122 + i] - lnM[o]) * lnI[o] * lna[i] + lnb[i];
        hpad[o * 256 + 60 + i] = (short)f2bf(tanhf(v));
    }
    p0 = *(const uint4*)(w2s + tid * 16);
    p1 = *(const uint4*)(w2s + tid * 16 + 8);
    __syncthreads();

    f32x16 acc2;
#pragma unroll
    for (int r = 0; r < 16; ++r) acc2[r] = 0.0f;

    for (int c = 0; c < INTER; ++c) {
        const int buf = c & 1;
        *(uint4*)(&aw[buf][tid * 16])     = p0;
        *(uint4*)(&aw[buf][tid * 16 + 8]) = p1;
        if (c < INTER - 1) {
            p0 = *(const uint4*)(w2s + (c + 1) * 4096 + tid * 16);
            p1 = *(const uint4*)(w2s + (c + 1) * 4096 + tid * 16 + 8);
        }
        __syncthreads();
        const short* bbase = hpad + c * 256 + i0 + nn + hh * 8;
        const short* abase = &aw[buf][lane * 8];
#pragma unroll
        for (int kc = 0; kc < 8; ++kc) {
            s16x8 af = *(const s16x8*)(abase + kc * 512);
            s16x8 bf;
#pragma unroll
            for (int j = 0; j < 8; ++j) bf[j] = bbase[kc * 16 + j];
            acc2 = __builtin_amdgcn_mfma_f32_32x32x16_bf16(af, bf, acc2, 0, 0, 0);
        }
    }
    __syncthreads();

    {
        const int i = i0 + nn;
#pragma unroll
        for (int r = 0; r < 4; ++r) {
            int e = r + 4 * hh;
            if (i < TLEN) lat[e * 122 + i] = acc2[r] + b2[e];
        }
    }
    __syncthreads();

    for (int q = tid; q < 480; q += 256) {
        int e_ = q / 60, k = q - e_ * 60 + 1;
        float re = 0.0f, im = 0.0f;
        int m = 0;
        for (int t = 0; t < TLEN; ++t) {
            float v = lat[e_ * 122 + t];
            float2 cs = tw[m];
            re += v * cs.x;
            im -= v * cs.y;
            m += k; m -= (m >= 121) ? 121 : 0;
        }
        float pw = re * re + im * im;
        atomicAdd(&S0[e_], pw);
        atomicAdd(&S1[e_], pw * (0.5f * (float)k));
    }
    if (tid < 16) {
        int e_ = tid >> 1, kk = tid & 1;
        float accv = fcb[e_ * 2 + kk];
        const float* fr = fcw + (e_ * 2 + kk) * TLEN;
        for (int t = 0; t < TLEN; ++t) accv += lat[e_ * 122 + t] * fr[t];
        vv[tid] = accv;
    }
    if (tid >= 32 && tid < 40) {
        int e_ = tid - 32;
        float s = 0.0f;
        for (int t = 0; t < TLEN; ++t) s += lat[e_ * 122 + t];
        bm[e_] = s * (1.0f / 121.0f);
    }
    __syncthreads();

    if (tid < 8) {
        int e_ = tid;
        float fv = S1[e_] / S0[e_];
        float av = 2.0f * sqrtf(S0[e_]) * (1.0f / 121.0f);
        float pv = atan2f(vv[2 * e_ + 1], vv[2 * e_]) * 0.15915494309189535f;
        float bv = bm[e_];
        int gi = w * 8 + e_;
        pP[gi] = pv; pF[gi] = fv; pA[gi] = av; pB[gi] = bv;
        if (n == 0) {
            oP[b * 8 + e_] = pv;
            oF[b * 8 + e_] = fv;
            oA[b * 8 + e_] = av;
            oB[b * 8 + e_] = bv;
        }
    }
    if (n == 0) {
        for (int idx = tid; idx < EMB * TLEN; idx += 256) {
            int e_ = idx / TLEN, i = idx - e_ * TLEN;
            oLat[(b * EMB + e_) * TLEN + i] = lat[e_ * 122 + i];
        }
    }
}

// ---------------------------------------------------------------------------
// Kernel 2: sinusoid resynthesis + overlap-add, gather form (no atomics).
// ---------------------------------------------------------------------------
__global__ __launch_bounds__(256) void k_signal(
    const float* __restrict__ pP, const float* __restrict__ pF,
    const float* __restrict__ pA, const float* __restrict__ pB,
    float* __restrict__ sig, float* __restrict__ oSig)
{
    const int blk = blockIdx.x;
    const int b = blk >> 3, e = blk & 7;
    const int tid = threadIdx.x;
    __shared__ float sp[FULL], sf[FULL], sa[FULL], sb[FULL];
    for (int nn = tid; nn < FULL; nn += 256) {
        int gi = (b * FULL + nn) * 8 + e;
        sp[nn] = pP[gi]; sf[nn] = pF[gi]; sa[nn] = pA[gi]; sb[nn] = pB[gi];
    }
    __syncthreads();
    for (int u = tid; u < LP; u += 256) {
        int nlo = (u - 120 > 0) ? (u - 120) : 0;
        int nhi = (u < 239) ? u : 239;
        float s = 0.0f;
        for (int nn = nlo; nn <= nhi; ++nn) {
            float tt = (float)(u - nn);
            float z = sf[nn] * (tt * (1.0f / 60.0f) - 1.0f) + sp[nn];
            z -= floorf(z);
            s += sa[nn] * sinf(6.2831853071795864f * z) + sb[nn];
        }
        float wgt = (u < TLEN) ? (float)(u + 1) : ((u > 239) ? (float)(LP - u) : 121.0f);
        float val = s / wgt;
        sig[(b * EMB + e) * LP + u] = val;
        if (u < TLEN) oSig[(b * EMB + e) * TLEN + u] = val;
    }
}

// ---------------------------------------------------------------------------
// Kernel 3: decoder conv1 + BatchNorm partial sums.
// ---------------------------------------------------------------------------
__global__ __launch_bounds__(256) void k_dec1(
    const float* __restrict__ sig, const float* __restrict__ dw1, const float* __restrict__ db1,
    float* __restrict__ dbuf, float* __restrict__ bns)
{
    const int b = blockIdx.x / 3, og = blockIdx.x % 3;
    const int tid = threadIdx.x;
    __shared__ float ycp[EMB * 364];
    for (int idx = tid; idx < EMB * 364; idx += 256) {
        int c = idx / 364, q = idx - c * 364;
        float v = 0.0f;
        if (q >= 60 && q < 300) v = sig[(b * EMB + c) * LP + q];
        ycp[idx] = v;
    }
    __syncthreads();
    const int it = tid & 31, ol = tid >> 5;
    const int o = og * 8 + ol;
    const float bias = db1[o];
    float s = 0.0f, s2 = 0.0f;
    for (int g = 0; g < 8; ++g) {
        int i = it + 32 * g;
        if (i < FULL) {
            float accv = bias;
            for (int c = 0; c < EMB; ++c) {
                const float* wr = dw1 + (o * EMB + c) * TLEN;
                const float* yr = &ycp[c * 364 + i];
                for (int k = 0; k < TLEN; ++k) accv += wr[k] * yr[k];
            }
            dbuf[(b * INTER + o) * FULL + i] = accv;
            s += accv; s2 += accv * accv;
        }
    }
    for (int d = 16; d > 0; d >>= 1) { s += __shfl_down(s, d, 32); s2 += __shfl_down(s2, d, 32); }
    if (it == 0) { atomicAdd(&bns[o], s); atomicAdd(&bns[24 + o], s2); }
}

// ---------------------------------------------------------------------------
// Kernel 4: BatchNorm apply + tanh + decoder conv2.
// ---------------------------------------------------------------------------
__global__ __launch_bounds__(256) void k_dec2(
    const float* __restrict__ dbuf, const float* __restrict__ bns,
    const float* __restrict__ gma, const float* __restrict__ bta,
    const float* __restrict__ dw2, const float* __restrict__ db2,
    float* __restrict__ oY, float* __restrict__ oYp)
{
    const int b = blockIdx.x / 9, ocg = blockIdx.x % 9;
    const int tid = threadIdx.x;
    __shared__ float ddp[INTER * 364];
    __shared__ float scl[INTER], sft[INTER];
    if (tid < INTER) {
        float m  = bns[tid] * (1.0f / 3840.0f);
        float v  = bns[24 + tid] * (1.0f / 3840.0f) - m * m;
        float rs = rsqrtf(fmaxf(v, 0.0f) + 1e-5f);
        float g  = gma[tid];
        scl[tid] = rs * g;
        sft[tid] = bta[tid] - m * rs * g;
    }
    __syncthreads();
    for (int idx = tid; idx < INTER * 364; idx += 256) {
        int c = idx / 364, q = idx - c * 364;
        float v = 0.0f;
        if (q >= 60 && q < 300) {
            float dv = dbuf[(b * INTER + c) * FULL + (q - 60)];
            v = tanhf(dv * scl[c] + sft[c]);
        }
        ddp[idx] = v;
    }
    __syncthreads();
    const int it = tid & 31, ol = tid >> 5;
    const int oc = ocg * 8 + ol;
    const float bias = db2[oc];
    for (int g = 0; g < 8; ++g) {
        int i = it + 32 * g;
        if (i < FULL) {
            float accv = bias;
            for (int c = 0; c < INTER; ++c) {
                const float* wr = dw2 + (oc * INTER + c) * TLEN;
                const float* dr = &ddp[c * 364 + i];
                for (int k = 0; k < TLEN; ++k) accv += wr[k] * dr[k];
            }
            oY[(b * INCH + oc) * FULL + i] = accv;
            if (i < TLEN) oYp[(b * INCH + oc) * TLEN + i] = accv;
        }
    }
}

// ---------------------------------------------------------------------------
extern "C" void kernel_launch(void* const* d_in, const int* in_sizes, int n_in,
                              void* d_out, int out_size, void* d_ws, size_t ws_size,
                              hipStream_t stream)
{
    const float* x   = (const float*)d_in[0];
    const float* w1  = (const float*)d_in[1];
    const float* b1  = (const float*)d_in[2];
    const float* lna = (const float*)d_in[3];
    const float* lnb = (const float*)d_in[4];
    const float* w2  = (const float*)d_in[5];
    const float* b2  = (const float*)d_in[6];
    const float* fcw = (const float*)d_in[7];
    const float* fcb = (const float*)d_in[8];
    const float* dw1 = (const float*)d_in[9];
    const float* db1 = (const float*)d_in[10];
    const float* gma = (const float*)d_in[11];
    const float* bta = (const float*)d_in[12];
    const float* dw2 = (const float*)d_in[13];
    const float* db2 = (const float*)d_in[14];

    // Output layout (flat fp32, reference return order):
    float* out  = (float*)d_out;
    float* oY   = out;                 // [16][72][240]
    float* oLat = out + 276480;        // [16][8][121]
    float* oSig = out + 291968;        // [16][8][121]
    float* oP   = out + 307456;
    float* oF   = out + 307584;
    float* oA   = out + 307712;
    float* oB   = out + 307840;
    float* oYp  = out + 307968;        // [16][72][121]

    // Workspace layout:
    //   [0, 589824)           w1s (bf16 swizzled, fallback path only)
    //   [589824, 786432)      w2s (bf16 swizzled, both paths)
    //   [786432, 1462464)     fp32 region: pP/pF/pA/pB (overlaid by dbuf), sig, bns
    //   [1462464, +44.97 MB)  R prefix table (prefix path only)
    short* w1s  = (short*)d_ws;
    short* w2s  = w1s + 294912;
    float* fb   = (float*)((char*)d_ws + 786432);
    float* pP   = fb;
    float* pF   = pP + 30720;
    float* pA   = pF + 30720;
    float* pB   = pA + 30720;
    float* dbuf = fb;                  // overlay (temporally disjoint)
    float* sig  = fb + 122880;
    float* bns  = sig + 46080;
    float* R    = (float*)((char*)d_ws + 1462464);

    const size_t needed = 1462464ull + 44974080ull;   // ~46.4 MB
    const bool use_prefix = (ws_size >= needed);

    hipMemsetAsync(bns, 0, 48 * sizeof(float), stream);
    k_prep_w2<<<384, 256, 0, stream>>>(w2, w2s);
    if (use_prefix) {
        k_qr<<<384, 256, 0, stream>>>(x, w1, R);
        k_enc_pref<<<NWIN, 256, 0, stream>>>(R, b1, lna, lnb, w2s, b2, fcw, fcb,
                                             pP, pF, pA, pB, oLat, oP, oF, oA, oB);
    } else {
        k_prep_w1<<<1152, 256, 0, stream>>>(w1, w1s);
        k_enc<<<NWIN, 256, 0, stream>>>(x, w1s, b1, lna, lnb, w2s, b2, fcw, fcb,
                                        pP, pF, pA, pB, oLat, oP, oF, oA, oB);
    }
    k_signal<<<128, 256, 0, stream>>>(pP, pF, pA, pB, sig, oSig);
    k_dec1<<<48, 256, 0, stream>>>(sig, dw1, db1, dbuf, bns);
    k_dec2<<<144, 256, 0, stream>>>(dbuf, bns, gma, bta, dw2, db2, oY, oYp);
}

// Round 7
// 891.725 us; speedup vs baseline: 9.4813x; 1.7420x over previous
//
#include <hip/hip_runtime.h>
#include <math.h>

// ---------------------------------------------------------------------------
// PAE pipeline on MI355X. Round 7: decoder restructured for latency tolerance.
//   encoder: conv1 via prefix-sum table R (k_qr), conv2 per-window MFMA bf16
//   (k_enc_pref) -- both byte-identical to round 6 (verified, absmax 0.0625).
//   decoder: k_dec1 384 blocks x 64 thr (sliding-float4-window conv, 4 outputs
//   per thread), k_bn (BN+tanh precompute, global), k_dec2 1152 blocks x 64 thr.
//   Round-6 counters: k_dec2 was 745 us @ 144 blocks, VALUBusy 4.5% -- pure
//   launch-geometry/latency problem for a 1.6 GFLOP conv.
// ---------------------------------------------------------------------------

#define INCH   72
#define TLEN   121
#define FULL   240
#define INTER  24
#define EMB    8
#define LP     360
#define NWIN   3840

typedef __attribute__((ext_vector_type(8)))  short s16x8;
typedef __attribute__((ext_vector_type(16))) float f32x16;

// fp32 -> bf16 (RNE) as raw ushort
__device__ __forceinline__ unsigned short f2bf(float f) {
    unsigned u = __float_as_uint(f);
    unsigned r = ((u >> 16) & 1u) + 0x7FFFu;
    return (unsigned short)((u + r) >> 16);
}

// ---------------------------------------------------------------------------
// w2 pre-swizzle for MFMA A-fragments (once per launch).
// ---------------------------------------------------------------------------
__global__ __launch_bounds__(256) void k_prep_w2(const float* __restrict__ w2,
                                                 short* __restrict__ w2s) {
    int idx = blockIdx.x * 256 + threadIdx.x;           // < 24*8*64*8 = 98304
    int j = idx & 7, ln = (idx >> 3) & 63, kc = (idx >> 9) & 7, c = idx >> 12;
    int o = ln & 31, kk = kc * 16 + (ln >> 5) * 8 + j;
    float v = (o < EMB && kk < TLEN) ? w2[(o * INTER + c) * TLEN + kk] : 0.0f;
    w2s[idx] = (short)f2bf(v);
}

// ---------------------------------------------------------------------------
// k_qr: Q + exclusive prefix R, fused. Block = (b,o) (384 blocks).
// ---------------------------------------------------------------------------
__global__ __launch_bounds__(256) void k_qr(
    const float* __restrict__ x, const float* __restrict__ w1,
    float* __restrict__ R)
{
    const int blk = blockIdx.x;          // b*24 + o
    const int b = blk / INTER, o = blk - b * INTER;
    const int tid = threadIdx.x;
    __shared__ float xs[INCH * FULL];    // 69120 B
    for (int idx = tid; idx < INCH * FULL; idx += 256)
        xs[idx] = x[b * INCH * FULL + idx];
    __syncthreads();
    if (tid >= FULL) return;             // no further barriers below
    const int s = tid;
    const float* wq = w1 + o * (INCH * TLEN);
    float* Rb = R + (size_t)blk * (122 * FULL);
    Rb[s] = 0.0f;                        // m = 0 (exclusive prefix base)
    float P = 0.0f;
    for (int m = 0; m < TLEN; ++m) {
        int idxm = s + m;
        idxm -= (idxm >= FULL) ? FULL : 0;
        float q = 0.0f;
        for (int c = 0; c < INCH; ++c)
            q += wq[c * TLEN + m] * xs[c * FULL + idxm];
        P += q;
        Rb[(m + 1) * FULL + s] = P;
    }
}

// ---------------------------------------------------------------------------
// k_enc_pref: encoder with conv1 via R-gather. 3840 blocks x 256 thr.
// ---------------------------------------------------------------------------
__global__ __launch_bounds__(256) void k_enc_pref(
    const float* __restrict__ R,  const float* __restrict__ b1,
    const float* __restrict__ lna, const float* __restrict__ lnb,
    const short* __restrict__ w2s, const float* __restrict__ b2,
    const float* __restrict__ fcw, const float* __restrict__ fcb,
    float* __restrict__ pP, float* __restrict__ pF, float* __restrict__ pA, float* __restrict__ pB,
    float* __restrict__ oLat, float* __restrict__ oP, float* __restrict__ oF,
    float* __restrict__ oA, float* __restrict__ oB)
{
    const int w   = blockIdx.x;
    const int b   = w / FULL, n = w - b * FULL;
    const int tid = threadIdx.x;
    const int lane = tid & 63, wid = tid >> 6;

    __shared__ __align__(16) short aw[2][4096];        // 16384 B (A dbuf)
    __shared__ __align__(16) short hpad[INTER * 256];  // 12288 B
    __shared__ float hp[INTER * 122];                  // 11712 B
    __shared__ float lat[EMB * 122];                   // 3904 B
    __shared__ float2 tw[121];
    __shared__ float lnM[INTER], lnI[INTER];
    __shared__ float S0[8], S1[8], vv[16], bm[8];

    for (int idx = tid; idx < INTER * 256; idx += 256) hpad[idx] = 0;
    if (tid < TLEN) {
        float s, c;
        sincosf(6.2831853071795864f * (float)tid / 121.0f, &s, &c);
        tw[tid] = make_float2(c, s);
    }
    if (tid < 8) { S0[tid] = 0.0f; S1[tid] = 0.0f; }

    // --- conv1 result via prefix-sum gather ---
    const float* Rb = R + (size_t)(b * INTER) * (122 * FULL);
    for (int idx = tid; idx < INTER * TLEN; idx += 256) {
        int o = idx / TLEN, i = idx - o * TLEN;
        int st = n + i - 120;
        st += (st < 0) ? FULL : 0;                     // (n+i-120) mod 240
        int up = (i <= 60) ? 121 : (181 - i);          // m_hi + 1
        int lo = (i <= 60) ? (60 - i) : 0;             // m_lo
        const float* Ro = Rb + (size_t)o * (122 * FULL);
        hp[o * 122 + i] = Ro[up * FULL + st] - Ro[lo * FULL + st] + b1[o];
    }
    __syncthreads();

    // --- LayerNorm (ddof=1, /(std+1e-5)) stats ---
    if (tid < INTER) {
        float s = 0.0f, s2 = 0.0f;
        for (int i = 0; i < TLEN; ++i) { float v = hp[tid * 122 + i]; s += v; s2 += v * v; }
        float mean = s * (1.0f / 121.0f);
        float var  = fmaxf((s2 - s * mean) * (1.0f / 120.0f), 0.0f);
        lnM[tid] = mean;
        lnI[tid] = 1.0f / (sqrtf(var) + 1e-5f);
    }
    __syncthreads();
    for (int idx = tid; idx < INTER * TLEN; idx += 256) {
        int o = idx / TLEN, i = idx - o * TLEN;
        float v = (hp[o * 122 + i] - lnM[o]) * lnI[o] * lna[i] + lnb[i];
        hpad[o * 256 + 60 + i] = (short)f2bf(tanhf(v));
    }
    // prefetch w2 chunk for channel 0
    uint4 p0 = *(const uint4*)(w2s + tid * 16);
    uint4 p1 = *(const uint4*)(w2s + tid * 16 + 8);
    __syncthreads();   // hpad ready

    const int i0 = wid * 32;
    const int nn = lane & 31, hh = lane >> 5;

    // --- conv2 MFMA: D[e=32(8 valid), i=128] over K = 24ch x 128 ---
    f32x16 acc2;
#pragma unroll
    for (int r = 0; r < 16; ++r) acc2[r] = 0.0f;

    for (int c = 0; c < INTER; ++c) {
        const int buf = c & 1;
        *(uint4*)(&aw[buf][tid * 16])     = p0;
        *(uint4*)(&aw[buf][tid * 16 + 8]) = p1;
        if (c < INTER - 1) {
            p0 = *(const uint4*)(w2s + (c + 1) * 4096 + tid * 16);
            p1 = *(const uint4*)(w2s + (c + 1) * 4096 + tid * 16 + 8);
        }
        __syncthreads();
        const short* bbase = hpad + c * 256 + i0 + nn + hh * 8;
        const short* abase = &aw[buf][lane * 8];
#pragma unroll
        for (int kc = 0; kc < 8; ++kc) {
            s16x8 af = *(const s16x8*)(abase + kc * 512);
            s16x8 bf;
#pragma unroll
            for (int j = 0; j < 8; ++j) bf[j] = bbase[kc * 16 + j];
            acc2 = __builtin_amdgcn_mfma_f32_32x32x16_bf16(af, bf, acc2, 0, 0, 0);
        }
        __syncthreads();
    }

    // --- conv2 epilogue: rows e<8 live in regs 0..3 (e = (r&3)+4*hh) ---
    {
        const int i = i0 + nn;
#pragma unroll
        for (int r = 0; r < 4; ++r) {
            int e = r + 4 * hh;
            if (i < TLEN) lat[e * 122 + i] = acc2[r] + b2[e];
        }
    }
    __syncthreads();

    // --- DFT bins 1..60: power sums for f and a ---
    for (int q = tid; q < 480; q += 256) {
        int e_ = q / 60, k = q - e_ * 60 + 1;
        float re = 0.0f, im = 0.0f;
        int m = 0;
        for (int t = 0; t < TLEN; ++t) {
            float v = lat[e_ * 122 + t];
            float2 cs = tw[m];
            re += v * cs.x;
            im -= v * cs.y;
            m += k; m -= (m >= 121) ? 121 : 0;
        }
        float pw = re * re + im * im;
        atomicAdd(&S0[e_], pw);
        atomicAdd(&S1[e_], pw * (0.5f * (float)k));   // FREQS[k-1] = k/2
    }
    // --- fc ---
    if (tid < 16) {
        int e_ = tid >> 1, kk = tid & 1;
        float accv = fcb[e_ * 2 + kk];
        const float* fr = fcw + (e_ * 2 + kk) * TLEN;
        for (int t = 0; t < TLEN; ++t) accv += lat[e_ * 122 + t] * fr[t];
        vv[tid] = accv;
    }
    // --- b = mean(latent) ---
    if (tid >= 32 && tid < 40) {
        int e_ = tid - 32;
        float s = 0.0f;
        for (int t = 0; t < TLEN; ++t) s += lat[e_ * 122 + t];
        bm[e_] = s * (1.0f / 121.0f);
    }
    __syncthreads();

    if (tid < 8) {
        int e_ = tid;
        float fv = S1[e_] / S0[e_];
        float av = 2.0f * sqrtf(S0[e_]) * (1.0f / 121.0f);
        float pv = atan2f(vv[2 * e_ + 1], vv[2 * e_]) * 0.15915494309189535f;
        float bv = bm[e_];
        int gi = w * 8 + e_;
        pP[gi] = pv; pF[gi] = fv; pA[gi] = av; pB[gi] = bv;
        if (n == 0) {
            oP[b * 8 + e_] = pv;
            oF[b * 8 + e_] = fv;
            oA[b * 8 + e_] = av;
            oB[b * 8 + e_] = bv;
        }
    }
    if (n == 0) {
        for (int idx = tid; idx < EMB * TLEN; idx += 256) {
            int e_ = idx / TLEN, i = idx - e_ * TLEN;
            oLat[(b * EMB + e_) * TLEN + i] = lat[e_ * 122 + i];
        }
    }
}

// ---------------------------------------------------------------------------
// Kernel 2: sinusoid resynthesis + overlap-add, gather form (no atomics).
// ---------------------------------------------------------------------------
__global__ __launch_bounds__(256) void k_signal(
    const float* __restrict__ pP, const float* __restrict__ pF,
    const float* __restrict__ pA, const float* __restrict__ pB,
    float* __restrict__ sig, float* __restrict__ oSig)
{
    const int blk = blockIdx.x;
    const int b = blk >> 3, e = blk & 7;
    const int tid = threadIdx.x;
    __shared__ float sp[FULL], sf[FULL], sa[FULL], sb[FULL];
    for (int nn = tid; nn < FULL; nn += 256) {
        int gi = (b * FULL + nn) * 8 + e;
        sp[nn] = pP[gi]; sf[nn] = pF[gi]; sa[nn] = pA[gi]; sb[nn] = pB[gi];
    }
    __syncthreads();
    for (int u = tid; u < LP; u += 256) {
        int nlo = (u - 120 > 0) ? (u - 120) : 0;
        int nhi = (u < 239) ? u : 239;
        float s = 0.0f;
        for (int nn = nlo; nn <= nhi; ++nn) {
            float tt = (float)(u - nn);
            float z = sf[nn] * (tt * (1.0f / 60.0f) - 1.0f) + sp[nn];
            z -= floorf(z);
            s += sa[nn] * sinf(6.2831853071795864f * z) + sb[nn];
        }
        float wgt = (u < TLEN) ? (float)(u + 1) : ((u > 239) ? (float)(LP - u) : 121.0f);
        float val = s / wgt;
        sig[(b * EMB + e) * LP + u] = val;
        if (u < TLEN) oSig[(b * EMB + e) * TLEN + u] = val;
    }
}

// ---------------------------------------------------------------------------
// k_dec1: decoder conv1, sliding-float4-window. Block = (b,o), 384 x 64 thr.
// Thread t<60 computes outputs i = 4t..4t+3. Per 4 taps: 1 ds_read_b128 +
// 4 scalar weight loads + 16 FMA. BN sums via wave reduce + 2 atomics.
// ---------------------------------------------------------------------------
__global__ __launch_bounds__(64) void k_dec1(
    const float* __restrict__ sig, const float* __restrict__ dw1, const float* __restrict__ db1,
    float* __restrict__ dbuf, float* __restrict__ bns)
{
    const int blk = blockIdx.x;            // b*24 + o
    const int b = blk / INTER, o = blk - b * INTER;
    const int tid = threadIdx.x;
    __shared__ __align__(16) float ycp[EMB * 364];   // 11648 B
    for (int idx = tid; idx < EMB * 364; idx += 64) {
        int c = idx / 364, q = idx - c * 364;
        float v = 0.0f;
        if (q >= 60 && q < 300) v = sig[(b * EMB + c) * LP + q];
        ycp[idx] = v;
    }
    __syncthreads();
    const int te = (tid < 60) ? tid : 59;  // clamp; lanes >=60 masked at store
    const float bias = db1[o];
    float a0 = bias, a1 = bias, a2 = bias, a3 = bias;
    for (int c = 0; c < EMB; ++c) {
        const float* wr = dw1 + (o * EMB + c) * TLEN;
        const float* base = ycp + c * 364 + 4 * te;
        float4 cur = *(const float4*)base;
        for (int kb = 0; kb < 30; ++kb) {
            float4 nxt = *(const float4*)(base + 4 * kb + 4);
            float w0 = wr[4*kb], w1 = wr[4*kb+1], w2 = wr[4*kb+2], w3 = wr[4*kb+3];
            a0 += w0*cur.x; a1 += w0*cur.y; a2 += w0*cur.z; a3 += w0*cur.w;
            a0 += w1*cur.y; a1 += w1*cur.z; a2 += w1*cur.w; a3 += w1*nxt.x;
            a0 += w2*cur.z; a1 += w2*cur.w; a2 += w2*nxt.x; a3 += w2*nxt.y;
            a0 += w3*cur.w; a1 += w3*nxt.x; a2 += w3*nxt.y; a3 += w3*nxt.z;
            cur = nxt;
        }
        float wl = wr[120];                // cur now holds elements 120..123
        a0 += wl*cur.x; a1 += wl*cur.y; a2 += wl*cur.z; a3 += wl*cur.w;
    }
    float s = 0.0f, s2 = 0.0f;
    if (tid < 60) {
        float4* dst = (float4*)(dbuf + (b * INTER + o) * FULL + 4 * tid);
        *dst = make_float4(a0, a1, a2, a3);
        s  = a0 + a1 + a2 + a3;
        s2 = a0*a0 + a1*a1 + a2*a2 + a3*a3;
    }
    for (int d = 32; d > 0; d >>= 1) { s += __shfl_down(s, d); s2 += __shfl_down(s2, d); }
    if (tid == 0) { atomicAdd(&bns[o], s); atomicAdd(&bns[24 + o], s2); }
}

// ---------------------------------------------------------------------------
// k_bn: BN apply (biased var) + tanh into padded global ddp_g[16][24][364].
// ---------------------------------------------------------------------------
__global__ __launch_bounds__(256) void k_bn(
    const float* __restrict__ dbuf, const float* __restrict__ bns,
    const float* __restrict__ gma, const float* __restrict__ bta,
    float* __restrict__ ddp_g)
{
    int gid = blockIdx.x * 256 + threadIdx.x;        // < 16*24*364 = 139776
    if (gid >= 16 * INTER * 364) return;
    int q = gid % 364, bc = gid / 364, c = bc % INTER;
    float m  = bns[c] * (1.0f / 3840.0f);
    float v  = bns[24 + c] * (1.0f / 3840.0f) - m * m;
    float rs = rsqrtf(fmaxf(v, 0.0f) + 1e-5f);
    float scl = rs * gma[c];
    float sft = bta[c] - m * scl;
    float val = 0.0f;
    if (q >= 60 && q < 300) val = tanhf(dbuf[bc * FULL + (q - 60)] * scl + sft);
    ddp_g[gid] = val;
}

// ---------------------------------------------------------------------------
// k_dec2: decoder conv2, sliding-float4-window. Block = (b,oc), 1152 x 64 thr.
// Stages 24x364 tanh'd tile (34.9 KB LDS) via uint4; thread t<60 computes
// outputs i = 4t..4t+3. Writes y_out and yplot.
// ---------------------------------------------------------------------------
__global__ __launch_bounds__(64) void k_dec2(
    const float* __restrict__ ddp_g, const float* __restrict__ dw2, const float* __restrict__ db2,
    float* __restrict__ oY, float* __restrict__ oYp)
{
    const int blk = blockIdx.x;            // b*72 + oc
    const int b = blk / INCH, oc = blk - b * INCH;
    const int tid = threadIdx.x;
    __shared__ __align__(16) float sdp[INTER * 364]; // 34944 B
    const uint4* src = (const uint4*)(ddp_g + b * (INTER * 364));
    for (int idx = tid; idx < INTER * 364 / 4; idx += 64)
        ((uint4*)sdp)[idx] = src[idx];
    __syncthreads();
    const int te = (tid < 60) ? tid : 59;
    const float bias = db2[oc];
    float a0 = bias, a1 = bias, a2 = bias, a3 = bias;
    for (int c = 0; c < INTER; ++c) {
        const float* wr = dw2 + (oc * INTER + c) * TLEN;
        const float* base = sdp + c * 364 + 4 * te;
        float4 cur = *(const float4*)base;
        for (int kb = 0; kb < 30; ++kb) {
            float4 nxt = *(const float4*)(base + 4 * kb + 4);
            float w0 = wr[4*kb], w1 = wr[4*kb+1], w2 = wr[4*kb+2], w3 = wr[4*kb+3];
            a0 += w0*cur.x; a1 += w0*cur.y; a2 += w0*cur.z; a3 += w0*cur.w;
            a0 += w1*cur.y; a1 += w1*cur.z; a2 += w1*cur.w; a3 += w1*nxt.x;
            a0 += w2*cur.z; a1 += w2*cur.w; a2 += w2*nxt.x; a3 += w2*nxt.y;
            a0 += w3*cur.w; a1 += w3*nxt.x; a2 += w3*nxt.y; a3 += w3*nxt.z;
            cur = nxt;
        }
        float wl = wr[120];
        a0 += wl*cur.x; a1 += wl*cur.y; a2 += wl*cur.z; a3 += wl*cur.w;
    }
    if (tid < 60) {
        const int i = 4 * tid;
        float4* dst = (float4*)(oY + (b * INCH + oc) * FULL + i);
        *dst = make_float4(a0, a1, a2, a3);
        float* yp = oYp + (b * INCH + oc) * TLEN;
        if (i     < TLEN) yp[i]     = a0;
        if (i + 1 < TLEN) yp[i + 1] = a1;
        if (i + 2 < TLEN) yp[i + 2] = a2;
        if (i + 3 < TLEN) yp[i + 3] = a3;
    }
}

// ---------------------------------------------------------------------------
extern "C" void kernel_launch(void* const* d_in, const int* in_sizes, int n_in,
                              void* d_out, int out_size, void* d_ws, size_t ws_size,
                              hipStream_t stream)
{
    const float* x   = (const float*)d_in[0];
    const float* w1  = (const float*)d_in[1];
    const float* b1  = (const float*)d_in[2];
    const float* lna = (const float*)d_in[3];
    const float* lnb = (const float*)d_in[4];
    const float* w2  = (const float*)d_in[5];
    const float* b2  = (const float*)d_in[6];
    const float* fcw = (const float*)d_in[7];
    const float* fcb = (const float*)d_in[8];
    const float* dw1 = (const float*)d_in[9];
    const float* db1 = (const float*)d_in[10];
    const float* gma = (const float*)d_in[11];
    const float* bta = (const float*)d_in[12];
    const float* dw2 = (const float*)d_in[13];
    const float* db2 = (const float*)d_in[14];

    // Output layout (flat fp32, reference return order):
    float* out  = (float*)d_out;
    float* oY   = out;                 // [16][72][240]
    float* oLat = out + 276480;        // [16][8][121]
    float* oSig = out + 291968;        // [16][8][121]
    float* oP   = out + 307456;
    float* oF   = out + 307584;
    float* oA   = out + 307712;
    float* oB   = out + 307840;
    float* oYp  = out + 307968;        // [16][72][121]

    // Workspace layout (bytes; ws_size proven >= 46.4 MB by round 6):
    //   [0, 196608)            w2s bf16 swizzled
    //   [196608, 872640)       fp32: pP/pF/pA/pB (overlaid by dbuf), sig, bns
    //   [872640, 1431744)      ddp_g [16][24][364] fp32 (BN+tanh precompute)
    //   [1431744, 46405824)    R prefix table [384][122][240] fp32
    short* w2s  = (short*)d_ws;
    float* fb   = (float*)((char*)d_ws + 196608);
    float* pP   = fb;
    float* pF   = pP + 30720;
    float* pA   = pF + 30720;
    float* pB   = pA + 30720;
    float* dbuf = fb;                  // overlay (temporally disjoint)
    float* sig  = fb + 122880;
    float* bns  = sig + 46080;
    float* ddp_g = (float*)((char*)d_ws + 872640);
    float* R    = (float*)((char*)d_ws + 1431744);

    hipMemsetAsync(bns, 0, 48 * sizeof(float), stream);
    k_prep_w2<<<384, 256, 0, stream>>>(w2, w2s);
    k_qr<<<384, 256, 0, stream>>>(x, w1, R);
    k_enc_pref<<<NWIN, 256, 0, stream>>>(R, b1, lna, lnb, w2s, b2, fcw, fcb,
                                         pP, pF, pA, pB, oLat, oP, oF, oA, oB);
    k_signal<<<128, 256, 0, stream>>>(pP, pF, pA, pB, sig, oSig);
    k_dec1<<<384, 64, 0, stream>>>(sig, dw1, db1, dbuf, bns);
    k_bn<<<(16 * INTER * 364 + 255) / 256, 256, 0, stream>>>(dbuf, bns, gma, bta, ddp_g);
    k_dec2<<<16 * INCH, 64, 0, stream>>>(ddp_g, dw2, db2, oY, oYp);
}

// Round 8
// 591.650 us; speedup vs baseline: 14.2901x; 1.5072x over previous
//
#include <hip/hip_runtime.h>
#include <math.h>

// ---------------------------------------------------------------------------
// PAE pipeline on MI355X. Round 8: split encoder into
//   k_qr (prefix table R, unchanged) ->
//   k_gather_ln (coalesced R-tile stage, conv1 diff + LN + tanh -> bf16 h3,
//                h3 overlays the block's own dead R tile) ->
//   k_enc2 (per-window: hT[pos][c] in LDS, conv2 = tap-loop MFMA 16x16x32
//           contracting over c with aligned ds_read_b128 A-fragments and
//           per-tap weight fragments streamed from L2; DFT/fc epilogues).
// Round-7 diagnosis: conv2's 64 ds_read_u16/ch/wave (~280 us LDS issue) and
// scattered anti-diagonal R reads (185 MB @ 341 GB/s) dominated k_enc_pref.
// ---------------------------------------------------------------------------

#define INCH   72
#define TLEN   121
#define FULL   240
#define INTER  24
#define EMB    8
#define LP     360
#define NWIN   3840

typedef __attribute__((ext_vector_type(8)))  short s16x8;
typedef __attribute__((ext_vector_type(4)))  float f32x4;

// fp32 -> bf16 (RNE) as raw ushort
__device__ __forceinline__ unsigned short f2bf(float f) {
    unsigned u = __float_as_uint(f);
    unsigned r = ((u >> 16) & 1u) + 0x7FFFu;
    return (unsigned short)((u + r) >> 16);
}

// ---------------------------------------------------------------------------
// w2 fragment prep: w2f[tap][lane][j] = w2[e=lane&15][c=(lane>>4)*8+j][tap],
// zero-padded for e>=8, c>=24. B-fragment of mfma_f32_16x16x32_bf16.
// ---------------------------------------------------------------------------
__global__ __launch_bounds__(256) void k_prep_w2f(const float* __restrict__ w2,
                                                  short* __restrict__ w2f) {
    int idx = blockIdx.x * 256 + threadIdx.x;       // < 121*64*8 = 61952
    if (idx >= 61952) return;
    int j = idx & 7, ln = (idx >> 3) & 63, tap = idx >> 9;
    int e = ln & 15, c = (ln >> 4) * 8 + j;
    float v = (e < EMB && c < INTER) ? w2[(e * INTER + c) * TLEN + tap] : 0.0f;
    w2f[idx] = (short)f2bf(v);
}

// ---------------------------------------------------------------------------
// k_qr: Q + exclusive prefix R, fused. Block = (b,o) (384 blocks).
// R[blk][m][s], m in [0,121], s in [0,240): R[m] = sum_{m'<m} Q[m'].
// ---------------------------------------------------------------------------
__global__ __launch_bounds__(256) void k_qr(
    const float* __restrict__ x, const float* __restrict__ w1,
    float* __restrict__ R)
{
    const int blk = blockIdx.x;          // b*24 + o
    const int b = blk / INTER, o = blk - b * INTER;
    const int tid = threadIdx.x;
    __shared__ float xs[INCH * FULL];    // 69120 B
    for (int idx = tid; idx < INCH * FULL; idx += 256)
        xs[idx] = x[b * INCH * FULL + idx];
    __syncthreads();
    if (tid >= FULL) return;             // no further barriers below
    const int s = tid;
    const float* wq = w1 + o * (INCH * TLEN);
    float* Rb = R + (size_t)blk * (122 * FULL);
    Rb[s] = 0.0f;
    float P = 0.0f;
    for (int m = 0; m < TLEN; ++m) {
        int idxm = s + m;
        idxm -= (idxm >= FULL) ? FULL : 0;
        float q = 0.0f;
        for (int c = 0; c < INCH; ++c)
            q += wq[c * TLEN + m] * xs[c * FULL + idxm];
        P += q;
        Rb[(m + 1) * FULL + s] = P;
    }
}

// ---------------------------------------------------------------------------
// k_gather_ln: block = (b,o). Stage R tile coalesced into LDS, then per n:
// two-pass conv1-diff -> LN(ddof=1, /(std+eps)) -> tanh -> bf16, written to
// h3[blk][n][i] which OVERLAYS this block's own R tile (dead after staging).
// ---------------------------------------------------------------------------
__global__ __launch_bounds__(256) void k_gather_ln(
    float* __restrict__ R, const float* __restrict__ b1,
    const float* __restrict__ lna, const float* __restrict__ lnb)
{
    const int blk = blockIdx.x;          // b*24 + o
    const int o = blk % INTER;
    const int tid = threadIdx.x;
    __shared__ float Rt[122 * FULL];     // 117120 B
    float* Rg = R + (size_t)blk * (122 * FULL);
    for (int idx = tid; idx < (122 * FULL) / 4; idx += 256)
        ((float4*)Rt)[idx] = ((const float4*)Rg)[idx];
    __syncthreads();
    if (tid >= FULL) return;             // no further barriers below
    const int n = tid;
    const float bias = b1[o];
    float s = 0.0f, s2 = 0.0f;
    for (int i = 0; i < TLEN; ++i) {
        int st = n + i - 120; st += (st < 0) ? FULL : 0;
        float v = (i <= 60) ? (Rt[121 * FULL + st] - Rt[(60 - i) * FULL + st])
                            : Rt[(181 - i) * FULL + st];
        v += bias;
        s += v; s2 += v * v;
    }
    float mean = s * (1.0f / 121.0f);
    float var  = fmaxf((s2 - s * mean) * (1.0f / 120.0f), 0.0f);   // ddof=1
    float inv  = 1.0f / (sqrtf(var) + 1e-5f);                      // (std+eps)
    unsigned short* dst = (unsigned short*)Rg + n * TLEN;          // overlay
    for (int i = 0; i < TLEN; ++i) {
        int st = n + i - 120; st += (st < 0) ? FULL : 0;
        float v = (i <= 60) ? (Rt[121 * FULL + st] - Rt[(60 - i) * FULL + st])
                            : Rt[(181 - i) * FULL + st];
        v += bias;
        v = (v - mean) * inv * lna[i] + lnb[i];
        dst[i] = f2bf(tanhf(v));
    }
}

// ---------------------------------------------------------------------------
// k_enc2: per-window conv2 MFMA + DFT/fc/b epilogues. 3840 blocks x 256 thr.
// hT[pos][c]: 256 rows x 32 c (bf16), rows [60,181) valid, rest zero.
// latent[e][i] = sum_tap sum_c w2[e][c][tap] * hT[i+tap][c]:
// per tap, per 16-wide i-tile: D[i][e] += A[i][c] * B[c][e], K=32 (c padded).
// A-fragment = aligned ds_read_b128; B streamed from w2f (global, L2-hot).
// LDS ~22 KB. No barriers inside the tap loop.
// ---------------------------------------------------------------------------
__global__ __launch_bounds__(256) void k_enc2(
    const float* __restrict__ R, const short* __restrict__ w2f,
    const float* __restrict__ b2,
    const float* __restrict__ fcw, const float* __restrict__ fcb,
    float* __restrict__ pP, float* __restrict__ pF, float* __restrict__ pA, float* __restrict__ pB,
    float* __restrict__ oLat, float* __restrict__ oP, float* __restrict__ oF,
    float* __restrict__ oA, float* __restrict__ oB)
{
    const int w   = blockIdx.x;
    const int b   = w / FULL, n = w - b * FULL;
    const int tid = threadIdx.x;
    const int lane = tid & 63, wid = tid >> 6;

    __shared__ __align__(16) short hT[256 * 32];   // 16384 B
    __shared__ float lat[EMB * 122];               // 3904 B
    __shared__ float2 tw[121];
    __shared__ float S0[8], S1[8], vv[16], bm[8];

    // zero hT (covers pad rows/cols), trig table, S init
    for (int idx = tid; idx < 1024; idx += 256) ((uint4*)hT)[idx] = make_uint4(0,0,0,0);
    if (tid < TLEN) {
        float s, c;
        sincosf(6.2831853071795864f * (float)tid / 121.0f, &s, &c);
        tw[tid] = make_float2(c, s);
    }
    if (tid < 8) { S0[tid] = 0.0f; S1[tid] = 0.0f; }
    __syncthreads();

    // fill hT[60+i][o] from h3 (bf16, overlaid on R tiles)
    for (int idx = tid; idx < INTER * TLEN; idx += 256) {
        int o = idx / TLEN, i = idx - o * TLEN;
        const unsigned short* h3 =
            (const unsigned short*)(R + (size_t)(b * INTER + o) * (122 * FULL)) + n * TLEN;
        hT[(60 + i) * 32 + o] = (short)h3[i];
    }
    __syncthreads();

    // --- conv2 MFMA: 2 i-tiles per wave, 121 taps, K=32 over c ---
    const int m = lane & 15, quad = lane >> 4;
    const int t0 = wid * 32;
    f32x4 acc0 = {0.0f, 0.0f, 0.0f, 0.0f};
    f32x4 acc1 = {0.0f, 0.0f, 0.0f, 0.0f};
    s16x8 bcur = *(const s16x8*)(w2f + lane * 8);
    for (int tap = 0; tap < TLEN; ++tap) {
        s16x8 bnxt = bcur;
        if (tap < TLEN - 1) bnxt = *(const s16x8*)(w2f + (tap + 1) * 512 + lane * 8);
        s16x8 a0 = *(const s16x8*)(hT + (t0 + m + tap) * 32 + quad * 8);
        s16x8 a1 = *(const s16x8*)(hT + (t0 + 16 + m + tap) * 32 + quad * 8);
        acc0 = __builtin_amdgcn_mfma_f32_16x16x32_bf16(a0, bcur, acc0, 0, 0, 0);
        acc1 = __builtin_amdgcn_mfma_f32_16x16x32_bf16(a1, bcur, acc1, 0, 0, 0);
        bcur = bnxt;
    }
    // epilogue: C/D col=lane&15 (=e), row=(lane>>4)*4+r (=i within tile)
    {
        const int e = lane & 15;
        if (e < EMB) {
            float bias = b2[e];
#pragma unroll
            for (int r = 0; r < 4; ++r) {
                int i0v = t0 + quad * 4 + r;
                if (i0v < TLEN) lat[e * 122 + i0v] = acc0[r] + bias;
                int i1v = t0 + 16 + quad * 4 + r;
                if (i1v < TLEN) lat[e * 122 + i1v] = acc1[r] + bias;
            }
        }
    }
    __syncthreads();

    // --- DFT bins 1..60: power sums for f and a ---
    for (int q = tid; q < 480; q += 256) {
        int e_ = q / 60, k = q - e_ * 60 + 1;
        float re = 0.0f, im = 0.0f;
        int mm = 0;
        for (int t = 0; t < TLEN; ++t) {
            float v = lat[e_ * 122 + t];
            float2 cs = tw[mm];
            re += v * cs.x;
            im -= v * cs.y;
            mm += k; mm -= (mm >= 121) ? 121 : 0;    // k*t mod 121
        }
        float pw = re * re + im * im;
        atomicAdd(&S0[e_], pw);
        atomicAdd(&S1[e_], pw * (0.5f * (float)k));  // FREQS[k-1] = k/2
    }
    // --- fc ---
    if (tid < 16) {
        int e_ = tid >> 1, kk = tid & 1;
        float accv = fcb[e_ * 2 + kk];
        const float* fr = fcw + (e_ * 2 + kk) * TLEN;
        for (int t = 0; t < TLEN; ++t) accv += lat[e_ * 122 + t] * fr[t];
        vv[tid] = accv;
    }
    // --- b = mean(latent) ---
    if (tid >= 32 && tid < 40) {
        int e_ = tid - 32;
        float s = 0.0f;
        for (int t = 0; t < TLEN; ++t) s += lat[e_ * 122 + t];
        bm[e_] = s * (1.0f / 121.0f);
    }
    __syncthreads();

    if (tid < 8) {
        int e_ = tid;
        float fv = S1[e_] / S0[e_];
        float av = 2.0f * sqrtf(S0[e_]) * (1.0f / 121.0f);
        float pv = atan2f(vv[2 * e_ + 1], vv[2 * e_]) * 0.15915494309189535f;
        float bv = bm[e_];
        int gi = w * 8 + e_;
        pP[gi] = pv; pF[gi] = fv; pA[gi] = av; pB[gi] = bv;
        if (n == 0) {
            oP[b * 8 + e_] = pv;
            oF[b * 8 + e_] = fv;
            oA[b * 8 + e_] = av;
            oB[b * 8 + e_] = bv;
        }
    }
    if (n == 0) {
        for (int idx = tid; idx < EMB * TLEN; idx += 256) {
            int e_ = idx / TLEN, i = idx - e_ * TLEN;
            oLat[(b * EMB + e_) * TLEN + i] = lat[e_ * 122 + i];
        }
    }
}

// ---------------------------------------------------------------------------
// Kernel: sinusoid resynthesis + overlap-add, gather form (no atomics).
// ---------------------------------------------------------------------------
__global__ __launch_bounds__(256) void k_signal(
    const float* __restrict__ pP, const float* __restrict__ pF,
    const float* __restrict__ pA, const float* __restrict__ pB,
    float* __restrict__ sig, float* __restrict__ oSig)
{
    const int blk = blockIdx.x;
    const int b = blk >> 3, e = blk & 7;
    const int tid = threadIdx.x;
    __shared__ float sp[FULL], sf[FULL], sa[FULL], sb[FULL];
    for (int nn = tid; nn < FULL; nn += 256) {
        int gi = (b * FULL + nn) * 8 + e;
        sp[nn] = pP[gi]; sf[nn] = pF[gi]; sa[nn] = pA[gi]; sb[nn] = pB[gi];
    }
    __syncthreads();
    for (int u = tid; u < LP; u += 256) {
        int nlo = (u - 120 > 0) ? (u - 120) : 0;
        int nhi = (u < 239) ? u : 239;
        float s = 0.0f;
        for (int nn = nlo; nn <= nhi; ++nn) {
            float tt = (float)(u - nn);
            float z = sf[nn] * (tt * (1.0f / 60.0f) - 1.0f) + sp[nn];
            z -= floorf(z);
            s += sa[nn] * sinf(6.2831853071795864f * z) + sb[nn];
        }
        float wgt = (u < TLEN) ? (float)(u + 1) : ((u > 239) ? (float)(LP - u) : 121.0f);
        float val = s / wgt;
        sig[(b * EMB + e) * LP + u] = val;
        if (u < TLEN) oSig[(b * EMB + e) * TLEN + u] = val;
    }
}

// ---------------------------------------------------------------------------
// k_dec1: decoder conv1, sliding-float4-window. Block = (b,o), 384 x 64 thr.
// ---------------------------------------------------------------------------
__global__ __launch_bounds__(64) void k_dec1(
    const float* __restrict__ sig, const float* __restrict__ dw1, const float* __restrict__ db1,
    float* __restrict__ dbuf, float* __restrict__ bns)
{
    const int blk = blockIdx.x;            // b*24 + o
    const int b = blk / INTER, o = blk - b * INTER;
    const int tid = threadIdx.x;
    __shared__ __align__(16) float ycp[EMB * 364];   // 11648 B
    for (int idx = tid; idx < EMB * 364; idx += 64) {
        int c = idx / 364, q = idx - c * 364;
        float v = 0.0f;
        if (q >= 60 && q < 300) v = sig[(b * EMB + c) * LP + q];
        ycp[idx] = v;
    }
    __syncthreads();
    const int te = (tid < 60) ? tid : 59;  // clamp; lanes >=60 masked at store
    const float bias = db1[o];
    float a0 = bias, a1 = bias, a2 = bias, a3 = bias;
    for (int c = 0; c < EMB; ++c) {
        const float* wr = dw1 + (o * EMB + c) * TLEN;
        const float* base = ycp + c * 364 + 4 * te;
        float4 cur = *(const float4*)base;
        for (int kb = 0; kb < 30; ++kb) {
            float4 nxt = *(const float4*)(base + 4 * kb + 4);
            float w0 = wr[4*kb], w1 = wr[4*kb+1], w2 = wr[4*kb+2], w3 = wr[4*kb+3];
            a0 += w0*cur.x; a1 += w0*cur.y; a2 += w0*cur.z; a3 += w0*cur.w;
            a0 += w1*cur.y; a1 += w1*cur.z; a2 += w1*cur.w; a3 += w1*nxt.x;
            a0 += w2*cur.z; a1 += w2*cur.w; a2 += w2*nxt.x; a3 += w2*nxt.y;
            a0 += w3*cur.w; a1 += w3*nxt.x; a2 += w3*nxt.y; a3 += w3*nxt.z;
            cur = nxt;
        }
        float wl = wr[120];
        a0 += wl*cur.x; a1 += wl*cur.y; a2 += wl*cur.z; a3 += wl*cur.w;
    }
    float s = 0.0f, s2 = 0.0f;
    if (tid < 60) {
        float4* dst = (float4*)(dbuf + (b * INTER + o) * FULL + 4 * tid);
        *dst = make_float4(a0, a1, a2, a3);
        s  = a0 + a1 + a2 + a3;
        s2 = a0*a0 + a1*a1 + a2*a2 + a3*a3;
    }
    for (int d = 32; d > 0; d >>= 1) { s += __shfl_down(s, d); s2 += __shfl_down(s2, d); }
    if (tid == 0) { atomicAdd(&bns[o], s); atomicAdd(&bns[24 + o], s2); }
}

// ---------------------------------------------------------------------------
// k_bn: BN apply (biased var) + tanh into padded global ddp_g[16][24][364].
// ---------------------------------------------------------------------------
__global__ __launch_bounds__(256) void k_bn(
    const float* __restrict__ dbuf, const float* __restrict__ bns,
    const float* __restrict__ gma, const float* __restrict__ bta,
    float* __restrict__ ddp_g)
{
    int gid = blockIdx.x * 256 + threadIdx.x;        // < 16*24*364 = 139776
    if (gid >= 16 * INTER * 364) return;
    int q = gid % 364, bc = gid / 364, c = bc % INTER;
    float m  = bns[c] * (1.0f / 3840.0f);
    float v  = bns[24 + c] * (1.0f / 3840.0f) - m * m;
    float rs = rsqrtf(fmaxf(v, 0.0f) + 1e-5f);
    float scl = rs * gma[c];
    float sft = bta[c] - m * scl;
    float val = 0.0f;
    if (q >= 60 && q < 300) val = tanhf(dbuf[bc * FULL + (q - 60)] * scl + sft);
    ddp_g[gid] = val;
}

// ---------------------------------------------------------------------------
// k_dec2: decoder conv2, sliding-float4-window. Block = (b,oc), 1152 x 64 thr.
// ---------------------------------------------------------------------------
__global__ __launch_bounds__(64) void k_dec2(
    const float* __restrict__ ddp_g, const float* __restrict__ dw2, const float* __restrict__ db2,
    float* __restrict__ oY, float* __restrict__ oYp)
{
    const int blk = blockIdx.x;            // b*72 + oc
    const int b = blk / INCH, oc = blk - b * INCH;
    const int tid = threadIdx.x;
    __shared__ __align__(16) float sdp[INTER * 364]; // 34944 B
    const uint4* src = (const uint4*)(ddp_g + b * (INTER * 364));
    for (int idx = tid; idx < INTER * 364 / 4; idx += 64)
        ((uint4*)sdp)[idx] = src[idx];
    __syncthreads();
    const int te = (tid < 60) ? tid : 59;
    const float bias = db2[oc];
    float a0 = bias, a1 = bias, a2 = bias, a3 = bias;
    for (int c = 0; c < INTER; ++c) {
        const float* wr = dw2 + (oc * INTER + c) * TLEN;
        const float* base = sdp + c * 364 + 4 * te;
        float4 cur = *(const float4*)base;
        for (int kb = 0; kb < 30; ++kb) {
            float4 nxt = *(const float4*)(base + 4 * kb + 4);
            float w0 = wr[4*kb], w1 = wr[4*kb+1], w2 = wr[4*kb+2], w3 = wr[4*kb+3];
            a0 += w0*cur.x; a1 += w0*cur.y; a2 += w0*cur.z; a3 += w0*cur.w;
            a0 += w1*cur.y; a1 += w1*cur.z; a2 += w1*cur.w; a3 += w1*nxt.x;
            a0 += w2*cur.z; a1 += w2*cur.w; a2 += w2*nxt.x; a3 += w2*nxt.y;
            a0 += w3*cur.w; a1 += w3*nxt.x; a2 += w3*nxt.y; a3 += w3*nxt.z;
            cur = nxt;
        }
        float wl = wr[120];
        a0 += wl*cur.x; a1 += wl*cur.y; a2 += wl*cur.z; a3 += wl*cur.w;
    }
    if (tid < 60) {
        const int i = 4 * tid;
        float4* dst = (float4*)(oY + (b * INCH + oc) * FULL + i);
        *dst = make_float4(a0, a1, a2, a3);
        float* yp = oYp + (b * INCH + oc) * TLEN;
        if (i     < TLEN) yp[i]     = a0;
        if (i + 1 < TLEN) yp[i + 1] = a1;
        if (i + 2 < TLEN) yp[i + 2] = a2;
        if (i + 3 < TLEN) yp[i + 3] = a3;
    }
}

// ---------------------------------------------------------------------------
extern "C" void kernel_launch(void* const* d_in, const int* in_sizes, int n_in,
                              void* d_out, int out_size, void* d_ws, size_t ws_size,
                              hipStream_t stream)
{
    const float* x   = (const float*)d_in[0];
    const float* w1  = (const float*)d_in[1];
    const float* b1  = (const float*)d_in[2];
    const float* lna = (const float*)d_in[3];
    const float* lnb = (const float*)d_in[4];
    const float* w2  = (const float*)d_in[5];
    const float* b2  = (const float*)d_in[6];
    const float* fcw = (const float*)d_in[7];
    const float* fcb = (const float*)d_in[8];
    const float* dw1 = (const float*)d_in[9];
    const float* db1 = (const float*)d_in[10];
    const float* gma = (const float*)d_in[11];
    const float* bta = (const float*)d_in[12];
    const float* dw2 = (const float*)d_in[13];
    const float* db2 = (const float*)d_in[14];

    // Output layout (flat fp32, reference return order):
    float* out  = (float*)d_out;
    float* oY   = out;                 // [16][72][240]
    float* oLat = out + 276480;        // [16][8][121]
    float* oSig = out + 291968;        // [16][8][121]
    float* oP   = out + 307456;
    float* oF   = out + 307584;
    float* oA   = out + 307712;
    float* oB   = out + 307840;
    float* oYp  = out + 307968;        // [16][72][121]

    // Workspace layout (bytes; ws_size >= 46,436,544 proven in round 6):
    //   [0, 123904)            w2f bf16 fragments [121][64][8]
    //   [123904, 1359040)      fp32: pP/pF/pA/pB (dbuf overlay), sig, bns, ddp_g
    //   [1359040, 46333120)    R prefix table [384][122][240] fp32;
    //                          h3 bf16 [240][121] overlays each blk's own tile
    short* w2f  = (short*)d_ws;
    float* fb   = (float*)((char*)d_ws + 123904);
    float* pP   = fb;
    float* pF   = pP + 30720;
    float* pA   = pF + 30720;
    float* pB   = pA + 30720;
    float* dbuf = fb;                  // overlay (temporally disjoint)
    float* sig  = fb + 122880;         // 46080
    float* bns  = sig + 46080;         // 48
    float* ddp_g = bns + 48;           // 139776
    float* R    = (float*)((char*)d_ws + 1359040);

    hipMemsetAsync(bns, 0, 48 * sizeof(float), stream);
    k_prep_w2f<<<242, 256, 0, stream>>>(w2, w2f);
    k_qr<<<384, 256, 0, stream>>>(x, w1, R);
    k_gather_ln<<<384, 256, 0, stream>>>(R, b1, lna, lnb);
    k_enc2<<<NWIN, 256, 0, stream>>>(R, w2f, b2, fcw, fcb,
                                     pP, pF, pA, pB, oLat, oP, oF, oA, oB);
    k_signal<<<128, 256, 0, stream>>>(pP, pF, pA, pB, sig, oSig);
    k_dec1<<<384, 64, 0, stream>>>(sig, dw1, db1, dbuf, bns);
    k_bn<<<(16 * INTER * 364 + 255) / 256, 256, 0, stream>>>(dbuf, bns, gma, bta, ddp_g);
    k_dec2<<<16 * INCH, 64, 0, stream>>>(ddp_g, dw2, db2, oY, oYp);
}

// Round 9
// 591.294 us; speedup vs baseline: 14.2987x; 1.0006x over previous
//
#include <hip/hip_runtime.h>
#include <math.h>

// ---------------------------------------------------------------------------
// PAE pipeline on MI355X. Round 9:
//   k_enc2: bank-conflict-free hT (stride 40, 2-stage transpose fill) +
//           DFT/power stats via MFMA against precomputed bf16 trig fragments
//           (w3f) instead of 968 LDS reads + 2.4k VALU per block.
//   k_dec1/k_dec2: weights staged to LDS (SMEM-latency removal).
//   Everything else byte-identical to round 8 (verified, absmax 0.0625).
// ---------------------------------------------------------------------------

#define INCH   72
#define TLEN   121
#define FULL   240
#define INTER  24
#define EMB    8
#define LP     360
#define NWIN   3840

typedef __attribute__((ext_vector_type(8)))  short s16x8;
typedef __attribute__((ext_vector_type(4)))  float f32x4;

// fp32 -> bf16 (RNE) as raw ushort
__device__ __forceinline__ unsigned short f2bf(float f) {
    unsigned u = __float_as_uint(f);
    unsigned r = ((u >> 16) & 1u) + 0x7FFFu;
    return (unsigned short)((u + r) >> 16);
}

// ---------------------------------------------------------------------------
// w2 fragment prep: w2f[tap][lane][j] = w2[e=lane&15][c=(lane>>4)*8+j][tap].
// B-fragment of mfma_f32_16x16x32_bf16 (verified round 8).
// ---------------------------------------------------------------------------
__global__ __launch_bounds__(256) void k_prep_w2f(const float* __restrict__ w2,
                                                  short* __restrict__ w2f) {
    int idx = blockIdx.x * 256 + threadIdx.x;       // < 121*64*8 = 61952
    if (idx >= 61952) return;
    int j = idx & 7, ln = (idx >> 3) & 63, tap = idx >> 9;
    int e = ln & 15, c = (ln >> 4) * 8 + j;
    float v = (e < EMB && c < INTER) ? w2[(e * INTER + c) * TLEN + tap] : 0.0f;
    w2f[idx] = (short)f2bf(v);
}

// ---------------------------------------------------------------------------
// DFT trig fragments: w3f[((ch*8+tl)*64+ln)*8+j], B-frag of 16x16x32.
// k = (tl&3)*16 + (ln&15) + 1 (bin), t = (ln>>4)*8 + j + ch*32 (time).
// tl<4: cos(2*pi*k*t/121); tl>=4: -sin(...). Zero for t>=121 or k>60.
// ---------------------------------------------------------------------------
__global__ __launch_bounds__(256) void k_prep_w3f(short* __restrict__ w3f) {
    int idx = blockIdx.x * 256 + threadIdx.x;       // < 16384
    if (idx >= 16384) return;
    int j = idx & 7, ln = (idx >> 3) & 63, tl = (idx >> 9) & 7, ch = idx >> 12;
    int t = (ln >> 4) * 8 + j + ch * 32;
    int colIdx = (tl & 3) * 16 + (ln & 15);
    int k = colIdx + 1;
    float v = 0.0f;
    if (t < TLEN && colIdx < 60) {
        int mm = (k * t) % 121;
        float s, c;
        sincosf(6.2831853071795864f * (float)mm / 121.0f, &s, &c);
        v = (tl < 4) ? c : -s;
    }
    w3f[idx] = (short)f2bf(v);
}

// ---------------------------------------------------------------------------
// k_qr: Q + exclusive prefix R, fused. Block = (b,o) (384 blocks).
// ---------------------------------------------------------------------------
__global__ __launch_bounds__(256) void k_qr(
    const float* __restrict__ x, const float* __restrict__ w1,
    float* __restrict__ R)
{
    const int blk = blockIdx.x;          // b*24 + o
    const int b = blk / INTER, o = blk - b * INTER;
    const int tid = threadIdx.x;
    __shared__ float xs[INCH * FULL];    // 69120 B
    for (int idx = tid; idx < INCH * FULL; idx += 256)
        xs[idx] = x[b * INCH * FULL + idx];
    __syncthreads();
    if (tid >= FULL) return;
    const int s = tid;
    const float* wq = w1 + o * (INCH * TLEN);
    float* Rb = R + (size_t)blk * (122 * FULL);
    Rb[s] = 0.0f;
    float P = 0.0f;
    for (int m = 0; m < TLEN; ++m) {
        int idxm = s + m;
        idxm -= (idxm >= FULL) ? FULL : 0;
        float q = 0.0f;
        for (int c = 0; c < INCH; ++c)
            q += wq[c * TLEN + m] * xs[c * FULL + idxm];
        P += q;
        Rb[(m + 1) * FULL + s] = P;
    }
}

// ---------------------------------------------------------------------------
// k_gather_ln: conv1 diff + LN + tanh -> bf16 h3 (overlays own R tile).
// ---------------------------------------------------------------------------
__global__ __launch_bounds__(256) void k_gather_ln(
    float* __restrict__ R, const float* __restrict__ b1,
    const float* __restrict__ lna, const float* __restrict__ lnb)
{
    const int blk = blockIdx.x;          // b*24 + o
    const int o = blk % INTER;
    const int tid = threadIdx.x;
    __shared__ float Rt[122 * FULL];     // 117120 B
    float* Rg = R + (size_t)blk * (122 * FULL);
    for (int idx = tid; idx < (122 * FULL) / 4; idx += 256)
        ((float4*)Rt)[idx] = ((const float4*)Rg)[idx];
    __syncthreads();
    if (tid >= FULL) return;
    const int n = tid;
    const float bias = b1[o];
    float s = 0.0f, s2 = 0.0f;
    for (int i = 0; i < TLEN; ++i) {
        int st = n + i - 120; st += (st < 0) ? FULL : 0;
        float v = (i <= 60) ? (Rt[121 * FULL + st] - Rt[(60 - i) * FULL + st])
                            : Rt[(181 - i) * FULL + st];
        v += bias;
        s += v; s2 += v * v;
    }
    float mean = s * (1.0f / 121.0f);
    float var  = fmaxf((s2 - s * mean) * (1.0f / 120.0f), 0.0f);
    float inv  = 1.0f / (sqrtf(var) + 1e-5f);
    unsigned short* dst = (unsigned short*)Rg + n * TLEN;
    for (int i = 0; i < TLEN; ++i) {
        int st = n + i - 120; st += (st < 0) ? FULL : 0;
        float v = (i <= 60) ? (Rt[121 * FULL + st] - Rt[(60 - i) * FULL + st])
                            : Rt[(181 - i) * FULL + st];
        v += bias;
        v = (v - mean) * inv * lna[i] + lnb[i];
        dst[i] = f2bf(tanhf(v));
    }
}

// ---------------------------------------------------------------------------
// k_enc2: per-window conv2 MFMA + DFT-MFMA + fc/b epilogues.
// hT rows stride 40 shorts (80 B, 16B-aligned, bank-stride 20 -> conflict-free)
// latb rows stride 136 shorts (272 B, aligned, conflict-free).
// ---------------------------------------------------------------------------
__global__ __launch_bounds__(256) void k_enc2(
    const float* __restrict__ R, const short* __restrict__ w2f,
    const short* __restrict__ w3f, const float* __restrict__ b2,
    const float* __restrict__ fcw, const float* __restrict__ fcb,
    float* __restrict__ pP, float* __restrict__ pF, float* __restrict__ pA, float* __restrict__ pB,
    float* __restrict__ oLat, float* __restrict__ oP, float* __restrict__ oF,
    float* __restrict__ oA, float* __restrict__ oB)
{
    const int w   = blockIdx.x;
    const int b   = w / FULL, n = w - b * FULL;
    const int tid = threadIdx.x;
    const int lane = tid & 63, wid = tid >> 6;

    __shared__ __align__(16) short hT[248 * 40];     // 19840 B, stride 40
    __shared__ __align__(16) short hs[24 * 132];     // 6336 B (transpose stage)
    __shared__ __align__(16) short latb[16 * 136];   // 4352 B (bf16 latent)
    __shared__ float lat[EMB * 122];                 // 3904 B (fp32 latent)
    __shared__ float S0[8], S1[8], vv[16], bm[8];

    // zero hT and latb
    for (int idx = tid; idx < 1240; idx += 256) ((uint4*)hT)[idx] = make_uint4(0,0,0,0);
    for (int idx = tid; idx < 272;  idx += 256) ((uint4*)latb)[idx] = make_uint4(0,0,0,0);
    if (tid < 8) { S0[tid] = 0.0f; S1[tid] = 0.0f; }

    // stage h3 rows coalesced: hs[o][i]
    for (int idx = tid; idx < INTER * TLEN; idx += 256) {
        int o = idx / TLEN, i = idx - o * TLEN;
        const unsigned short* h3 =
            (const unsigned short*)(R + (size_t)(b * INTER + o) * (122 * FULL)) + n * TLEN;
        hs[o * 132 + i] = (short)h3[i];
    }
    __syncthreads();
    // transpose into hT[(60+i)*40 + o] (conflict-free both sides)
    for (int idx = tid; idx < TLEN * 32; idx += 256) {
        int i = idx >> 5, o = idx & 31;
        short v = (o < INTER) ? hs[o * 132 + i] : (short)0;
        hT[(60 + i) * 40 + o] = v;
    }
    __syncthreads();

    const int m = lane & 15, quad = lane >> 4;
    const int t0 = wid * 32;

    // --- conv2 MFMA: 2 i-tiles per wave, 121 taps, K=32 over c ---
    f32x4 acc0 = {0.0f, 0.0f, 0.0f, 0.0f};
    f32x4 acc1 = {0.0f, 0.0f, 0.0f, 0.0f};
    const short* aptr = hT + (t0 + m) * 40 + quad * 8;
    s16x8 bcur = *(const s16x8*)(w2f + lane * 8);
    for (int tap = 0; tap < TLEN; ++tap) {
        s16x8 bnxt = bcur;
        if (tap < TLEN - 1) bnxt = *(const s16x8*)(w2f + (tap + 1) * 512 + lane * 8);
        s16x8 a0 = *(const s16x8*)(aptr + tap * 40);
        s16x8 a1 = *(const s16x8*)(aptr + (16 + tap) * 40);
        acc0 = __builtin_amdgcn_mfma_f32_16x16x32_bf16(a0, bcur, acc0, 0, 0, 0);
        acc1 = __builtin_amdgcn_mfma_f32_16x16x32_bf16(a1, bcur, acc1, 0, 0, 0);
        bcur = bnxt;
    }
    // epilogue: C/D col=lane&15 (=e), row=quad*4+r (=i in tile)
    {
        const int e = lane & 15;
        if (e < EMB) {
            float bias = b2[e];
#pragma unroll
            for (int r = 0; r < 4; ++r) {
                int i0v = t0 + quad * 4 + r;
                if (i0v < TLEN) {
                    float v = acc0[r] + bias;
                    lat[e * 122 + i0v] = v;
                    latb[e * 136 + i0v] = (short)f2bf(v);
                }
                int i1v = t0 + 16 + quad * 4 + r;
                if (i1v < TLEN) {
                    float v = acc1[r] + bias;
                    lat[e * 122 + i1v] = v;
                    latb[e * 136 + i1v] = (short)f2bf(v);
                }
            }
        }
    }
    __syncthreads();

    // --- DFT via MFMA: wave wid handles bin cols [16*wid,16*wid+16) re+im ---
    {
        f32x4 accR = {0.0f, 0.0f, 0.0f, 0.0f};
        f32x4 accI = {0.0f, 0.0f, 0.0f, 0.0f};
#pragma unroll
        for (int ch = 0; ch < 4; ++ch) {
            s16x8 a  = *(const s16x8*)(latb + (lane & 15) * 136 + quad * 8 + ch * 32);
            s16x8 br = *(const s16x8*)(w3f + (((ch * 8) + wid) * 64 + lane) * 8);
            s16x8 bi = *(const s16x8*)(w3f + (((ch * 8) + 4 + wid) * 64 + lane) * 8);
            accR = __builtin_amdgcn_mfma_f32_16x16x32_bf16(a, br, accR, 0, 0, 0);
            accI = __builtin_amdgcn_mfma_f32_16x16x32_bf16(a, bi, accI, 0, 0, 0);
        }
        const int colj = lane & 15;
        const int col  = wid * 16 + colj;              // bin-1
        const float fw = 0.5f * (float)(col + 1);      // FREQS = k/2
#pragma unroll
        for (int r = 0; r < 4; ++r) {
            float pw = (col < 60) ? (accR[r] * accR[r] + accI[r] * accI[r]) : 0.0f;
            float s1 = pw * fw;
#pragma unroll
            for (int off = 1; off < 16; off <<= 1) {
                pw += __shfl_xor(pw, off);
                s1 += __shfl_xor(s1, off);
            }
            if (colj == 0) {
                int e = quad * 4 + r;                  // rows 8..15 are zero-pad
                if (e < EMB) { atomicAdd(&S0[e], pw); atomicAdd(&S1[e], s1); }
            }
        }
    }
    // --- fc ---
    if (tid < 16) {
        int e_ = tid >> 1, kk = tid & 1;
        float accv = fcb[e_ * 2 + kk];
        const float* fr = fcw + (e_ * 2 + kk) * TLEN;
        for (int t = 0; t < TLEN; ++t) accv += lat[e_ * 122 + t] * fr[t];
        vv[tid] = accv;
    }
    // --- b = mean(latent) ---
    if (tid >= 32 && tid < 40) {
        int e_ = tid - 32;
        float s = 0.0f;
        for (int t = 0; t < TLEN; ++t) s += lat[e_ * 122 + t];
        bm[e_] = s * (1.0f / 121.0f);
    }
    __syncthreads();

    if (tid < 8) {
        int e_ = tid;
        float fv = S1[e_] / S0[e_];
        float av = 2.0f * sqrtf(S0[e_]) * (1.0f / 121.0f);
        float pv = atan2f(vv[2 * e_ + 1], vv[2 * e_]) * 0.15915494309189535f;
        float bv = bm[e_];
        int gi = w * 8 + e_;
        pP[gi] = pv; pF[gi] = fv; pA[gi] = av; pB[gi] = bv;
        if (n == 0) {
            oP[b * 8 + e_] = pv;
            oF[b * 8 + e_] = fv;
            oA[b * 8 + e_] = av;
            oB[b * 8 + e_] = bv;
        }
    }
    if (n == 0) {
        for (int idx = tid; idx < EMB * TLEN; idx += 256) {
            int e_ = idx / TLEN, i = idx - e_ * TLEN;
            oLat[(b * EMB + e_) * TLEN + i] = lat[e_ * 122 + i];
        }
    }
}

// ---------------------------------------------------------------------------
// k_signal: sinusoid resynthesis + overlap-add, gather form.
// ---------------------------------------------------------------------------
__global__ __launch_bounds__(256) void k_signal(
    const float* __restrict__ pP, const float* __restrict__ pF,
    const float* __restrict__ pA, const float* __restrict__ pB,
    float* __restrict__ sig, float* __restrict__ oSig)
{
    const int blk = blockIdx.x;
    const int b = blk >> 3, e = blk & 7;
    const int tid = threadIdx.x;
    __shared__ float sp[FULL], sf[FULL], sa[FULL], sb[FULL];
    for (int nn = tid; nn < FULL; nn += 256) {
        int gi = (b * FULL + nn) * 8 + e;
        sp[nn] = pP[gi]; sf[nn] = pF[gi]; sa[nn] = pA[gi]; sb[nn] = pB[gi];
    }
    __syncthreads();
    for (int u = tid; u < LP; u += 256) {
        int nlo = (u - 120 > 0) ? (u - 120) : 0;
        int nhi = (u < 239) ? u : 239;
        float s = 0.0f;
        for (int nn = nlo; nn <= nhi; ++nn) {
            float tt = (float)(u - nn);
            float z = sf[nn] * (tt * (1.0f / 60.0f) - 1.0f) + sp[nn];
            z -= floorf(z);
            s += sa[nn] * sinf(6.2831853071795864f * z) + sb[nn];
        }
        float wgt = (u < TLEN) ? (float)(u + 1) : ((u > 239) ? (float)(LP - u) : 121.0f);
        float val = s / wgt;
        sig[(b * EMB + e) * LP + u] = val;
        if (u < TLEN) oSig[(b * EMB + e) * TLEN + u] = val;
    }
}

// ---------------------------------------------------------------------------
// k_dec1: decoder conv1, sliding-float4-window; weights staged to LDS.
// ---------------------------------------------------------------------------
__global__ __launch_bounds__(64) void k_dec1(
    const float* __restrict__ sig, const float* __restrict__ dw1, const float* __restrict__ db1,
    float* __restrict__ dbuf, float* __restrict__ bns)
{
    const int blk = blockIdx.x;            // b*24 + o
    const int b = blk / INTER, o = blk - b * INTER;
    const int tid = threadIdx.x;
    __shared__ __align__(16) float ycp[EMB * 364];   // 11648 B
    __shared__ float wds[EMB * TLEN];                // 3872 B
    for (int idx = tid; idx < EMB * 364; idx += 64) {
        int c = idx / 364, q = idx - c * 364;
        float v = 0.0f;
        if (q >= 60 && q < 300) v = sig[(b * EMB + c) * LP + q];
        ycp[idx] = v;
    }
    for (int idx = tid; idx < EMB * TLEN; idx += 64)
        wds[idx] = dw1[o * (EMB * TLEN) + idx];
    __syncthreads();
    const int te = (tid < 60) ? tid : 59;
    const float bias = db1[o];
    float a0 = bias, a1 = bias, a2 = bias, a3 = bias;
    for (int c = 0; c < EMB; ++c) {
        const float* wr = wds + c * TLEN;
        const float* base = ycp + c * 364 + 4 * te;
        float4 cur = *(const float4*)base;
        for (int kb = 0; kb < 30; ++kb) {
            float4 nxt = *(const float4*)(base + 4 * kb + 4);
            float w0 = wr[4*kb], w1 = wr[4*kb+1], w2 = wr[4*kb+2], w3 = wr[4*kb+3];
            a0 += w0*cur.x; a1 += w0*cur.y; a2 += w0*cur.z; a3 += w0*cur.w;
            a0 += w1*cur.y; a1 += w1*cur.z; a2 += w1*cur.w; a3 += w1*nxt.x;
            a0 += w2*cur.z; a1 += w2*cur.w; a2 += w2*nxt.x; a3 += w2*nxt.y;
            a0 += w3*cur.w; a1 += w3*nxt.x; a2 += w3*nxt.y; a3 += w3*nxt.z;
            cur = nxt;
        }
        float wl = wr[120];
        a0 += wl*cur.x; a1 += wl*cur.y; a2 += wl*cur.z; a3 += wl*cur.w;
    }
    float s = 0.0f, s2 = 0.0f;
    if (tid < 60) {
        float4* dst = (float4*)(dbuf + (b * INTER + o) * FULL + 4 * tid);
        *dst = make_float4(a0, a1, a2, a3);
        s  = a0 + a1 + a2 + a3;
        s2 = a0*a0 + a1*a1 + a2*a2 + a3*a3;
    }
    for (int d = 32; d > 0; d >>= 1) { s += __shfl_down(s, d); s2 += __shfl_down(s2, d); }
    if (tid == 0) { atomicAdd(&bns[o], s); atomicAdd(&bns[24 + o], s2); }
}

// ---------------------------------------------------------------------------
// k_bn: BN apply (biased var) + tanh into padded global ddp_g[16][24][364].
// ---------------------------------------------------------------------------
__global__ __launch_bounds__(256) void k_bn(
    const float* __restrict__ dbuf, const float* __restrict__ bns,
    const float* __restrict__ gma, const float* __restrict__ bta,
    float* __restrict__ ddp_g)
{
    int gid = blockIdx.x * 256 + threadIdx.x;        // < 16*24*364 = 139776
    if (gid >= 16 * INTER * 364) return;
    int q = gid % 364, bc = gid / 364, c = bc % INTER;
    float m  = bns[c] * (1.0f / 3840.0f);
    float v  = bns[24 + c] * (1.0f / 3840.0f) - m * m;
    float rs = rsqrtf(fmaxf(v, 0.0f) + 1e-5f);
    float scl = rs * gma[c];
    float sft = bta[c] - m * scl;
    float val = 0.0f;
    if (q >= 60 && q < 300) val = tanhf(dbuf[bc * FULL + (q - 60)] * scl + sft);
    ddp_g[gid] = val;
}

// ---------------------------------------------------------------------------
// k_dec2: decoder conv2, sliding-float4-window; weights staged to LDS.
// ---------------------------------------------------------------------------
__global__ __launch_bounds__(64) void k_dec2(
    const float* __restrict__ ddp_g, const float* __restrict__ dw2, const float* __restrict__ db2,
    float* __restrict__ oY, float* __restrict__ oYp)
{
    const int blk = blockIdx.x;            // b*72 + oc
    const int b = blk / INCH, oc = blk - b * INCH;
    const int tid = threadIdx.x;
    __shared__ __align__(16) float sdp[INTER * 364]; // 34944 B
    __shared__ float wds2[INTER * TLEN];             // 11616 B
    const uint4* src = (const uint4*)(ddp_g + b * (INTER * 364));
    for (int idx = tid; idx < INTER * 364 / 4; idx += 64)
        ((uint4*)sdp)[idx] = src[idx];
    for (int idx = tid; idx < INTER * TLEN; idx += 64)
        wds2[idx] = dw2[oc * (INTER * TLEN) + idx];
    __syncthreads();
    const int te = (tid < 60) ? tid : 59;
    const float bias = db2[oc];
    float a0 = bias, a1 = bias, a2 = bias, a3 = bias;
    for (int c = 0; c < INTER; ++c) {
        const float* wr = wds2 + c * TLEN;
        const float* base = sdp + c * 364 + 4 * te;
        float4 cur = *(const float4*)base;
        for (int kb = 0; kb < 30; ++kb) {
            float4 nxt = *(const float4*)(base + 4 * kb + 4);
            float w0 = wr[4*kb], w1 = wr[4*kb+1], w2 = wr[4*kb+2], w3 = wr[4*kb+3];
            a0 += w0*cur.x; a1 += w0*cur.y; a2 += w0*cur.z; a3 += w0*cur.w;
            a0 += w1*cur.y; a1 += w1*cur.z; a2 += w1*cur.w; a3 += w1*nxt.x;
            a0 += w2*cur.z; a1 += w2*cur.w; a2 += w2*nxt.x; a3 += w2*nxt.y;
            a0 += w3*cur.w; a1 += w3*nxt.x; a2 += w3*nxt.y; a3 += w3*nxt.z;
            cur = nxt;
        }
        float wl = wr[120];
        a0 += wl*cur.x; a1 += wl*cur.y; a2 += wl*cur.z; a3 += wl*cur.w;
    }
    if (tid < 60) {
        const int i = 4 * tid;
        float4* dst = (float4*)(oY + (b * INCH + oc) * FULL + i);
        *dst = make_float4(a0, a1, a2, a3);
        float* yp = oYp + (b * INCH + oc) * TLEN;
        if (i     < TLEN) yp[i]     = a0;
        if (i + 1 < TLEN) yp[i + 1] = a1;
        if (i + 2 < TLEN) yp[i + 2] = a2;
        if (i + 3 < TLEN) yp[i + 3] = a3;
    }
}

// ---------------------------------------------------------------------------
extern "C" void kernel_launch(void* const* d_in, const int* in_sizes, int n_in,
                              void* d_out, int out_size, void* d_ws, size_t ws_size,
                              hipStream_t stream)
{
    const float* x   = (const float*)d_in[0];
    const float* w1  = (const float*)d_in[1];
    const float* b1  = (const float*)d_in[2];
    const float* lna = (const float*)d_in[3];
    const float* lnb = (const float*)d_in[4];
    const float* w2  = (const float*)d_in[5];
    const float* b2  = (const float*)d_in[6];
    const float* fcw = (const float*)d_in[7];
    const float* fcb = (const float*)d_in[8];
    const float* dw1 = (const float*)d_in[9];
    const float* db1 = (const float*)d_in[10];
    const float* gma = (const float*)d_in[11];
    const float* bta = (const float*)d_in[12];
    const float* dw2 = (const float*)d_in[13];
    const float* db2 = (const float*)d_in[14];

    // Output layout (flat fp32, reference return order):
    float* out  = (float*)d_out;
    float* oY   = out;                 // [16][72][240]
    float* oLat = out + 276480;        // [16][8][121]
    float* oSig = out + 291968;        // [16][8][121]
    float* oP   = out + 307456;
    float* oF   = out + 307584;
    float* oA   = out + 307712;
    float* oB   = out + 307840;
    float* oYp  = out + 307968;        // [16][72][121]

    // Workspace layout (bytes; ws_size >= 46,436,544 proven in round 6):
    //   [0, 123904)           w2f bf16 fragments [121][64][8]
    //   [123904, 156672)      w3f bf16 DFT fragments [4][8][64][8]
    //   [156672, 1391808)     fp32: pP/pF/pA/pB (dbuf overlay), sig, bns, ddp_g
    //   [1391808, 46365888)   R prefix table [384][122][240] fp32 (+h3 overlay)
    short* w2f  = (short*)d_ws;
    short* w3f  = (short*)((char*)d_ws + 123904);
    float* fb   = (float*)((char*)d_ws + 156672);
    float* pP   = fb;
    float* pF   = pP + 30720;
    float* pA   = pF + 30720;
    float* pB   = pA + 30720;
    float* dbuf = fb;                  // overlay (temporally disjoint)
    float* sig  = fb + 122880;         // 46080
    float* bns  = sig + 46080;         // 48
    float* ddp_g = bns + 48;           // 139776
    float* R    = (float*)((char*)d_ws + 1391808);

    hipMemsetAsync(bns, 0, 48 * sizeof(float), stream);
    k_prep_w2f<<<242, 256, 0, stream>>>(w2, w2f);
    k_prep_w3f<<<64, 256, 0, stream>>>(w3f);
    k_qr<<<384, 256, 0, stream>>>(x, w1, R);
    k_gather_ln<<<384, 256, 0, stream>>>(R, b1, lna, lnb);
    k_enc2<<<NWIN, 256, 0, stream>>>(R, w2f, w3f, b2, fcw, fcb,
                                     pP, pF, pA, pB, oLat, oP, oF, oA, oB);
    k_signal<<<128, 256, 0, stream>>>(pP, pF, pA, pB, sig, oSig);
    k_dec1<<<384, 64, 0, stream>>>(sig, dw1, db1, dbuf, bns);
    k_bn<<<(16 * INTER * 364 + 255) / 256, 256, 0, stream>>>(dbuf, bns, gma, bta, ddp_g);
    k_dec2<<<16 * INCH, 64, 0, stream>>>(ddp_g, dw2, db2, oY, oYp);
}

// Round 10
// 513.784 us; speedup vs baseline: 16.4558x; 1.1509x over previous
//
#include <hip/hip_runtime.h>
#include <math.h>

// ---------------------------------------------------------------------------
// PAE pipeline on MI355X. Round 10:
//   k_enc2: A-fragment ring buffer (a1[tap] == a0[tap+16]) -> 137 vs 242
//           ds_read_b128 per wave; MFMA order unchanged (bit-identical).
//   k_dec1/k_dec2: 256-thr blocks, 4 waves split channels, LDS partial-sum
//           reduce; weights via block-uniform global reads (s_load path);
//           BN+tanh fused into k_dec2 staging (k_bn kernel removed).
//   k_qr / k_gather_ln / k_signal / preps byte-identical to round 9.
// ---------------------------------------------------------------------------

#define INCH   72
#define TLEN   121
#define FULL   240
#define INTER  24
#define EMB    8
#define LP     360
#define NWIN   3840

typedef __attribute__((ext_vector_type(8)))  short s16x8;
typedef __attribute__((ext_vector_type(4)))  float f32x4;

// fp32 -> bf16 (RNE) as raw ushort
__device__ __forceinline__ unsigned short f2bf(float f) {
    unsigned u = __float_as_uint(f);
    unsigned r = ((u >> 16) & 1u) + 0x7FFFu;
    return (unsigned short)((u + r) >> 16);
}

// ---------------------------------------------------------------------------
// w2 fragment prep: w2f[tap][lane][j] = w2[e=lane&15][c=(lane>>4)*8+j][tap].
// ---------------------------------------------------------------------------
__global__ __launch_bounds__(256) void k_prep_w2f(const float* __restrict__ w2,
                                                  short* __restrict__ w2f) {
    int idx = blockIdx.x * 256 + threadIdx.x;       // < 121*64*8 = 61952
    if (idx >= 61952) return;
    int j = idx & 7, ln = (idx >> 3) & 63, tap = idx >> 9;
    int e = ln & 15, c = (ln >> 4) * 8 + j;
    float v = (e < EMB && c < INTER) ? w2[(e * INTER + c) * TLEN + tap] : 0.0f;
    w2f[idx] = (short)f2bf(v);
}

// ---------------------------------------------------------------------------
// DFT trig fragments (B-frag of 16x16x32), verified round 9.
// ---------------------------------------------------------------------------
__global__ __launch_bounds__(256) void k_prep_w3f(short* __restrict__ w3f) {
    int idx = blockIdx.x * 256 + threadIdx.x;       // < 16384
    if (idx >= 16384) return;
    int j = idx & 7, ln = (idx >> 3) & 63, tl = (idx >> 9) & 7, ch = idx >> 12;
    int t = (ln >> 4) * 8 + j + ch * 32;
    int colIdx = (tl & 3) * 16 + (ln & 15);
    int k = colIdx + 1;
    float v = 0.0f;
    if (t < TLEN && colIdx < 60) {
        int mm = (k * t) % 121;
        float s, c;
        sincosf(6.2831853071795864f * (float)mm / 121.0f, &s, &c);
        v = (tl < 4) ? c : -s;
    }
    w3f[idx] = (short)f2bf(v);
}

// ---------------------------------------------------------------------------
// k_qr: Q + exclusive prefix R, fused. Block = (b,o) (384 blocks).
// ---------------------------------------------------------------------------
__global__ __launch_bounds__(256) void k_qr(
    const float* __restrict__ x, const float* __restrict__ w1,
    float* __restrict__ R)
{
    const int blk = blockIdx.x;          // b*24 + o
    const int b = blk / INTER, o = blk - b * INTER;
    const int tid = threadIdx.x;
    __shared__ float xs[INCH * FULL];    // 69120 B
    for (int idx = tid; idx < INCH * FULL; idx += 256)
        xs[idx] = x[b * INCH * FULL + idx];
    __syncthreads();
    if (tid >= FULL) return;
    const int s = tid;
    const float* wq = w1 + o * (INCH * TLEN);
    float* Rb = R + (size_t)blk * (122 * FULL);
    Rb[s] = 0.0f;
    float P = 0.0f;
    for (int m = 0; m < TLEN; ++m) {
        int idxm = s + m;
        idxm -= (idxm >= FULL) ? FULL : 0;
        float q = 0.0f;
        for (int c = 0; c < INCH; ++c)
            q += wq[c * TLEN + m] * xs[c * FULL + idxm];
        P += q;
        Rb[(m + 1) * FULL + s] = P;
    }
}

// ---------------------------------------------------------------------------
// k_gather_ln: conv1 diff + LN + tanh -> bf16 h3 (overlays own R tile).
// ---------------------------------------------------------------------------
__global__ __launch_bounds__(256) void k_gather_ln(
    float* __restrict__ R, const float* __restrict__ b1,
    const float* __restrict__ lna, const float* __restrict__ lnb)
{
    const int blk = blockIdx.x;          // b*24 + o
    const int o = blk % INTER;
    const int tid = threadIdx.x;
    __shared__ float Rt[122 * FULL];     // 117120 B
    float* Rg = R + (size_t)blk * (122 * FULL);
    for (int idx = tid; idx < (122 * FULL) / 4; idx += 256)
        ((float4*)Rt)[idx] = ((const float4*)Rg)[idx];
    __syncthreads();
    if (tid >= FULL) return;
    const int n = tid;
    const float bias = b1[o];
    float s = 0.0f, s2 = 0.0f;
    for (int i = 0; i < TLEN; ++i) {
        int st = n + i - 120; st += (st < 0) ? FULL : 0;
        float v = (i <= 60) ? (Rt[121 * FULL + st] - Rt[(60 - i) * FULL + st])
                            : Rt[(181 - i) * FULL + st];
        v += bias;
        s += v; s2 += v * v;
    }
    float mean = s * (1.0f / 121.0f);
    float var  = fmaxf((s2 - s * mean) * (1.0f / 120.0f), 0.0f);
    float inv  = 1.0f / (sqrtf(var) + 1e-5f);
    unsigned short* dst = (unsigned short*)Rg + n * TLEN;
    for (int i = 0; i < TLEN; ++i) {
        int st = n + i - 120; st += (st < 0) ? FULL : 0;
        float v = (i <= 60) ? (Rt[121 * FULL + st] - Rt[(60 - i) * FULL + st])
                            : Rt[(181 - i) * FULL + st];
        v += bias;
        v = (v - mean) * inv * lna[i] + lnb[i];
        dst[i] = f2bf(tanhf(v));
    }
}

// ---------------------------------------------------------------------------
// k_enc2: per-window conv2 MFMA (ring-buffered A) + DFT-MFMA + fc/b.
// ---------------------------------------------------------------------------
__global__ __launch_bounds__(256) void k_enc2(
    const float* __restrict__ R, const short* __restrict__ w2f,
    const short* __restrict__ w3f, const float* __restrict__ b2,
    const float* __restrict__ fcw, const float* __restrict__ fcb,
    float* __restrict__ pP, float* __restrict__ pF, float* __restrict__ pA, float* __restrict__ pB,
    float* __restrict__ oLat, float* __restrict__ oP, float* __restrict__ oF,
    float* __restrict__ oA, float* __restrict__ oB)
{
    const int w   = blockIdx.x;
    const int b   = w / FULL, n = w - b * FULL;
    const int tid = threadIdx.x;
    const int lane = tid & 63, wid = tid >> 6;

    __shared__ __align__(16) short hT[248 * 40];     // 19840 B, stride 40
    __shared__ __align__(16) short hs[24 * 132];     // 6336 B
    __shared__ __align__(16) short latb[16 * 136];   // 4352 B
    __shared__ float lat[EMB * 122];                 // 3904 B
    __shared__ float S0[8], S1[8], vv[16], bm[8];

    for (int idx = tid; idx < 1240; idx += 256) ((uint4*)hT)[idx] = make_uint4(0,0,0,0);
    for (int idx = tid; idx < 272;  idx += 256) ((uint4*)latb)[idx] = make_uint4(0,0,0,0);
    if (tid < 8) { S0[tid] = 0.0f; S1[tid] = 0.0f; }

    for (int idx = tid; idx < INTER * TLEN; idx += 256) {
        int o = idx / TLEN, i = idx - o * TLEN;
        const unsigned short* h3 =
            (const unsigned short*)(R + (size_t)(b * INTER + o) * (122 * FULL)) + n * TLEN;
        hs[o * 132 + i] = (short)h3[i];
    }
    __syncthreads();
    for (int idx = tid; idx < TLEN * 32; idx += 256) {
        int i = idx >> 5, o = idx & 31;
        short v = (o < INTER) ? hs[o * 132 + i] : (short)0;
        hT[(60 + i) * 40 + o] = v;
    }
    __syncthreads();

    const int m = lane & 15, quad = lane >> 4;
    const int t0 = wid * 32;

    // --- conv2 MFMA with 16-deep A ring: a1[tap] == a0[tap+16] ---
    f32x4 acc0 = {0.0f, 0.0f, 0.0f, 0.0f};
    f32x4 acc1 = {0.0f, 0.0f, 0.0f, 0.0f};
    const short* aptr = hT + (t0 + m) * 40 + quad * 8;
    s16x8 ring[16];
#pragma unroll
    for (int j = 0; j < 16; ++j) ring[j] = *(const s16x8*)(aptr + j * 40);

    for (int t16 = 0; t16 < 7; ++t16) {          // taps 0..111
#pragma unroll
        for (int j = 0; j < 16; ++j) {
            const int tap = t16 * 16 + j;
            s16x8 bw = *(const s16x8*)(w2f + tap * 512 + lane * 8);
            s16x8 nw = *(const s16x8*)(aptr + (tap + 16) * 40);
            acc0 = __builtin_amdgcn_mfma_f32_16x16x32_bf16(ring[j], bw, acc0, 0, 0, 0);
            acc1 = __builtin_amdgcn_mfma_f32_16x16x32_bf16(nw,      bw, acc1, 0, 0, 0);
            ring[j] = nw;
        }
    }
#pragma unroll
    for (int j = 0; j < 9; ++j) {                // taps 112..120
        const int tap = 112 + j;
        s16x8 bw = *(const s16x8*)(w2f + tap * 512 + lane * 8);
        s16x8 nw = *(const s16x8*)(aptr + (tap + 16) * 40);
        acc0 = __builtin_amdgcn_mfma_f32_16x16x32_bf16(ring[j], bw, acc0, 0, 0, 0);
        acc1 = __builtin_amdgcn_mfma_f32_16x16x32_bf16(nw,      bw, acc1, 0, 0, 0);
    }

    // epilogue: C/D col=lane&15 (=e), row=quad*4+r (=i in tile)
    {
        const int e = lane & 15;
        if (e < EMB) {
            float bias = b2[e];
#pragma unroll
            for (int r = 0; r < 4; ++r) {
                int i0v = t0 + quad * 4 + r;
                if (i0v < TLEN) {
                    float v = acc0[r] + bias;
                    lat[e * 122 + i0v] = v;
                    latb[e * 136 + i0v] = (short)f2bf(v);
                }
                int i1v = t0 + 16 + quad * 4 + r;
                if (i1v < TLEN) {
                    float v = acc1[r] + bias;
                    lat[e * 122 + i1v] = v;
                    latb[e * 136 + i1v] = (short)f2bf(v);
                }
            }
        }
    }
    __syncthreads();

    // --- DFT via MFMA ---
    {
        f32x4 accR = {0.0f, 0.0f, 0.0f, 0.0f};
        f32x4 accI = {0.0f, 0.0f, 0.0f, 0.0f};
#pragma unroll
        for (int ch = 0; ch < 4; ++ch) {
            s16x8 a  = *(const s16x8*)(latb + (lane & 15) * 136 + quad * 8 + ch * 32);
            s16x8 br = *(const s16x8*)(w3f + (((ch * 8) + wid) * 64 + lane) * 8);
            s16x8 bi = *(const s16x8*)(w3f + (((ch * 8) + 4 + wid) * 64 + lane) * 8);
            accR = __builtin_amdgcn_mfma_f32_16x16x32_bf16(a, br, accR, 0, 0, 0);
            accI = __builtin_amdgcn_mfma_f32_16x16x32_bf16(a, bi, accI, 0, 0, 0);
        }
        const int colj = lane & 15;
        const int col  = wid * 16 + colj;
        const float fw = 0.5f * (float)(col + 1);
#pragma unroll
        for (int r = 0; r < 4; ++r) {
            float pw = (col < 60) ? (accR[r] * accR[r] + accI[r] * accI[r]) : 0.0f;
            float s1 = pw * fw;
#pragma unroll
            for (int off = 1; off < 16; off <<= 1) {
                pw += __shfl_xor(pw, off);
                s1 += __shfl_xor(s1, off);
            }
            if (colj == 0) {
                int e = quad * 4 + r;
                if (e < EMB) { atomicAdd(&S0[e], pw); atomicAdd(&S1[e], s1); }
            }
        }
    }
    // --- fc ---
    if (tid < 16) {
        int e_ = tid >> 1, kk = tid & 1;
        float accv = fcb[e_ * 2 + kk];
        const float* fr = fcw + (e_ * 2 + kk) * TLEN;
        for (int t = 0; t < TLEN; ++t) accv += lat[e_ * 122 + t] * fr[t];
        vv[tid] = accv;
    }
    if (tid >= 32 && tid < 40) {
        int e_ = tid - 32;
        float s = 0.0f;
        for (int t = 0; t < TLEN; ++t) s += lat[e_ * 122 + t];
        bm[e_] = s * (1.0f / 121.0f);
    }
    __syncthreads();

    if (tid < 8) {
        int e_ = tid;
        float fv = S1[e_] / S0[e_];
        float av = 2.0f * sqrtf(S0[e_]) * (1.0f / 121.0f);
        float pv = atan2f(vv[2 * e_ + 1], vv[2 * e_]) * 0.15915494309189535f;
        float bv = bm[e_];
        int gi = w * 8 + e_;
        pP[gi] = pv; pF[gi] = fv; pA[gi] = av; pB[gi] = bv;
        if (n == 0) {
            oP[b * 8 + e_] = pv;
            oF[b * 8 + e_] = fv;
            oA[b * 8 + e_] = av;
            oB[b * 8 + e_] = bv;
        }
    }
    if (n == 0) {
        for (int idx = tid; idx < EMB * TLEN; idx += 256) {
            int e_ = idx / TLEN, i = idx - e_ * TLEN;
            oLat[(b * EMB + e_) * TLEN + i] = lat[e_ * 122 + i];
        }
    }
}

// ---------------------------------------------------------------------------
// k_signal: sinusoid resynthesis + overlap-add, gather form.
// ---------------------------------------------------------------------------
__global__ __launch_bounds__(256) void k_signal(
    const float* __restrict__ pP, const float* __restrict__ pF,
    const float* __restrict__ pA, const float* __restrict__ pB,
    float* __restrict__ sig, float* __restrict__ oSig)
{
    const int blk = blockIdx.x;
    const int b = blk >> 3, e = blk & 7;
    const int tid = threadIdx.x;
    __shared__ float sp[FULL], sf[FULL], sa[FULL], sb[FULL];
    for (int nn = tid; nn < FULL; nn += 256) {
        int gi = (b * FULL + nn) * 8 + e;
        sp[nn] = pP[gi]; sf[nn] = pF[gi]; sa[nn] = pA[gi]; sb[nn] = pB[gi];
    }
    __syncthreads();
    for (int u = tid; u < LP; u += 256) {
        int nlo = (u - 120 > 0) ? (u - 120) : 0;
        int nhi = (u < 239) ? u : 239;
        float s = 0.0f;
        for (int nn = nlo; nn <= nhi; ++nn) {
            float tt = (float)(u - nn);
            float z = sf[nn] * (tt * (1.0f / 60.0f) - 1.0f) + sp[nn];
            z -= floorf(z);
            s += sa[nn] * sinf(6.2831853071795864f * z) + sb[nn];
        }
        float wgt = (u < TLEN) ? (float)(u + 1) : ((u > 239) ? (float)(LP - u) : 121.0f);
        float val = s / wgt;
        sig[(b * EMB + e) * LP + u] = val;
        if (u < TLEN) oSig[(b * EMB + e) * TLEN + u] = val;
    }
}

// ---------------------------------------------------------------------------
// k_dec1: decoder conv1. Block = (b,o), 384 x 256 thr; 4 waves x 2 channels,
// LDS partial-sum reduce; weights via block-uniform global reads.
// ---------------------------------------------------------------------------
__global__ __launch_bounds__(256) void k_dec1(
    const float* __restrict__ sig, const float* __restrict__ dw1, const float* __restrict__ db1,
    float* __restrict__ dbuf, float* __restrict__ bns)
{
    const int blk = blockIdx.x;            // b*24 + o
    const int b = blk / INTER, o = blk - b * INTER;
    const int tid = threadIdx.x;
    const int lane = tid & 63, wid = tid >> 6;
    __shared__ __align__(16) float ycp[EMB * 364];   // 11648 B
    __shared__ __align__(16) float part[4][240];     // 3840 B
    for (int idx = tid; idx < EMB * 364; idx += 256) {
        int c = idx / 364, q = idx - c * 364;
        float v = 0.0f;
        if (q >= 60 && q < 300) v = sig[(b * EMB + c) * LP + q];
        ycp[idx] = v;
    }
    __syncthreads();
    const int te = (lane < 60) ? lane : 59;
    float a0 = 0.0f, a1 = 0.0f, a2 = 0.0f, a3 = 0.0f;
    for (int cl = 0; cl < 2; ++cl) {
        const int c = wid * 2 + cl;
        const float* wr = dw1 + (o * EMB + c) * TLEN;
        const float* base = ycp + c * 364 + 4 * te;
        float4 cur = *(const float4*)base;
        for (int kb = 0; kb < 30; ++kb) {
            float4 nxt = *(const float4*)(base + 4 * kb + 4);
            float w0 = wr[4*kb], w1 = wr[4*kb+1], w2 = wr[4*kb+2], w3 = wr[4*kb+3];
            a0 += w0*cur.x; a1 += w0*cur.y; a2 += w0*cur.z; a3 += w0*cur.w;
            a0 += w1*cur.y; a1 += w1*cur.z; a2 += w1*cur.w; a3 += w1*nxt.x;
            a0 += w2*cur.z; a1 += w2*cur.w; a2 += w2*nxt.x; a3 += w2*nxt.y;
            a0 += w3*cur.w; a1 += w3*nxt.x; a2 += w3*nxt.y; a3 += w3*nxt.z;
            cur = nxt;
        }
        float wl = wr[120];
        a0 += wl*cur.x; a1 += wl*cur.y; a2 += wl*cur.z; a3 += wl*cur.w;
    }
    if (lane < 60) {
        float4* dst = (float4*)&part[wid][4 * lane];
        *dst = make_float4(a0, a1, a2, a3);
    }
    __syncthreads();
    float s = 0.0f, s2 = 0.0f;
    if (tid < 60) {
        const float bias = db1[o];
        float4 f;
        f.x = part[0][4*tid+0] + part[1][4*tid+0] + part[2][4*tid+0] + part[3][4*tid+0] + bias;
        f.y = part[0][4*tid+1] + part[1][4*tid+1] + part[2][4*tid+1] + part[3][4*tid+1] + bias;
        f.z = part[0][4*tid+2] + part[1][4*tid+2] + part[2][4*tid+2] + part[3][4*tid+2] + bias;
        f.w = part[0][4*tid+3] + part[1][4*tid+3] + part[2][4*tid+3] + part[3][4*tid+3] + bias;
        *(float4*)(dbuf + (b * INTER + o) * FULL + 4 * tid) = f;
        s  = f.x + f.y + f.z + f.w;
        s2 = f.x*f.x + f.y*f.y + f.z*f.z + f.w*f.w;
    }
    if (wid == 0) {
        for (int d = 32; d > 0; d >>= 1) { s += __shfl_down(s, d); s2 += __shfl_down(s2, d); }
        if (tid == 0) { atomicAdd(&bns[o], s); atomicAdd(&bns[24 + o], s2); }
    }
}

// ---------------------------------------------------------------------------
// k_dec2: decoder conv2 with fused BN+tanh staging. Block = (b,oc),
// 1152 x 256 thr; 4 waves x 6 channels, LDS partial-sum reduce.
// ---------------------------------------------------------------------------
__global__ __launch_bounds__(256) void k_dec2(
    const float* __restrict__ dbuf, const float* __restrict__ bns,
    const float* __restrict__ gma, const float* __restrict__ bta,
    const float* __restrict__ dw2, const float* __restrict__ db2,
    float* __restrict__ oY, float* __restrict__ oYp)
{
    const int blk = blockIdx.x;            // b*72 + oc
    const int b = blk / INCH, oc = blk - b * INCH;
    const int tid = threadIdx.x;
    const int lane = tid & 63, wid = tid >> 6;
    __shared__ __align__(16) float sdp[INTER * 364]; // 34944 B
    __shared__ __align__(16) float part[4][240];     // 3840 B
    __shared__ float scl[INTER], sft[INTER];
    if (tid < INTER) {
        float m  = bns[tid] * (1.0f / 3840.0f);
        float v  = bns[24 + tid] * (1.0f / 3840.0f) - m * m;
        float rs = rsqrtf(fmaxf(v, 0.0f) + 1e-5f);
        float g  = gma[tid];
        scl[tid] = rs * g;
        sft[tid] = bta[tid] - m * rs * g;
    }
    __syncthreads();
    for (int idx = tid; idx < INTER * 364; idx += 256) {
        int c = idx / 364, q = idx - c * 364;
        float v = 0.0f;
        if (q >= 60 && q < 300)
            v = tanhf(dbuf[(b * INTER + c) * FULL + (q - 60)] * scl[c] + sft[c]);
        sdp[idx] = v;
    }
    __syncthreads();
    const int te = (lane < 60) ? lane : 59;
    float a0 = 0.0f, a1 = 0.0f, a2 = 0.0f, a3 = 0.0f;
    for (int cl = 0; cl < 6; ++cl) {
        const int c = wid * 6 + cl;
        const float* wr = dw2 + (oc * INTER + c) * TLEN;
        const float* base = sdp + c * 364 + 4 * te;
        float4 cur = *(const float4*)base;
        for (int kb = 0; kb < 30; ++kb) {
            float4 nxt = *(const float4*)(base + 4 * kb + 4);
            float w0 = wr[4*kb], w1 = wr[4*kb+1], w2 = wr[4*kb+2], w3 = wr[4*kb+3];
            a0 += w0*cur.x; a1 += w0*cur.y; a2 += w0*cur.z; a3 += w0*cur.w;
            a0 += w1*cur.y; a1 += w1*cur.z; a2 += w1*cur.w; a3 += w1*nxt.x;
            a0 += w2*cur.z; a1 += w2*cur.w; a2 += w2*nxt.x; a3 += w2*nxt.y;
            a0 += w3*cur.w; a1 += w3*nxt.x; a2 += w3*nxt.y; a3 += w3*nxt.z;
            cur = nxt;
        }
        float wl = wr[120];
        a0 += wl*cur.x; a1 += wl*cur.y; a2 += wl*cur.z; a3 += wl*cur.w;
    }
    if (lane < 60) {
        float4* dst = (float4*)&part[wid][4 * lane];
        *dst = make_float4(a0, a1, a2, a3);
    }
    __syncthreads();
    if (tid < 60) {
        const float bias = db2[oc];
        float4 f;
        f.x = part[0][4*tid+0] + part[1][4*tid+0] + part[2][4*tid+0] + part[3][4*tid+0] + bias;
        f.y = part[0][4*tid+1] + part[1][4*tid+1] + part[2][4*tid+1] + part[3][4*tid+1] + bias;
        f.z = part[0][4*tid+2] + part[1][4*tid+2] + part[2][4*tid+2] + part[3][4*tid+2] + bias;
        f.w = part[0][4*tid+3] + part[1][4*tid+3] + part[2][4*tid+3] + part[3][4*tid+3] + bias;
        const int i = 4 * tid;
        *(float4*)(oY + (b * INCH + oc) * FULL + i) = f;
        float* yp = oYp + (b * INCH + oc) * TLEN;
        if (i     < TLEN) yp[i]     = f.x;
        if (i + 1 < TLEN) yp[i + 1] = f.y;
        if (i + 2 < TLEN) yp[i + 2] = f.z;
        if (i + 3 < TLEN) yp[i + 3] = f.w;
    }
}

// ---------------------------------------------------------------------------
extern "C" void kernel_launch(void* const* d_in, const int* in_sizes, int n_in,
                              void* d_out, int out_size, void* d_ws, size_t ws_size,
                              hipStream_t stream)
{
    const float* x   = (const float*)d_in[0];
    const float* w1  = (const float*)d_in[1];
    const float* b1  = (const float*)d_in[2];
    const float* lna = (const float*)d_in[3];
    const float* lnb = (const float*)d_in[4];
    const float* w2  = (const float*)d_in[5];
    const float* b2  = (const float*)d_in[6];
    const float* fcw = (const float*)d_in[7];
    const float* fcb = (const float*)d_in[8];
    const float* dw1 = (const float*)d_in[9];
    const float* db1 = (const float*)d_in[10];
    const float* gma = (const float*)d_in[11];
    const float* bta = (const float*)d_in[12];
    const float* dw2 = (const float*)d_in[13];
    const float* db2 = (const float*)d_in[14];

    // Output layout (flat fp32, reference return order):
    float* out  = (float*)d_out;
    float* oY   = out;                 // [16][72][240]
    float* oLat = out + 276480;        // [16][8][121]
    float* oSig = out + 291968;        // [16][8][121]
    float* oP   = out + 307456;
    float* oF   = out + 307584;
    float* oA   = out + 307712;
    float* oB   = out + 307840;
    float* oYp  = out + 307968;        // [16][72][121]

    // Workspace layout (bytes; ws_size >= 46.4 MB proven in round 6):
    //   [0, 123904)           w2f bf16 fragments [121][64][8]
    //   [123904, 156672)      w3f bf16 DFT fragments
    //   [156672, 1391808)     fp32: pP/pF/pA/pB (dbuf overlay), sig, bns
    //   [1391808, 46365888)   R prefix table [384][122][240] fp32 (+h3 overlay)
    short* w2f  = (short*)d_ws;
    short* w3f  = (short*)((char*)d_ws + 123904);
    float* fb   = (float*)((char*)d_ws + 156672);
    float* pP   = fb;
    float* pF   = pP + 30720;
    float* pA   = pF + 30720;
    float* pB   = pA + 30720;
    float* dbuf = fb;                  // overlay (temporally disjoint)
    float* sig  = fb + 122880;         // 46080
    float* bns  = sig + 46080;         // 48
    float* R    = (float*)((char*)d_ws + 1391808);

    hipMemsetAsync(bns, 0, 48 * sizeof(float), stream);
    k_prep_w2f<<<242, 256, 0, stream>>>(w2, w2f);
    k_prep_w3f<<<64, 256, 0, stream>>>(w3f);
    k_qr<<<384, 256, 0, stream>>>(x, w1, R);
    k_gather_ln<<<384, 256, 0, stream>>>(R, b1, lna, lnb);
    k_enc2<<<NWIN, 256, 0, stream>>>(R, w2f, w3f, b2, fcw, fcb,
                                     pP, pF, pA, pB, oLat, oP, oF, oA, oB);
    k_signal<<<128, 256, 0, stream>>>(pP, pF, pA, pB, sig, oSig);
    k_dec1<<<384, 256, 0, stream>>>(sig, dw1, db1, dbuf, bns);
    k_dec2<<<16 * INCH, 256, 0, stream>>>(dbuf, bns, gma, bta, dw2, db2, oY, oYp);
}

// Round 11
// 475.203 us; speedup vs baseline: 17.7918x; 1.0812x over previous
//
#include <hip/hip_runtime.h>
#include <math.h>

// ---------------------------------------------------------------------------
// PAE pipeline on MI355X. Round 11:
//   k_qr (124 us, LDS-issue-bound: 8712 ds_read_b32/thread) replaced by
//   k_q: per-tap MFMA GEMM [24o x 72c x 240s] writing Q[b][o][m][s] (bf16
//        inputs, fp32 accum), 256 blocks (16b x 8 tap-groups x 2 s-halves).
//   k_gather_ln: stages Q tile, computes the exclusive prefix over m IN LDS
//        (242 conflict-free ops/thread), then gather/LN/tanh as before;
//        h3 bf16 overlays the block's own dead Q tile.
//   k_enc2 / k_signal / k_dec1 / k_dec2 / preps byte-identical to round 10.
// ---------------------------------------------------------------------------

#define INCH   72
#define TLEN   121
#define FULL   240
#define INTER  24
#define EMB    8
#define LP     360
#define NWIN   3840

typedef __attribute__((ext_vector_type(8)))  short s16x8;
typedef __attribute__((ext_vector_type(4)))  float f32x4;

// fp32 -> bf16 (RNE) as raw ushort
__device__ __forceinline__ unsigned short f2bf(float f) {
    unsigned u = __float_as_uint(f);
    unsigned r = ((u >> 16) & 1u) + 0x7FFFu;
    return (unsigned short)((u + r) >> 16);
}

// ---------------------------------------------------------------------------
// w2 fragment prep: w2f[tap][lane][j] = w2[e=lane&15][c=(lane>>4)*8+j][tap].
// ---------------------------------------------------------------------------
__global__ __launch_bounds__(256) void k_prep_w2f(const float* __restrict__ w2,
                                                  short* __restrict__ w2f) {
    int idx = blockIdx.x * 256 + threadIdx.x;       // < 121*64*8 = 61952
    if (idx >= 61952) return;
    int j = idx & 7, ln = (idx >> 3) & 63, tap = idx >> 9;
    int e = ln & 15, c = (ln >> 4) * 8 + j;
    float v = (e < EMB && c < INTER) ? w2[(e * INTER + c) * TLEN + tap] : 0.0f;
    w2f[idx] = (short)f2bf(v);
}

// ---------------------------------------------------------------------------
// DFT trig fragments (B-frag of 16x16x32), verified round 9.
// ---------------------------------------------------------------------------
__global__ __launch_bounds__(256) void k_prep_w3f(short* __restrict__ w3f) {
    int idx = blockIdx.x * 256 + threadIdx.x;       // < 16384
    if (idx >= 16384) return;
    int j = idx & 7, ln = (idx >> 3) & 63, tl = (idx >> 9) & 7, ch = idx >> 12;
    int t = (ln >> 4) * 8 + j + ch * 32;
    int colIdx = (tl & 3) * 16 + (ln & 15);
    int k = colIdx + 1;
    float v = 0.0f;
    if (t < TLEN && colIdx < 60) {
        int mm = (k * t) % 121;
        float s, c;
        sincosf(6.2831853071795864f * (float)mm / 121.0f, &s, &c);
        v = (tl < 4) ? c : -s;
    }
    w3f[idx] = (short)f2bf(v);
}

// ---------------------------------------------------------------------------
// w1 A-fragments for k_q: layout (((tap*2+ot)*3+ch)*64+ln)*8+j,
// A[m=o][k=c] with o = ot*16 + (ln&15), c = (ln>>4)*8 + j + ch*32.
// ---------------------------------------------------------------------------
__global__ __launch_bounds__(256) void k_prep_w1fA(const float* __restrict__ w1,
                                                   short* __restrict__ w1fA) {
    int idx = blockIdx.x * 256 + threadIdx.x;       // < 121*2*3*64*8 = 371712
    if (idx >= 371712) return;
    int j = idx & 7, ln = (idx >> 3) & 63;
    int rest = idx >> 9;                 // tap*6 + ot*3 + ch
    int ch = rest % 3;
    int rest2 = rest / 3;                // tap*2 + ot
    int ot = rest2 & 1, tap = rest2 >> 1;
    int o = ot * 16 + (ln & 15);
    int c = (ln >> 4) * 8 + j + ch * 32;
    float v = (o < INTER && c < INCH) ? w1[(o * INCH + c) * TLEN + tap] : 0.0f;
    w1fA[idx] = (short)f2bf(v);
}

// ---------------------------------------------------------------------------
// k_q: Q[b][o][m][s] = sum_c w1[o,c,m] * x[b,c,(s+m)%240] via MFMA.
// Block = b*16 + sh*8 + mg (256 blocks, 256 thr). mg<7: taps mg*16..+15,
// mg=7: taps 112..120. sh: s-half (120 positions). D[o][s] tiles: A=w1fA,
// B = xTb[pos][c] (bf16, stride 104, zero-padded c>=72 -- A is zero there
// too so pad never contributes). fp32 accumulate; coalesced 64B-run stores.
// ---------------------------------------------------------------------------
__global__ __launch_bounds__(256) void k_q(
    const float* __restrict__ x, const short* __restrict__ w1fA,
    float* __restrict__ Q)
{
    const int blk = blockIdx.x;
    const int mg = blk & 7, sh = (blk >> 3) & 1, b = blk >> 4;
    const int tid = threadIdx.x;
    const int lane = tid & 63, wid = tid >> 6;
    const int s0 = sh * 120;
    __shared__ __align__(16) short xTb[248 * 104];   // 51584 B

    for (int idx = tid; idx < (248 * 104) / 8; idx += 256)
        ((uint4*)xTb)[idx] = make_uint4(0, 0, 0, 0);
    __syncthreads();
    for (int idx = tid; idx < 72 * 248; idx += 256) {
        int c = idx / 248, l = idx - c * 248;
        int g = s0 + l; g -= (g >= FULL) ? FULL : 0;
        xTb[l * 104 + c] = (short)f2bf(x[(b * INCH + c) * FULL + g]);
    }
    __syncthreads();

    const int ntaps = (mg < 7) ? 16 : 9;
    const int col = lane & 15, quad = lane >> 4;
    for (int j = 0; j < ntaps; ++j) {
        const int m = mg * 16 + j;
        s16x8 a[2][3];
#pragma unroll
        for (int ot = 0; ot < 2; ++ot)
#pragma unroll
            for (int ch = 0; ch < 3; ++ch)
                a[ot][ch] = *(const s16x8*)(w1fA + (((m * 2 + ot) * 3 + ch) * 64 + lane) * 8);
#pragma unroll
        for (int tt = 0; tt < 2; ++tt) {
            const int ts = (wid + tt * 4) * 16;          // s-tile base (0..112)
            const short* brow = xTb + (ts + col + m) * 104 + quad * 8;
            s16x8 b0 = *(const s16x8*)(brow);
            s16x8 b1 = *(const s16x8*)(brow + 32);
            s16x8 b2 = *(const s16x8*)(brow + 64);
            const int sl = ts + col;
#pragma unroll
            for (int ot = 0; ot < 2; ++ot) {
                f32x4 acc = {0.0f, 0.0f, 0.0f, 0.0f};
                acc = __builtin_amdgcn_mfma_f32_16x16x32_bf16(a[ot][0], b0, acc, 0, 0, 0);
                acc = __builtin_amdgcn_mfma_f32_16x16x32_bf16(a[ot][1], b1, acc, 0, 0, 0);
                acc = __builtin_amdgcn_mfma_f32_16x16x32_bf16(a[ot][2], b2, acc, 0, 0, 0);
                if (sl < 120) {
#pragma unroll
                    for (int r = 0; r < 4; ++r) {
                        int o = ot * 16 + quad * 4 + r;   // row = M index
                        if (o < INTER)
                            Q[((size_t)(b * INTER + o) * TLEN + m) * FULL + s0 + sl] = acc[r];
                    }
                }
            }
        }
    }
}

// ---------------------------------------------------------------------------
// k_gather_ln: stage Q tile, in-LDS exclusive prefix over m, then
// conv1 diff + LN + tanh -> bf16 h3 overlaying the block's own Q tile.
// ---------------------------------------------------------------------------
__global__ __launch_bounds__(256) void k_gather_ln(
    float* __restrict__ Q, const float* __restrict__ b1,
    const float* __restrict__ lna, const float* __restrict__ lnb)
{
    const int blk = blockIdx.x;          // b*24 + o
    const int o = blk % INTER;
    const int tid = threadIdx.x;
    __shared__ float Rt[122 * FULL];     // 117120 B
    float* Qg = Q + (size_t)blk * (TLEN * FULL);
    for (int idx = tid; idx < FULL / 4; idx += 256)
        ((float4*)Rt)[idx] = make_float4(0.0f, 0.0f, 0.0f, 0.0f);
    for (int idx = tid; idx < (TLEN * FULL) / 4; idx += 256)
        ((float4*)(Rt + FULL))[idx] = ((const float4*)Qg)[idx];
    __syncthreads();
    if (tid < FULL) {                    // prefix: R[m] = sum_{m'<m} Q[m']
        float P = 0.0f;
        for (int mm = 1; mm <= TLEN; ++mm) {
            P += Rt[mm * FULL + tid];
            Rt[mm * FULL + tid] = P;
        }
    }
    __syncthreads();
    if (tid < FULL) {
        const int n = tid;
        const float bias = b1[o];
        float s = 0.0f, s2 = 0.0f;
        for (int i = 0; i < TLEN; ++i) {
            int st = n + i - 120; st += (st < 0) ? FULL : 0;
            float v = (i <= 60) ? (Rt[121 * FULL + st] - Rt[(60 - i) * FULL + st])
                                : Rt[(181 - i) * FULL + st];
            v += bias;
            s += v; s2 += v * v;
        }
        float mean = s * (1.0f / 121.0f);
        float var  = fmaxf((s2 - s * mean) * (1.0f / 120.0f), 0.0f);
        float inv  = 1.0f / (sqrtf(var) + 1e-5f);
        unsigned short* dst = (unsigned short*)Qg + n * TLEN;
        for (int i = 0; i < TLEN; ++i) {
            int st = n + i - 120; st += (st < 0) ? FULL : 0;
            float v = (i <= 60) ? (Rt[121 * FULL + st] - Rt[(60 - i) * FULL + st])
                                : Rt[(181 - i) * FULL + st];
            v += bias;
            v = (v - mean) * inv * lna[i] + lnb[i];
            dst[i] = f2bf(tanhf(v));
        }
    }
}

// ---------------------------------------------------------------------------
// k_enc2: per-window conv2 MFMA (ring-buffered A) + DFT-MFMA + fc/b.
// ---------------------------------------------------------------------------
__global__ __launch_bounds__(256) void k_enc2(
    const float* __restrict__ Q, const short* __restrict__ w2f,
    const short* __restrict__ w3f, const float* __restrict__ b2,
    const float* __restrict__ fcw, const float* __restrict__ fcb,
    float* __restrict__ pP, float* __restrict__ pF, float* __restrict__ pA, float* __restrict__ pB,
    float* __restrict__ oLat, float* __restrict__ oP, float* __restrict__ oF,
    float* __restrict__ oA, float* __restrict__ oB)
{
    const int w   = blockIdx.x;
    const int b   = w / FULL, n = w - b * FULL;
    const int tid = threadIdx.x;
    const int lane = tid & 63, wid = tid >> 6;

    __shared__ __align__(16) short hT[248 * 40];     // 19840 B, stride 40
    __shared__ __align__(16) short hs[24 * 132];     // 6336 B
    __shared__ __align__(16) short latb[16 * 136];   // 4352 B
    __shared__ float lat[EMB * 122];                 // 3904 B
    __shared__ float S0[8], S1[8], vv[16], bm[8];

    for (int idx = tid; idx < 1240; idx += 256) ((uint4*)hT)[idx] = make_uint4(0,0,0,0);
    for (int idx = tid; idx < 272;  idx += 256) ((uint4*)latb)[idx] = make_uint4(0,0,0,0);
    if (tid < 8) { S0[tid] = 0.0f; S1[tid] = 0.0f; }

    for (int idx = tid; idx < INTER * TLEN; idx += 256) {
        int o = idx / TLEN, i = idx - o * TLEN;
        const unsigned short* h3 =
            (const unsigned short*)(Q + (size_t)(b * INTER + o) * (TLEN * FULL)) + n * TLEN;
        hs[o * 132 + i] = (short)h3[i];
    }
    __syncthreads();
    for (int idx = tid; idx < TLEN * 32; idx += 256) {
        int i = idx >> 5, o = idx & 31;
        short v = (o < INTER) ? hs[o * 132 + i] : (short)0;
        hT[(60 + i) * 40 + o] = v;
    }
    __syncthreads();

    const int m = lane & 15, quad = lane >> 4;
    const int t0 = wid * 32;

    // --- conv2 MFMA with 16-deep A ring: a1[tap] == a0[tap+16] ---
    f32x4 acc0 = {0.0f, 0.0f, 0.0f, 0.0f};
    f32x4 acc1 = {0.0f, 0.0f, 0.0f, 0.0f};
    const short* aptr = hT + (t0 + m) * 40 + quad * 8;
    s16x8 ring[16];
#pragma unroll
    for (int j = 0; j < 16; ++j) ring[j] = *(const s16x8*)(aptr + j * 40);

    for (int t16 = 0; t16 < 7; ++t16) {          // taps 0..111
#pragma unroll
        for (int j = 0; j < 16; ++j) {
            const int tap = t16 * 16 + j;
            s16x8 bw = *(const s16x8*)(w2f + tap * 512 + lane * 8);
            s16x8 nw = *(const s16x8*)(aptr + (tap + 16) * 40);
            acc0 = __builtin_amdgcn_mfma_f32_16x16x32_bf16(ring[j], bw, acc0, 0, 0, 0);
            acc1 = __builtin_amdgcn_mfma_f32_16x16x32_bf16(nw,      bw, acc1, 0, 0, 0);
            ring[j] = nw;
        }
    }
#pragma unroll
    for (int j = 0; j < 9; ++j) {                // taps 112..120
        const int tap = 112 + j;
        s16x8 bw = *(const s16x8*)(w2f + tap * 512 + lane * 8);
        s16x8 nw = *(const s16x8*)(aptr + (tap + 16) * 40);
        acc0 = __builtin_amdgcn_mfma_f32_16x16x32_bf16(ring[j], bw, acc0, 0, 0, 0);
        acc1 = __builtin_amdgcn_mfma_f32_16x16x32_bf16(nw,      bw, acc1, 0, 0, 0);
    }

    {
        const int e = lane & 15;
        if (e < EMB) {
            float bias = b2[e];
#pragma unroll
            for (int r = 0; r < 4; ++r) {
                int i0v = t0 + quad * 4 + r;
                if (i0v < TLEN) {
                    float v = acc0[r] + bias;
                    lat[e * 122 + i0v] = v;
                    latb[e * 136 + i0v] = (short)f2bf(v);
                }
                int i1v = t0 + 16 + quad * 4 + r;
                if (i1v < TLEN) {
                    float v = acc1[r] + bias;
                    lat[e * 122 + i1v] = v;
                    latb[e * 136 + i1v] = (short)f2bf(v);
                }
            }
        }
    }
    __syncthreads();

    // --- DFT via MFMA ---
    {
        f32x4 accR = {0.0f, 0.0f, 0.0f, 0.0f};
        f32x4 accI = {0.0f, 0.0f, 0.0f, 0.0f};
#pragma unroll
        for (int ch = 0; ch < 4; ++ch) {
            s16x8 a  = *(const s16x8*)(latb + (lane & 15) * 136 + quad * 8 + ch * 32);
            s16x8 br = *(const s16x8*)(w3f + (((ch * 8) + wid) * 64 + lane) * 8);
            s16x8 bi = *(const s16x8*)(w3f + (((ch * 8) + 4 + wid) * 64 + lane) * 8);
            accR = __builtin_amdgcn_mfma_f32_16x16x32_bf16(a, br, accR, 0, 0, 0);
            accI = __builtin_amdgcn_mfma_f32_16x16x32_bf16(a, bi, accI, 0, 0, 0);
        }
        const int colj = lane & 15;
        const int col  = wid * 16 + colj;
        const float fw = 0.5f * (float)(col + 1);
#pragma unroll
        for (int r = 0; r < 4; ++r) {
            float pw = (col < 60) ? (accR[r] * accR[r] + accI[r] * accI[r]) : 0.0f;
            float s1 = pw * fw;
#pragma unroll
            for (int off = 1; off < 16; off <<= 1) {
                pw += __shfl_xor(pw, off);
                s1 += __shfl_xor(s1, off);
            }
            if (colj == 0) {
                int e = quad * 4 + r;
                if (e < EMB) { atomicAdd(&S0[e], pw); atomicAdd(&S1[e], s1); }
            }
        }
    }
    // --- fc ---
    if (tid < 16) {
        int e_ = tid >> 1, kk = tid & 1;
        float accv = fcb[e_ * 2 + kk];
        const float* fr = fcw + (e_ * 2 + kk) * TLEN;
        for (int t = 0; t < TLEN; ++t) accv += lat[e_ * 122 + t] * fr[t];
        vv[tid] = accv;
    }
    if (tid >= 32 && tid < 40) {
        int e_ = tid - 32;
        float s = 0.0f;
        for (int t = 0; t < TLEN; ++t) s += lat[e_ * 122 + t];
        bm[e_] = s * (1.0f / 121.0f);
    }
    __syncthreads();

    if (tid < 8) {
        int e_ = tid;
        float fv = S1[e_] / S0[e_];
        float av = 2.0f * sqrtf(S0[e_]) * (1.0f / 121.0f);
        float pv = atan2f(vv[2 * e_ + 1], vv[2 * e_]) * 0.15915494309189535f;
        float bv = bm[e_];
        int gi = w * 8 + e_;
        pP[gi] = pv; pF[gi] = fv; pA[gi] = av; pB[gi] = bv;
        if (n == 0) {
            oP[b * 8 + e_] = pv;
            oF[b * 8 + e_] = fv;
            oA[b * 8 + e_] = av;
            oB[b * 8 + e_] = bv;
        }
    }
    if (n == 0) {
        for (int idx = tid; idx < EMB * TLEN; idx += 256) {
            int e_ = idx / TLEN, i = idx - e_ * TLEN;
            oLat[(b * EMB + e_) * TLEN + i] = lat[e_ * 122 + i];
        }
    }
}

// ---------------------------------------------------------------------------
// k_signal: sinusoid resynthesis + overlap-add, gather form.
// ---------------------------------------------------------------------------
__global__ __launch_bounds__(256) void k_signal(
    const float* __restrict__ pP, const float* __restrict__ pF,
    const float* __restrict__ pA, const float* __restrict__ pB,
    float* __restrict__ sig, float* __restrict__ oSig)
{
    const int blk = blockIdx.x;
    const int b = blk >> 3, e = blk & 7;
    const int tid = threadIdx.x;
    __shared__ float sp[FULL], sf[FULL], sa[FULL], sb[FULL];
    for (int nn = tid; nn < FULL; nn += 256) {
        int gi = (b * FULL + nn) * 8 + e;
        sp[nn] = pP[gi]; sf[nn] = pF[gi]; sa[nn] = pA[gi]; sb[nn] = pB[gi];
    }
    __syncthreads();
    for (int u = tid; u < LP; u += 256) {
        int nlo = (u - 120 > 0) ? (u - 120) : 0;
        int nhi = (u < 239) ? u : 239;
        float s = 0.0f;
        for (int nn = nlo; nn <= nhi; ++nn) {
            float tt = (float)(u - nn);
            float z = sf[nn] * (tt * (1.0f / 60.0f) - 1.0f) + sp[nn];
            z -= floorf(z);
            s += sa[nn] * sinf(6.2831853071795864f * z) + sb[nn];
        }
        float wgt = (u < TLEN) ? (float)(u + 1) : ((u > 239) ? (float)(LP - u) : 121.0f);
        float val = s / wgt;
        sig[(b * EMB + e) * LP + u] = val;
        if (u < TLEN) oSig[(b * EMB + e) * TLEN + u] = val;
    }
}

// ---------------------------------------------------------------------------
// k_dec1: decoder conv1. Block = (b,o), 384 x 256 thr; 4 waves x 2 channels,
// LDS partial-sum reduce; weights via block-uniform global reads.
// ---------------------------------------------------------------------------
__global__ __launch_bounds__(256) void k_dec1(
    const float* __restrict__ sig, const float* __restrict__ dw1, const float* __restrict__ db1,
    float* __restrict__ dbuf, float* __restrict__ bns)
{
    const int blk = blockIdx.x;            // b*24 + o
    const int b = blk / INTER, o = blk - b * INTER;
    const int tid = threadIdx.x;
    const int lane = tid & 63, wid = tid >> 6;
    __shared__ __align__(16) float ycp[EMB * 364];   // 11648 B
    __shared__ __align__(16) float part[4][240];     // 3840 B
    for (int idx = tid; idx < EMB * 364; idx += 256) {
        int c = idx / 364, q = idx - c * 364;
        float v = 0.0f;
        if (q >= 60 && q < 300) v = sig[(b * EMB + c) * LP + q];
        ycp[idx] = v;
    }
    __syncthreads();
    const int te = (lane < 60) ? lane : 59;
    float a0 = 0.0f, a1 = 0.0f, a2 = 0.0f, a3 = 0.0f;
    for (int cl = 0; cl < 2; ++cl) {
        const int c = wid * 2 + cl;
        const float* wr = dw1 + (o * EMB + c) * TLEN;
        const float* base = ycp + c * 364 + 4 * te;
        float4 cur = *(const float4*)base;
        for (int kb = 0; kb < 30; ++kb) {
            float4 nxt = *(const float4*)(base + 4 * kb + 4);
            float w0 = wr[4*kb], w1 = wr[4*kb+1], w2 = wr[4*kb+2], w3 = wr[4*kb+3];
            a0 += w0*cur.x; a1 += w0*cur.y; a2 += w0*cur.z; a3 += w0*cur.w;
            a0 += w1*cur.y; a1 += w1*cur.z; a2 += w1*cur.w; a3 += w1*nxt.x;
            a0 += w2*cur.z; a1 += w2*cur.w; a2 += w2*nxt.x; a3 += w2*nxt.y;
            a0 += w3*cur.w; a1 += w3*nxt.x; a2 += w3*nxt.y; a3 += w3*nxt.z;
            cur = nxt;
        }
        float wl = wr[120];
        a0 += wl*cur.x; a1 += wl*cur.y; a2 += wl*cur.z; a3 += wl*cur.w;
    }
    if (lane < 60) {
        float4* dst = (float4*)&part[wid][4 * lane];
        *dst = make_float4(a0, a1, a2, a3);
    }
    __syncthreads();
    float s = 0.0f, s2 = 0.0f;
    if (tid < 60) {
        const float bias = db1[o];
        float4 f;
        f.x = part[0][4*tid+0] + part[1][4*tid+0] + part[2][4*tid+0] + part[3][4*tid+0] + bias;
        f.y = part[0][4*tid+1] + part[1][4*tid+1] + part[2][4*tid+1] + part[3][4*tid+1] + bias;
        f.z = part[0][4*tid+2] + part[1][4*tid+2] + part[2][4*tid+2] + part[3][4*tid+2] + bias;
        f.w = part[0][4*tid+3] + part[1][4*tid+3] + part[2][4*tid+3] + part[3][4*tid+3] + bias;
        *(float4*)(dbuf + (b * INTER + o) * FULL + 4 * tid) = f;
        s  = f.x + f.y + f.z + f.w;
        s2 = f.x*f.x + f.y*f.y + f.z*f.z + f.w*f.w;
    }
    if (wid == 0) {
        for (int d = 32; d > 0; d >>= 1) { s += __shfl_down(s, d); s2 += __shfl_down(s2, d); }
        if (tid == 0) { atomicAdd(&bns[o], s); atomicAdd(&bns[24 + o], s2); }
    }
}

// ---------------------------------------------------------------------------
// k_dec2: decoder conv2 with fused BN+tanh staging. Block = (b,oc),
// 1152 x 256 thr; 4 waves x 6 channels, LDS partial-sum reduce.
// ---------------------------------------------------------------------------
__global__ __launch_bounds__(256) void k_dec2(
    const float* __restrict__ dbuf, const float* __restrict__ bns,
    const float* __restrict__ gma, const float* __restrict__ bta,
    const float* __restrict__ dw2, const float* __restrict__ db2,
    float* __restrict__ oY, float* __restrict__ oYp)
{
    const int blk = blockIdx.x;            // b*72 + oc
    const int b = blk / INCH, oc = blk - b * INCH;
    const int tid = threadIdx.x;
    const int lane = tid & 63, wid = tid >> 6;
    __shared__ __align__(16) float sdp[INTER * 364]; // 34944 B
    __shared__ __align__(16) float part[4][240];     // 3840 B
    __shared__ float scl[INTER], sft[INTER];
    if (tid < INTER) {
        float m  = bns[tid] * (1.0f / 3840.0f);
        float v  = bns[24 + tid] * (1.0f / 3840.0f) - m * m;
        float rs = rsqrtf(fmaxf(v, 0.0f) + 1e-5f);
        float g  = gma[tid];
        scl[tid] = rs * g;
        sft[tid] = bta[tid] - m * rs * g;
    }
    __syncthreads();
    for (int idx = tid; idx < INTER * 364; idx += 256) {
        int c = idx / 364, q = idx - c * 364;
        float v = 0.0f;
        if (q >= 60 && q < 300)
            v = tanhf(dbuf[(b * INTER + c) * FULL + (q - 60)] * scl[c] + sft[c]);
        sdp[idx] = v;
    }
    __syncthreads();
    const int te = (lane < 60) ? lane : 59;
    float a0 = 0.0f, a1 = 0.0f, a2 = 0.0f, a3 = 0.0f;
    for (int cl = 0; cl < 6; ++cl) {
        const int c = wid * 6 + cl;
        const float* wr = dw2 + (oc * INTER + c) * TLEN;
        const float* base = sdp + c * 364 + 4 * te;
        float4 cur = *(const float4*)base;
        for (int kb = 0; kb < 30; ++kb) {
            float4 nxt = *(const float4*)(base + 4 * kb + 4);
            float w0 = wr[4*kb], w1 = wr[4*kb+1], w2 = wr[4*kb+2], w3 = wr[4*kb+3];
            a0 += w0*cur.x; a1 += w0*cur.y; a2 += w0*cur.z; a3 += w0*cur.w;
            a0 += w1*cur.y; a1 += w1*cur.z; a2 += w1*cur.w; a3 += w1*nxt.x;
            a0 += w2*cur.z; a1 += w2*cur.w; a2 += w2*nxt.x; a3 += w2*nxt.y;
            a0 += w3*cur.w; a1 += w3*nxt.x; a2 += w3*nxt.y; a3 += w3*nxt.z;
            cur = nxt;
        }
        float wl = wr[120];
        a0 += wl*cur.x; a1 += wl*cur.y; a2 += wl*cur.z; a3 += wl*cur.w;
    }
    if (lane < 60) {
        float4* dst = (float4*)&part[wid][4 * lane];
        *dst = make_float4(a0, a1, a2, a3);
    }
    __syncthreads();
    if (tid < 60) {
        const float bias = db2[oc];
        float4 f;
        f.x = part[0][4*tid+0] + part[1][4*tid+0] + part[2][4*tid+0] + part[3][4*tid+0] + bias;
        f.y = part[0][4*tid+1] + part[1][4*tid+1] + part[2][4*tid+1] + part[3][4*tid+1] + bias;
        f.z = part[0][4*tid+2] + part[1][4*tid+2] + part[2][4*tid+2] + part[3][4*tid+2] + bias;
        f.w = part[0][4*tid+3] + part[1][4*tid+3] + part[2][4*tid+3] + part[3][4*tid+3] + bias;
        const int i = 4 * tid;
        *(float4*)(oY + (b * INCH + oc) * FULL + i) = f;
        float* yp = oYp + (b * INCH + oc) * TLEN;
        if (i     < TLEN) yp[i]     = f.x;
        if (i + 1 < TLEN) yp[i + 1] = f.y;
        if (i + 2 < TLEN) yp[i + 2] = f.z;
        if (i + 3 < TLEN) yp[i + 3] = f.w;
    }
}

// ---------------------------------------------------------------------------
extern "C" void kernel_launch(void* const* d_in, const int* in_sizes, int n_in,
                              void* d_out, int out_size, void* d_ws, size_t ws_size,
                              hipStream_t stream)
{
    const float* x   = (const float*)d_in[0];
    const float* w1  = (const float*)d_in[1];
    const float* b1  = (const float*)d_in[2];
    const float* lna = (const float*)d_in[3];
    const float* lnb = (const float*)d_in[4];
    const float* w2  = (const float*)d_in[5];
    const float* b2  = (const float*)d_in[6];
    const float* fcw = (const float*)d_in[7];
    const float* fcb = (const float*)d_in[8];
    const float* dw1 = (const float*)d_in[9];
    const float* db1 = (const float*)d_in[10];
    const float* gma = (const float*)d_in[11];
    const float* bta = (const float*)d_in[12];
    const float* dw2 = (const float*)d_in[13];
    const float* db2 = (const float*)d_in[14];

    // Output layout (flat fp32, reference return order):
    float* out  = (float*)d_out;
    float* oY   = out;                 // [16][72][240]
    float* oLat = out + 276480;        // [16][8][121]
    float* oSig = out + 291968;        // [16][8][121]
    float* oP   = out + 307456;
    float* oF   = out + 307584;
    float* oA   = out + 307712;
    float* oB   = out + 307840;
    float* oYp  = out + 307968;        // [16][72][121]

    // Workspace layout (bytes; ws_size >= 46,436,544 proven in round 6):
    //   [0, 123904)           w2f bf16 fragments [121][64][8]
    //   [123904, 156672)      w3f bf16 DFT fragments
    //   [156672, 900096)      w1fA bf16 A-fragments [121][2][3][64][8]
    //   [900096, 1576128)     fp32: pP/pF/pA/pB (dbuf overlay), sig, bns
    //   [1576128, 46181568)   Q [16][24][121][240] fp32 (+h3 bf16 overlay)
    short* w2f  = (short*)d_ws;
    short* w3f  = (short*)((char*)d_ws + 123904);
    short* w1fA = (short*)((char*)d_ws + 156672);
    float* fb   = (float*)((char*)d_ws + 900096);
    float* pP   = fb;
    float* pF   = pP + 30720;
    float* pA   = pF + 30720;
    float* pB   = pA + 30720;
    float* dbuf = fb;                  // overlay (temporally disjoint)
    float* sig  = fb + 122880;         // 46080
    float* bns  = sig + 46080;         // 48
    float* Q    = (float*)((char*)d_ws + 1576128);

    hipMemsetAsync(bns, 0, 48 * sizeof(float), stream);
    k_prep_w2f<<<242, 256, 0, stream>>>(w2, w2f);
    k_prep_w3f<<<64, 256, 0, stream>>>(w3f);
    k_prep_w1fA<<<1452, 256, 0, stream>>>(w1, w1fA);
    k_q<<<256, 256, 0, stream>>>(x, w1fA, Q);
    k_gather_ln<<<384, 256, 0, stream>>>(Q, b1, lna, lnb);
    k_enc2<<<NWIN, 256, 0, stream>>>(Q, w2f, w3f, b2, fcw, fcb,
                                     pP, pF, pA, pB, oLat, oP, oF, oA, oB);
    k_signal<<<128, 256, 0, stream>>>(pP, pF, pA, pB, sig, oSig);
    k_dec1<<<384, 256, 0, stream>>>(sig, dw1, db1, dbuf, bns);
    k_dec2<<<16 * INCH, 256, 0, stream>>>(dbuf, bns, gma, bta, dw2, db2, oY, oYp);
}

// Round 12
// 419.260 us; speedup vs baseline: 20.1659x; 1.1334x over previous
//
#include <hip/hip_runtime.h>
#include <math.h>

// ---------------------------------------------------------------------------
// PAE pipeline on MI355X. Round 12:
//   k_gather_ln (137 us, 117KB-LDS latency-bound) split into:
//     k_prefix: in-place inclusive prefix over taps in global Q (row m -> R[m+1],
//               R[0] implicit zero). Coalesced, pipelined loads.
//     k_ln: reads R from global (L2-hot, coalesced; row index wave-uniform),
//           row R[121] staged in LDS (960B), two-pass LN + tanh, h3 staged in
//           58KB LDS then dumped over the dead R tile with uint4 stores.
//           59KB LDS -> 2 blocks/CU. Bit-identical arithmetic.
//   k_q / k_enc2 / k_signal / k_dec1 / k_dec2 / preps identical to round 11.
// ---------------------------------------------------------------------------

#define INCH   72
#define TLEN   121
#define FULL   240
#define INTER  24
#define EMB    8
#define LP     360
#define NWIN   3840

typedef __attribute__((ext_vector_type(8)))  short s16x8;
typedef __attribute__((ext_vector_type(4)))  float f32x4;

// fp32 -> bf16 (RNE) as raw ushort
__device__ __forceinline__ unsigned short f2bf(float f) {
    unsigned u = __float_as_uint(f);
    unsigned r = ((u >> 16) & 1u) + 0x7FFFu;
    return (unsigned short)((u + r) >> 16);
}

// ---------------------------------------------------------------------------
// w2 fragment prep: w2f[tap][lane][j] = w2[e=lane&15][c=(lane>>4)*8+j][tap].
// ---------------------------------------------------------------------------
__global__ __launch_bounds__(256) void k_prep_w2f(const float* __restrict__ w2,
                                                  short* __restrict__ w2f) {
    int idx = blockIdx.x * 256 + threadIdx.x;       // < 121*64*8 = 61952
    if (idx >= 61952) return;
    int j = idx & 7, ln = (idx >> 3) & 63, tap = idx >> 9;
    int e = ln & 15, c = (ln >> 4) * 8 + j;
    float v = (e < EMB && c < INTER) ? w2[(e * INTER + c) * TLEN + tap] : 0.0f;
    w2f[idx] = (short)f2bf(v);
}

// ---------------------------------------------------------------------------
// DFT trig fragments (B-frag of 16x16x32), verified round 9.
// ---------------------------------------------------------------------------
__global__ __launch_bounds__(256) void k_prep_w3f(short* __restrict__ w3f) {
    int idx = blockIdx.x * 256 + threadIdx.x;       // < 16384
    if (idx >= 16384) return;
    int j = idx & 7, ln = (idx >> 3) & 63, tl = (idx >> 9) & 7, ch = idx >> 12;
    int t = (ln >> 4) * 8 + j + ch * 32;
    int colIdx = (tl & 3) * 16 + (ln & 15);
    int k = colIdx + 1;
    float v = 0.0f;
    if (t < TLEN && colIdx < 60) {
        int mm = (k * t) % 121;
        float s, c;
        sincosf(6.2831853071795864f * (float)mm / 121.0f, &s, &c);
        v = (tl < 4) ? c : -s;
    }
    w3f[idx] = (short)f2bf(v);
}

// ---------------------------------------------------------------------------
// w1 A-fragments for k_q (verified round 11).
// ---------------------------------------------------------------------------
__global__ __launch_bounds__(256) void k_prep_w1fA(const float* __restrict__ w1,
                                                   short* __restrict__ w1fA) {
    int idx = blockIdx.x * 256 + threadIdx.x;       // < 121*2*3*64*8 = 371712
    if (idx >= 371712) return;
    int j = idx & 7, ln = (idx >> 3) & 63;
    int rest = idx >> 9;                 // tap*6 + ot*3 + ch
    int ch = rest % 3;
    int rest2 = rest / 3;                // tap*2 + ot
    int ot = rest2 & 1, tap = rest2 >> 1;
    int o = ot * 16 + (ln & 15);
    int c = (ln >> 4) * 8 + j + ch * 32;
    float v = (o < INTER && c < INCH) ? w1[(o * INCH + c) * TLEN + tap] : 0.0f;
    w1fA[idx] = (short)f2bf(v);
}

// ---------------------------------------------------------------------------
// k_q: Q[b][o][m][s] = sum_c w1[o,c,m] * x[b,c,(s+m)%240] via MFMA.
// (verified round 11)
// ---------------------------------------------------------------------------
__global__ __launch_bounds__(256) void k_q(
    const float* __restrict__ x, const short* __restrict__ w1fA,
    float* __restrict__ Q)
{
    const int blk = blockIdx.x;
    const int mg = blk & 7, sh = (blk >> 3) & 1, b = blk >> 4;
    const int tid = threadIdx.x;
    const int lane = tid & 63, wid = tid >> 6;
    const int s0 = sh * 120;
    __shared__ __align__(16) short xTb[248 * 104];   // 51584 B

    for (int idx = tid; idx < (248 * 104) / 8; idx += 256)
        ((uint4*)xTb)[idx] = make_uint4(0, 0, 0, 0);
    __syncthreads();
    for (int idx = tid; idx < 72 * 248; idx += 256) {
        int c = idx / 248, l = idx - c * 248;
        int g = s0 + l; g -= (g >= FULL) ? FULL : 0;
        xTb[l * 104 + c] = (short)f2bf(x[(b * INCH + c) * FULL + g]);
    }
    __syncthreads();

    const int ntaps = (mg < 7) ? 16 : 9;
    const int col = lane & 15, quad = lane >> 4;
    for (int j = 0; j < ntaps; ++j) {
        const int m = mg * 16 + j;
        s16x8 a[2][3];
#pragma unroll
        for (int ot = 0; ot < 2; ++ot)
#pragma unroll
            for (int ch = 0; ch < 3; ++ch)
                a[ot][ch] = *(const s16x8*)(w1fA + (((m * 2 + ot) * 3 + ch) * 64 + lane) * 8);
#pragma unroll
        for (int tt = 0; tt < 2; ++tt) {
            const int ts = (wid + tt * 4) * 16;          // s-tile base (0..112)
            const short* brow = xTb + (ts + col + m) * 104 + quad * 8;
            s16x8 b0 = *(const s16x8*)(brow);
            s16x8 b1 = *(const s16x8*)(brow + 32);
            s16x8 b2 = *(const s16x8*)(brow + 64);
            const int sl = ts + col;
#pragma unroll
            for (int ot = 0; ot < 2; ++ot) {
                f32x4 acc = {0.0f, 0.0f, 0.0f, 0.0f};
                acc = __builtin_amdgcn_mfma_f32_16x16x32_bf16(a[ot][0], b0, acc, 0, 0, 0);
                acc = __builtin_amdgcn_mfma_f32_16x16x32_bf16(a[ot][1], b1, acc, 0, 0, 0);
                acc = __builtin_amdgcn_mfma_f32_16x16x32_bf16(a[ot][2], b2, acc, 0, 0, 0);
                if (sl < 120) {
#pragma unroll
                    for (int r = 0; r < 4; ++r) {
                        int o = ot * 16 + quad * 4 + r;   // row = M index
                        if (o < INTER)
                            Q[((size_t)(b * INTER + o) * TLEN + m) * FULL + s0 + sl] = acc[r];
                    }
                }
            }
        }
    }
}

// ---------------------------------------------------------------------------
// k_prefix: in-place inclusive prefix over taps. After this, tile row m holds
// R[m+1] = sum_{m'<=m} Q[m']; R[0] is implicit zero.
// ---------------------------------------------------------------------------
__global__ __launch_bounds__(256) void k_prefix(float* __restrict__ Q)
{
    const int blk = blockIdx.x;          // b*24 + o
    const int tid = threadIdx.x;
    if (tid >= FULL) return;
    float* Qg = Q + (size_t)blk * (TLEN * FULL) + tid;
    float P = 0.0f;
    for (int m = 0; m < TLEN; ++m) {
        P += Qg[m * FULL];
        Qg[m * FULL] = P;
    }
}

// ---------------------------------------------------------------------------
// k_ln: conv1 diff from global R (coalesced, L2-hot; row R[121] in LDS) +
// LN(ddof=1, /(std+eps)) + tanh -> bf16 h3 staged in LDS, dumped over the
// dead R tile after a barrier. Bit-identical arithmetic to round 11.
// ---------------------------------------------------------------------------
__global__ __launch_bounds__(256) void k_ln(
    float* __restrict__ Q, const float* __restrict__ b1,
    const float* __restrict__ lna, const float* __restrict__ lnb)
{
    const int blk = blockIdx.x;          // b*24 + o
    const int o = blk % INTER;
    const int tid = threadIdx.x;
    __shared__ float r121[FULL];                         // 960 B (R[121])
    __shared__ __align__(16) unsigned short hls[FULL * TLEN]; // 58080 B
    float* Rg = Q + (size_t)blk * (TLEN * FULL);         // rows 0..120 = R[1..121]
    for (int idx = tid; idx < FULL; idx += 256)
        r121[idx] = Rg[120 * FULL + idx];
    __syncthreads();
    if (tid < FULL) {
        const int n = tid;
        const float bias = b1[o];
        float s = 0.0f, s2 = 0.0f;
        // pass 1: stats (i ascending, same accumulation order as before)
        for (int i = 0; i < 60; ++i) {                   // lo = 60-i >= 1
            int st = n + i - 120; st += (st < 0) ? FULL : 0;
            float v = r121[st] - Rg[(59 - i) * FULL + st] + bias;
            s += v; s2 += v * v;
        }
        {                                                // i = 60: lo = 0
            int st = n - 60; st += (st < 0) ? FULL : 0;
            float v = r121[st] + bias;
            s += v; s2 += v * v;
        }
        for (int i = 61; i < TLEN; ++i) {                // up = 181-i, lo = 0
            int st = n + i - 120; st += (st < 0) ? FULL : 0;
            float v = Rg[(180 - i) * FULL + st] + bias;
            s += v; s2 += v * v;
        }
        float mean = s * (1.0f / 121.0f);
        float var  = fmaxf((s2 - s * mean) * (1.0f / 120.0f), 0.0f);   // ddof=1
        float inv  = 1.0f / (sqrtf(var) + 1e-5f);                      // (std+eps)
        // pass 2: transform + tanh -> LDS
        unsigned short* hrow = hls + n * TLEN;
        for (int i = 0; i < 60; ++i) {
            int st = n + i - 120; st += (st < 0) ? FULL : 0;
            float v = r121[st] - Rg[(59 - i) * FULL + st] + bias;
            v = (v - mean) * inv * lna[i] + lnb[i];
            hrow[i] = f2bf(tanhf(v));
        }
        {
            int st = n - 60; st += (st < 0) ? FULL : 0;
            float v = r121[st] + bias;
            v = (v - mean) * inv * lna[60] + lnb[60];
            hrow[60] = f2bf(tanhf(v));
        }
        for (int i = 61; i < TLEN; ++i) {
            int st = n + i - 120; st += (st < 0) ? FULL : 0;
            float v = Rg[(180 - i) * FULL + st] + bias;
            v = (v - mean) * inv * lna[i] + lnb[i];
            hrow[i] = f2bf(tanhf(v));
        }
    }
    __syncthreads();
    // dump h3 (58080 B = 3630 uint4) over the dead R tile, coalesced
    uint4* dst = (uint4*)Rg;
    const uint4* src = (const uint4*)hls;
    for (int idx = tid; idx < 3630; idx += 256) dst[idx] = src[idx];
}

// ---------------------------------------------------------------------------
// k_enc2: per-window conv2 MFMA (ring-buffered A) + DFT-MFMA + fc/b.
// (verified rounds 9-11)
// ---------------------------------------------------------------------------
__global__ __launch_bounds__(256) void k_enc2(
    const float* __restrict__ Q, const short* __restrict__ w2f,
    const short* __restrict__ w3f, const float* __restrict__ b2,
    const float* __restrict__ fcw, const float* __restrict__ fcb,
    float* __restrict__ pP, float* __restrict__ pF, float* __restrict__ pA, float* __restrict__ pB,
    float* __restrict__ oLat, float* __restrict__ oP, float* __restrict__ oF,
    float* __restrict__ oA, float* __restrict__ oB)
{
    const int w   = blockIdx.x;
    const int b   = w / FULL, n = w - b * FULL;
    const int tid = threadIdx.x;
    const int lane = tid & 63, wid = tid >> 6;

    __shared__ __align__(16) short hT[248 * 40];     // 19840 B, stride 40
    __shared__ __align__(16) short hs[24 * 132];     // 6336 B
    __shared__ __align__(16) short latb[16 * 136];   // 4352 B
    __shared__ float lat[EMB * 122];                 // 3904 B
    __shared__ float S0[8], S1[8], vv[16], bm[8];

    for (int idx = tid; idx < 1240; idx += 256) ((uint4*)hT)[idx] = make_uint4(0,0,0,0);
    for (int idx = tid; idx < 272;  idx += 256) ((uint4*)latb)[idx] = make_uint4(0,0,0,0);
    if (tid < 8) { S0[tid] = 0.0f; S1[tid] = 0.0f; }

    for (int idx = tid; idx < INTER * TLEN; idx += 256) {
        int o = idx / TLEN, i = idx - o * TLEN;
        const unsigned short* h3 =
            (const unsigned short*)(Q + (size_t)(b * INTER + o) * (TLEN * FULL)) + n * TLEN;
        hs[o * 132 + i] = (short)h3[i];
    }
    __syncthreads();
    for (int idx = tid; idx < TLEN * 32; idx += 256) {
        int i = idx >> 5, o = idx & 31;
        short v = (o < INTER) ? hs[o * 132 + i] : (short)0;
        hT[(60 + i) * 40 + o] = v;
    }
    __syncthreads();

    const int m = lane & 15, quad = lane >> 4;
    const int t0 = wid * 32;

    // --- conv2 MFMA with 16-deep A ring: a1[tap] == a0[tap+16] ---
    f32x4 acc0 = {0.0f, 0.0f, 0.0f, 0.0f};
    f32x4 acc1 = {0.0f, 0.0f, 0.0f, 0.0f};
    const short* aptr = hT + (t0 + m) * 40 + quad * 8;
    s16x8 ring[16];
#pragma unroll
    for (int j = 0; j < 16; ++j) ring[j] = *(const s16x8*)(aptr + j * 40);

    for (int t16 = 0; t16 < 7; ++t16) {          // taps 0..111
#pragma unroll
        for (int j = 0; j < 16; ++j) {
            const int tap = t16 * 16 + j;
            s16x8 bw = *(const s16x8*)(w2f + tap * 512 + lane * 8);
            s16x8 nw = *(const s16x8*)(aptr + (tap + 16) * 40);
            acc0 = __builtin_amdgcn_mfma_f32_16x16x32_bf16(ring[j], bw, acc0, 0, 0, 0);
            acc1 = __builtin_amdgcn_mfma_f32_16x16x32_bf16(nw,      bw, acc1, 0, 0, 0);
            ring[j] = nw;
        }
    }
#pragma unroll
    for (int j = 0; j < 9; ++j) {                // taps 112..120
        const int tap = 112 + j;
        s16x8 bw = *(const s16x8*)(w2f + tap * 512 + lane * 8);
        s16x8 nw = *(const s16x8*)(aptr + (tap + 16) * 40);
        acc0 = __builtin_amdgcn_mfma_f32_16x16x32_bf16(ring[j], bw, acc0, 0, 0, 0);
        acc1 = __builtin_amdgcn_mfma_f32_16x16x32_bf16(nw,      bw, acc1, 0, 0, 0);
    }

    {
        const int e = lane & 15;
        if (e < EMB) {
            float bias = b2[e];
#pragma unroll
            for (int r = 0; r < 4; ++r) {
                int i0v = t0 + quad * 4 + r;
                if (i0v < TLEN) {
                    float v = acc0[r] + bias;
                    lat[e * 122 + i0v] = v;
                    latb[e * 136 + i0v] = (short)f2bf(v);
                }
                int i1v = t0 + 16 + quad * 4 + r;
                if (i1v < TLEN) {
                    float v = acc1[r] + bias;
                    lat[e * 122 + i1v] = v;
                    latb[e * 136 + i1v] = (short)f2bf(v);
                }
            }
        }
    }
    __syncthreads();

    // --- DFT via MFMA ---
    {
        f32x4 accR = {0.0f, 0.0f, 0.0f, 0.0f};
        f32x4 accI = {0.0f, 0.0f, 0.0f, 0.0f};
#pragma unroll
        for (int ch = 0; ch < 4; ++ch) {
            s16x8 a  = *(const s16x8*)(latb + (lane & 15) * 136 + quad * 8 + ch * 32);
            s16x8 br = *(const s16x8*)(w3f + (((ch * 8) + wid) * 64 + lane) * 8);
            s16x8 bi = *(const s16x8*)(w3f + (((ch * 8) + 4 + wid) * 64 + lane) * 8);
            accR = __builtin_amdgcn_mfma_f32_16x16x32_bf16(a, br, accR, 0, 0, 0);
            accI = __builtin_amdgcn_mfma_f32_16x16x32_bf16(a, bi, accI, 0, 0, 0);
        }
        const int colj = lane & 15;
        const int col  = wid * 16 + colj;
        const float fw = 0.5f * (float)(col + 1);
#pragma unroll
        for (int r = 0; r < 4; ++r) {
            float pw = (col < 60) ? (accR[r] * accR[r] + accI[r] * accI[r]) : 0.0f;
            float s1 = pw * fw;
#pragma unroll
            for (int off = 1; off < 16; off <<= 1) {
                pw += __shfl_xor(pw, off);
                s1 += __shfl_xor(s1, off);
            }
            if (colj == 0) {
                int e = quad * 4 + r;
                if (e < EMB) { atomicAdd(&S0[e], pw); atomicAdd(&S1[e], s1); }
            }
        }
    }
    // --- fc ---
    if (tid < 16) {
        int e_ = tid >> 1, kk = tid & 1;
        float accv = fcb[e_ * 2 + kk];
        const float* fr = fcw + (e_ * 2 + kk) * TLEN;
        for (int t = 0; t < TLEN; ++t) accv += lat[e_ * 122 + t] * fr[t];
        vv[tid] = accv;
    }
    if (tid >= 32 && tid < 40) {
        int e_ = tid - 32;
        float s = 0.0f;
        for (int t = 0; t < TLEN; ++t) s += lat[e_ * 122 + t];
        bm[e_] = s * (1.0f / 121.0f);
    }
    __syncthreads();

    if (tid < 8) {
        int e_ = tid;
        float fv = S1[e_] / S0[e_];
        float av = 2.0f * sqrtf(S0[e_]) * (1.0f / 121.0f);
        float pv = atan2f(vv[2 * e_ + 1], vv[2 * e_]) * 0.15915494309189535f;
        float bv = bm[e_];
        int gi = w * 8 + e_;
        pP[gi] = pv; pF[gi] = fv; pA[gi] = av; pB[gi] = bv;
        if (n == 0) {
            oP[b * 8 + e_] = pv;
            oF[b * 8 + e_] = fv;
            oA[b * 8 + e_] = av;
            oB[b * 8 + e_] = bv;
        }
    }
    if (n == 0) {
        for (int idx = tid; idx < EMB * TLEN; idx += 256) {
            int e_ = idx / TLEN, i = idx - e_ * TLEN;
            oLat[(b * EMB + e_) * TLEN + i] = lat[e_ * 122 + i];
        }
    }
}

// ---------------------------------------------------------------------------
// k_signal: sinusoid resynthesis + overlap-add, gather form.
// ---------------------------------------------------------------------------
__global__ __launch_bounds__(256) void k_signal(
    const float* __restrict__ pP, const float* __restrict__ pF,
    const float* __restrict__ pA, const float* __restrict__ pB,
    float* __restrict__ sig, float* __restrict__ oSig)
{
    const int blk = blockIdx.x;
    const int b = blk >> 3, e = blk & 7;
    const int tid = threadIdx.x;
    __shared__ float sp[FULL], sf[FULL], sa[FULL], sb[FULL];
    for (int nn = tid; nn < FULL; nn += 256) {
        int gi = (b * FULL + nn) * 8 + e;
        sp[nn] = pP[gi]; sf[nn] = pF[gi]; sa[nn] = pA[gi]; sb[nn] = pB[gi];
    }
    __syncthreads();
    for (int u = tid; u < LP; u += 256) {
        int nlo = (u - 120 > 0) ? (u - 120) : 0;
        int nhi = (u < 239) ? u : 239;
        float s = 0.0f;
        for (int nn = nlo; nn <= nhi; ++nn) {
            float tt = (float)(u - nn);
            float z = sf[nn] * (tt * (1.0f / 60.0f) - 1.0f) + sp[nn];
            z -= floorf(z);
            s += sa[nn] * sinf(6.2831853071795864f * z) + sb[nn];
        }
        float wgt = (u < TLEN) ? (float)(u + 1) : ((u > 239) ? (float)(LP - u) : 121.0f);
        float val = s / wgt;
        sig[(b * EMB + e) * LP + u] = val;
        if (u < TLEN) oSig[(b * EMB + e) * TLEN + u] = val;
    }
}

// ---------------------------------------------------------------------------
// k_dec1: decoder conv1. Block = (b,o), 384 x 256 thr; 4 waves x 2 channels,
// LDS partial-sum reduce; weights via block-uniform global reads.
// ---------------------------------------------------------------------------
__global__ __launch_bounds__(256) void k_dec1(
    const float* __restrict__ sig, const float* __restrict__ dw1, const float* __restrict__ db1,
    float* __restrict__ dbuf, float* __restrict__ bns)
{
    const int blk = blockIdx.x;            // b*24 + o
    const int b = blk / INTER, o = blk - b * INTER;
    const int tid = threadIdx.x;
    const int lane = tid & 63, wid = tid >> 6;
    __shared__ __align__(16) float ycp[EMB * 364];   // 11648 B
    __shared__ __align__(16) float part[4][240];     // 3840 B
    for (int idx = tid; idx < EMB * 364; idx += 256) {
        int c = idx / 364, q = idx - c * 364;
        float v = 0.0f;
        if (q >= 60 && q < 300) v = sig[(b * EMB + c) * LP + q];
        ycp[idx] = v;
    }
    __syncthreads();
    const int te = (lane < 60) ? lane : 59;
    float a0 = 0.0f, a1 = 0.0f, a2 = 0.0f, a3 = 0.0f;
    for (int cl = 0; cl < 2; ++cl) {
        const int c = wid * 2 + cl;
        const float* wr = dw1 + (o * EMB + c) * TLEN;
        const float* base = ycp + c * 364 + 4 * te;
        float4 cur = *(const float4*)base;
        for (int kb = 0; kb < 30; ++kb) {
            float4 nxt = *(const float4*)(base + 4 * kb + 4);
            float w0 = wr[4*kb], w1 = wr[4*kb+1], w2 = wr[4*kb+2], w3 = wr[4*kb+3];
            a0 += w0*cur.x; a1 += w0*cur.y; a2 += w0*cur.z; a3 += w0*cur.w;
            a0 += w1*cur.y; a1 += w1*cur.z; a2 += w1*cur.w; a3 += w1*nxt.x;
            a0 += w2*cur.z; a1 += w2*cur.w; a2 += w2*nxt.x; a3 += w2*nxt.y;
            a0 += w3*cur.w; a1 += w3*nxt.x; a2 += w3*nxt.y; a3 += w3*nxt.z;
            cur = nxt;
        }
        float wl = wr[120];
        a0 += wl*cur.x; a1 += wl*cur.y; a2 += wl*cur.z; a3 += wl*cur.w;
    }
    if (lane < 60) {
        float4* dst = (float4*)&part[wid][4 * lane];
        *dst = make_float4(a0, a1, a2, a3);
    }
    __syncthreads();
    float s = 0.0f, s2 = 0.0f;
    if (tid < 60) {
        const float bias = db1[o];
        float4 f;
        f.x = part[0][4*tid+0] + part[1][4*tid+0] + part[2][4*tid+0] + part[3][4*tid+0] + bias;
        f.y = part[0][4*tid+1] + part[1][4*tid+1] + part[2][4*tid+1] + part[3][4*tid+1] + bias;
        f.z = part[0][4*tid+2] + part[1][4*tid+2] + part[2][4*tid+2] + part[3][4*tid+2] + bias;
        f.w = part[0][4*tid+3] + part[1][4*tid+3] + part[2][4*tid+3] + part[3][4*tid+3] + bias;
        *(float4*)(dbuf + (b * INTER + o) * FULL + 4 * tid) = f;
        s  = f.x + f.y + f.z + f.w;
        s2 = f.x*f.x + f.y*f.y + f.z*f.z + f.w*f.w;
    }
    if (wid == 0) {
        for (int d = 32; d > 0; d >>= 1) { s += __shfl_down(s, d); s2 += __shfl_down(s2, d); }
        if (tid == 0) { atomicAdd(&bns[o], s); atomicAdd(&bns[24 + o], s2); }
    }
}

// ---------------------------------------------------------------------------
// k_dec2: decoder conv2 with fused BN+tanh staging. Block = (b,oc),
// 1152 x 256 thr; 4 waves x 6 channels, LDS partial-sum reduce.
// ---------------------------------------------------------------------------
__global__ __launch_bounds__(256) void k_dec2(
    const float* __restrict__ dbuf, const float* __restrict__ bns,
    const float* __restrict__ gma, const float* __restrict__ bta,
    const float* __restrict__ dw2, const float* __restrict__ db2,
    float* __restrict__ oY, float* __restrict__ oYp)
{
    const int blk = blockIdx.x;            // b*72 + oc
    const int b = blk / INCH, oc = blk - b * INCH;
    const int tid = threadIdx.x;
    const int lane = tid & 63, wid = tid >> 6;
    __shared__ __align__(16) float sdp[INTER * 364]; // 34944 B
    __shared__ __align__(16) float part[4][240];     // 3840 B
    __shared__ float scl[INTER], sft[INTER];
    if (tid < INTER) {
        float m  = bns[tid] * (1.0f / 3840.0f);
        float v  = bns[24 + tid] * (1.0f / 3840.0f) - m * m;
        float rs = rsqrtf(fmaxf(v, 0.0f) + 1e-5f);
        float g  = gma[tid];
        scl[tid] = rs * g;
        sft[tid] = bta[tid] - m * rs * g;
    }
    __syncthreads();
    for (int idx = tid; idx < INTER * 364; idx += 256) {
        int c = idx / 364, q = idx - c * 364;
        float v = 0.0f;
        if (q >= 60 && q < 300)
            v = tanhf(dbuf[(b * INTER + c) * FULL + (q - 60)] * scl[c] + sft[c]);
        sdp[idx] = v;
    }
    __syncthreads();
    const int te = (lane < 60) ? lane : 59;
    float a0 = 0.0f, a1 = 0.0f, a2 = 0.0f, a3 = 0.0f;
    for (int cl = 0; cl < 6; ++cl) {
        const int c = wid * 6 + cl;
        const float* wr = dw2 + (oc * INTER + c) * TLEN;
        const float* base = sdp + c * 364 + 4 * te;
        float4 cur = *(const float4*)base;
        for (int kb = 0; kb < 30; ++kb) {
            float4 nxt = *(const float4*)(base + 4 * kb + 4);
            float w0 = wr[4*kb], w1 = wr[4*kb+1], w2 = wr[4*kb+2], w3 = wr[4*kb+3];
            a0 += w0*cur.x; a1 += w0*cur.y; a2 += w0*cur.z; a3 += w0*cur.w;
            a0 += w1*cur.y; a1 += w1*cur.z; a2 += w1*cur.w; a3 += w1*nxt.x;
            a0 += w2*cur.z; a1 += w2*cur.w; a2 += w2*nxt.x; a3 += w2*nxt.y;
            a0 += w3*cur.w; a1 += w3*nxt.x; a2 += w3*nxt.y; a3 += w3*nxt.z;
            cur = nxt;
        }
        float wl = wr[120];
        a0 += wl*cur.x; a1 += wl*cur.y; a2 += wl*cur.z; a3 += wl*cur.w;
    }
    if (lane < 60) {
        float4* dst = (float4*)&part[wid][4 * lane];
        *dst = make_float4(a0, a1, a2, a3);
    }
    __syncthreads();
    if (tid < 60) {
        const float bias = db2[oc];
        float4 f;
        f.x = part[0][4*tid+0] + part[1][4*tid+0] + part[2][4*tid+0] + part[3][4*tid+0] + bias;
        f.y = part[0][4*tid+1] + part[1][4*tid+1] + part[2][4*tid+1] + part[3][4*tid+1] + bias;
        f.z = part[0][4*tid+2] + part[1][4*tid+2] + part[2][4*tid+2] + part[3][4*tid+2] + bias;
        f.w = part[0][4*tid+3] + part[1][4*tid+3] + part[2][4*tid+3] + part[3][4*tid+3] + bias;
        const int i = 4 * tid;
        *(float4*)(oY + (b * INCH + oc) * FULL + i) = f;
        float* yp = oYp + (b * INCH + oc) * TLEN;
        if (i     < TLEN) yp[i]     = f.x;
        if (i + 1 < TLEN) yp[i + 1] = f.y;
        if (i + 2 < TLEN) yp[i + 2] = f.z;
        if (i + 3 < TLEN) yp[i + 3] = f.w;
    }
}

// ---------------------------------------------------------------------------
extern "C" void kernel_launch(void* const* d_in, const int* in_sizes, int n_in,
                              void* d_out, int out_size, void* d_ws, size_t ws_size,
                              hipStream_t stream)
{
    const float* x   = (const float*)d_in[0];
    const float* w1  = (const float*)d_in[1];
    const float* b1  = (const float*)d_in[2];
    const float* lna = (const float*)d_in[3];
    const float* lnb = (const float*)d_in[4];
    const float* w2  = (const float*)d_in[5];
    const float* b2  = (const float*)d_in[6];
    const float* fcw = (const float*)d_in[7];
    const float* fcb = (const float*)d_in[8];
    const float* dw1 = (const float*)d_in[9];
    const float* db1 = (const float*)d_in[10];
    const float* gma = (const float*)d_in[11];
    const float* bta = (const float*)d_in[12];
    const float* dw2 = (const float*)d_in[13];
    const float* db2 = (const float*)d_in[14];

    // Output layout (flat fp32, reference return order):
    float* out  = (float*)d_out;
    float* oY   = out;                 // [16][72][240]
    float* oLat = out + 276480;        // [16][8][121]
    float* oSig = out + 291968;        // [16][8][121]
    float* oP   = out + 307456;
    float* oF   = out + 307584;
    float* oA   = out + 307712;
    float* oB   = out + 307840;
    float* oYp  = out + 307968;        // [16][72][121]

    // Workspace layout (bytes; ws_size >= 46,436,544 proven in round 6):
    //   [0, 123904)           w2f bf16 fragments [121][64][8]
    //   [123904, 156672)      w3f bf16 DFT fragments
    //   [156672, 900096)      w1fA bf16 A-fragments [121][2][3][64][8]
    //   [900096, 1576128)     fp32: pP/pF/pA/pB (dbuf overlay), sig, bns
    //   [1576128, 46181568)   Q [16][24][121][240] fp32 -> R in-place
    //                         -> h3 bf16 overlay after k_ln
    short* w2f  = (short*)d_ws;
    short* w3f  = (short*)((char*)d_ws + 123904);
    short* w1fA = (short*)((char*)d_ws + 156672);
    float* fb   = (float*)((char*)d_ws + 900096);
    float* pP   = fb;
    float* pF   = pP + 30720;
    float* pA   = pF + 30720;
    float* pB   = pA + 30720;
    float* dbuf = fb;                  // overlay (temporally disjoint)
    float* sig  = fb + 122880;         // 46080
    float* bns  = sig + 46080;         // 48
    float* Q    = (float*)((char*)d_ws + 1576128);

    hipMemsetAsync(bns, 0, 48 * sizeof(float), stream);
    k_prep_w2f<<<242, 256, 0, stream>>>(w2, w2f);
    k_prep_w3f<<<64, 256, 0, stream>>>(w3f);
    k_prep_w1fA<<<1452, 256, 0, stream>>>(w1, w1fA);
    k_q<<<256, 256, 0, stream>>>(x, w1fA, Q);
    k_prefix<<<384, 256, 0, stream>>>(Q);
    k_ln<<<384, 256, 0, stream>>>(Q, b1, lna, lnb);
    k_enc2<<<NWIN, 256, 0, stream>>>(Q, w2f, w3f, b2, fcw, fcb,
                                     pP, pF, pA, pB, oLat, oP, oF, oA, oB);
    k_signal<<<128, 256, 0, stream>>>(pP, pF, pA, pB, sig, oSig);
    k_dec1<<<384, 256, 0, stream>>>(sig, dw1, db1, dbuf, bns);
    k_dec2<<<16 * INCH, 256, 0, stream>>>(dbuf, bns, gma, bta, dw2, db2, oY, oYp);
}

// Round 13
// 382.647 us; speedup vs baseline: 22.0954x; 1.0957x over previous
//
#include <hip/hip_runtime.h>
#include <math.h>

// ---------------------------------------------------------------------------
// PAE pipeline on MI355X. Round 13:
//   k_enc2: conv2 MFMA split into 4 independent chains (even/odd taps x two
//           i-tiles) -> covers MFMA latency (was 2 chains, MfmaUtil 23%).
//   k_prefix_ln: fused prefix+LN. Prefix batches 4 loads (MLP), final P is
//           R[121] (register->LDS, no re-read), LN pass-1 reads L2-hot rows,
//           v cached bf16 in LDS so pass-2 has zero global reads.
//   k_prep_all: 3 prep kernels fused.
//   k_q / k_signal / k_dec1 / k_dec2 identical to round 12 (verified).
// ---------------------------------------------------------------------------

#define INCH   72
#define TLEN   121
#define FULL   240
#define INTER  24
#define EMB    8
#define LP     360
#define NWIN   3840

typedef __attribute__((ext_vector_type(8)))  short s16x8;
typedef __attribute__((ext_vector_type(4)))  float f32x4;

__device__ __forceinline__ unsigned short f2bf(float f) {
    unsigned u = __float_as_uint(f);
    unsigned r = ((u >> 16) & 1u) + 0x7FFFu;
    return (unsigned short)((u + r) >> 16);
}
__device__ __forceinline__ float bf2f(unsigned short u) {
    return __uint_as_float((unsigned)u << 16);
}

// ---------------------------------------------------------------------------
// k_prep_all: w2f | w3f | w1fA in one launch.
// ---------------------------------------------------------------------------
__global__ __launch_bounds__(256) void k_prep_all(
    const float* __restrict__ w2, const float* __restrict__ w1,
    short* __restrict__ w2f, short* __restrict__ w3f, short* __restrict__ w1fA)
{
    int gid = blockIdx.x * 256 + threadIdx.x;
    if (gid < 61952) {                                   // w2f
        int idx = gid;
        int j = idx & 7, ln = (idx >> 3) & 63, tap = idx >> 9;
        int e = ln & 15, c = (ln >> 4) * 8 + j;
        float v = (e < EMB && c < INTER) ? w2[(e * INTER + c) * TLEN + tap] : 0.0f;
        w2f[idx] = (short)f2bf(v);
    } else if (gid < 78336) {                            // w3f
        int idx = gid - 61952;
        int j = idx & 7, ln = (idx >> 3) & 63, tl = (idx >> 9) & 7, ch = idx >> 12;
        int t = (ln >> 4) * 8 + j + ch * 32;
        int colIdx = (tl & 3) * 16 + (ln & 15);
        int k = colIdx + 1;
        float v = 0.0f;
        if (t < TLEN && colIdx < 60) {
            int mm = (k * t) % 121;
            float s, c;
            sincosf(6.2831853071795864f * (float)mm / 121.0f, &s, &c);
            v = (tl < 4) ? c : -s;
        }
        w3f[idx] = (short)f2bf(v);
    } else if (gid < 450048) {                           // w1fA
        int idx = gid - 78336;
        int j = idx & 7, ln = (idx >> 3) & 63;
        int rest = idx >> 9;
        int ch = rest % 3;
        int rest2 = rest / 3;
        int ot = rest2 & 1, tap = rest2 >> 1;
        int o = ot * 16 + (ln & 15);
        int c = (ln >> 4) * 8 + j + ch * 32;
        float v = (o < INTER && c < INCH) ? w1[(o * INCH + c) * TLEN + tap] : 0.0f;
        w1fA[idx] = (short)f2bf(v);
    }
}

// ---------------------------------------------------------------------------
// k_q: Q[b][o][m][s] = sum_c w1[o,c,m] * x[b,c,(s+m)%240] via MFMA.
// (verified round 11)
// ---------------------------------------------------------------------------
__global__ __launch_bounds__(256) void k_q(
    const float* __restrict__ x, const short* __restrict__ w1fA,
    float* __restrict__ Q)
{
    const int blk = blockIdx.x;
    const int mg = blk & 7, sh = (blk >> 3) & 1, b = blk >> 4;
    const int tid = threadIdx.x;
    const int lane = tid & 63, wid = tid >> 6;
    const int s0 = sh * 120;
    __shared__ __align__(16) short xTb[248 * 104];   // 51584 B

    for (int idx = tid; idx < (248 * 104) / 8; idx += 256)
        ((uint4*)xTb)[idx] = make_uint4(0, 0, 0, 0);
    __syncthreads();
    for (int idx = tid; idx < 72 * 248; idx += 256) {
        int c = idx / 248, l = idx - c * 248;
        int g = s0 + l; g -= (g >= FULL) ? FULL : 0;
        xTb[l * 104 + c] = (short)f2bf(x[(b * INCH + c) * FULL + g]);
    }
    __syncthreads();

    const int ntaps = (mg < 7) ? 16 : 9;
    const int col = lane & 15, quad = lane >> 4;
    for (int j = 0; j < ntaps; ++j) {
        const int m = mg * 16 + j;
        s16x8 a[2][3];
#pragma unroll
        for (int ot = 0; ot < 2; ++ot)
#pragma unroll
            for (int ch = 0; ch < 3; ++ch)
                a[ot][ch] = *(const s16x8*)(w1fA + (((m * 2 + ot) * 3 + ch) * 64 + lane) * 8);
#pragma unroll
        for (int tt = 0; tt < 2; ++tt) {
            const int ts = (wid + tt * 4) * 16;          // s-tile base
            const short* brow = xTb + (ts + col + m) * 104 + quad * 8;
            s16x8 b0 = *(const s16x8*)(brow);
            s16x8 b1 = *(const s16x8*)(brow + 32);
            s16x8 b2 = *(const s16x8*)(brow + 64);
            const int sl = ts + col;
#pragma unroll
            for (int ot = 0; ot < 2; ++ot) {
                f32x4 acc = {0.0f, 0.0f, 0.0f, 0.0f};
                acc = __builtin_amdgcn_mfma_f32_16x16x32_bf16(a[ot][0], b0, acc, 0, 0, 0);
                acc = __builtin_amdgcn_mfma_f32_16x16x32_bf16(a[ot][1], b1, acc, 0, 0, 0);
                acc = __builtin_amdgcn_mfma_f32_16x16x32_bf16(a[ot][2], b2, acc, 0, 0, 0);
                if (sl < 120) {
#pragma unroll
                    for (int r = 0; r < 4; ++r) {
                        int o = ot * 16 + quad * 4 + r;
                        if (o < INTER)
                            Q[((size_t)(b * INTER + o) * TLEN + m) * FULL + s0 + sl] = acc[r];
                    }
                }
            }
        }
    }
}

// ---------------------------------------------------------------------------
// k_prefix_ln: fused prefix + conv1-diff + LN + tanh -> bf16 h3 overlay.
// Prefix: thread s walks taps with 4-batched loads; final P == R[121][s]
// stored to LDS from register. LN pass-1 reads rows 0..119 (L2-hot, just
// written by this block), caches v as bf16 in hls; pass-2 reads only LDS.
// ---------------------------------------------------------------------------
__global__ __launch_bounds__(256) void k_prefix_ln(
    float* __restrict__ Q, const float* __restrict__ b1,
    const float* __restrict__ lna, const float* __restrict__ lnb)
{
    const int blk = blockIdx.x;          // b*24 + o
    const int o = blk % INTER;
    const int tid = threadIdx.x;
    __shared__ float r121[FULL];                              // 960 B
    __shared__ __align__(16) unsigned short hls[FULL * TLEN]; // 58080 B
    float* Rg = Q + (size_t)blk * (TLEN * FULL);

    // --- prefix phase: in-place inclusive prefix over taps, col = tid ---
    if (tid < FULL) {
        float* Qc = Rg + tid;
        float P = 0.0f;
        for (int m = 0; m < 120; m += 4) {
            float q0 = Qc[m * FULL];
            float q1 = Qc[(m + 1) * FULL];
            float q2 = Qc[(m + 2) * FULL];
            float q3 = Qc[(m + 3) * FULL];
            P += q0; Qc[m * FULL]       = P;
            P += q1; Qc[(m + 1) * FULL] = P;
            P += q2; Qc[(m + 2) * FULL] = P;
            P += q3; Qc[(m + 3) * FULL] = P;
        }
        P += Qc[120 * FULL];
        Qc[120 * FULL] = P;              // row 120 = R[121]
        r121[tid] = P;                   // register -> LDS, no re-read
    }
    __syncthreads();

    if (tid < FULL) {
        const int n = tid;
        const float bias = b1[o];
        unsigned short* hrow = hls + n * TLEN;
        float s = 0.0f, s2 = 0.0f;
        // pass 1: compute v, cache bf16(v), accumulate stats (fp32 v)
        for (int i = 0; i < 60; ++i) {                   // lo = 60-i >= 1
            int st = n + i - 120; st += (st < 0) ? FULL : 0;
            float v = r121[st] - Rg[(59 - i) * FULL + st] + bias;
            s += v; s2 += v * v;
            hrow[i] = f2bf(v);
        }
        {                                                // i = 60: lo = 0
            int st = n - 60; st += (st < 0) ? FULL : 0;
            float v = r121[st] + bias;
            s += v; s2 += v * v;
            hrow[60] = f2bf(v);
        }
        for (int i = 61; i < TLEN; ++i) {                // up = 181-i, lo = 0
            int st = n + i - 120; st += (st < 0) ? FULL : 0;
            float v = Rg[(180 - i) * FULL + st] + bias;
            s += v; s2 += v * v;
            hrow[i] = f2bf(v);
        }
        float mean = s * (1.0f / 121.0f);
        float var  = fmaxf((s2 - s * mean) * (1.0f / 120.0f), 0.0f);   // ddof=1
        float inv  = 1.0f / (sqrtf(var) + 1e-5f);                      // (std+eps)
        // pass 2: LDS-only transform + tanh
        for (int i = 0; i < TLEN; ++i) {
            float v = bf2f(hrow[i]);
            v = (v - mean) * inv * lna[i] + lnb[i];
            hrow[i] = f2bf(tanhf(v));
        }
    }
    __syncthreads();
    // dump h3 (58080 B = 3630 uint4) over the dead R tile, coalesced
    uint4* dst = (uint4*)Rg;
    const uint4* src = (const uint4*)hls;
    for (int idx = tid; idx < 3630; idx += 256) dst[idx] = src[idx];
}

// ---------------------------------------------------------------------------
// k_enc2: per-window conv2 MFMA (ring-buffered A, 4 chains) + DFT-MFMA + fc/b.
// ---------------------------------------------------------------------------
__global__ __launch_bounds__(256) void k_enc2(
    const float* __restrict__ Q, const short* __restrict__ w2f,
    const short* __restrict__ w3f, const float* __restrict__ b2,
    const float* __restrict__ fcw, const float* __restrict__ fcb,
    float* __restrict__ pP, float* __restrict__ pF, float* __restrict__ pA, float* __restrict__ pB,
    float* __restrict__ oLat, float* __restrict__ oP, float* __restrict__ oF,
    float* __restrict__ oA, float* __restrict__ oB)
{
    const int w   = blockIdx.x;
    const int b   = w / FULL, n = w - b * FULL;
    const int tid = threadIdx.x;
    const int lane = tid & 63, wid = tid >> 6;

    __shared__ __align__(16) short hT[248 * 40];     // 19840 B, stride 40
    __shared__ __align__(16) short hs[24 * 132];     // 6336 B
    __shared__ __align__(16) short latb[16 * 136];   // 4352 B
    __shared__ float lat[EMB * 122];                 // 3904 B
    __shared__ float S0[8], S1[8], vv[16], bm[8];

    for (int idx = tid; idx < 1240; idx += 256) ((uint4*)hT)[idx] = make_uint4(0,0,0,0);
    for (int idx = tid; idx < 272;  idx += 256) ((uint4*)latb)[idx] = make_uint4(0,0,0,0);
    if (tid < 8) { S0[tid] = 0.0f; S1[tid] = 0.0f; }

    for (int idx = tid; idx < INTER * TLEN; idx += 256) {
        int o = idx / TLEN, i = idx - o * TLEN;
        const unsigned short* h3 =
            (const unsigned short*)(Q + (size_t)(b * INTER + o) * (TLEN * FULL)) + n * TLEN;
        hs[o * 132 + i] = (short)h3[i];
    }
    __syncthreads();
    for (int idx = tid; idx < TLEN * 32; idx += 256) {
        int i = idx >> 5, o = idx & 31;
        short v = (o < INTER) ? hs[o * 132 + i] : (short)0;
        hT[(60 + i) * 40 + o] = v;
    }
    __syncthreads();

    const int m = lane & 15, quad = lane >> 4;
    const int t0 = wid * 32;

    // --- conv2 MFMA: 4 independent chains (even/odd taps x two i-tiles) ---
    f32x4 acc0a = {0,0,0,0}, acc0b = {0,0,0,0};
    f32x4 acc1a = {0,0,0,0}, acc1b = {0,0,0,0};
    const short* aptr = hT + (t0 + m) * 40 + quad * 8;
    s16x8 ring[16];
#pragma unroll
    for (int j = 0; j < 16; ++j) ring[j] = *(const s16x8*)(aptr + j * 40);

    for (int t16 = 0; t16 < 7; ++t16) {          // taps 0..111
#pragma unroll
        for (int j = 0; j < 16; j += 2) {
            const int tap = t16 * 16 + j;
            s16x8 bw0 = *(const s16x8*)(w2f + tap * 512 + lane * 8);
            s16x8 bw1 = *(const s16x8*)(w2f + (tap + 1) * 512 + lane * 8);
            s16x8 nw0 = *(const s16x8*)(aptr + (tap + 16) * 40);
            s16x8 nw1 = *(const s16x8*)(aptr + (tap + 17) * 40);
            acc0a = __builtin_amdgcn_mfma_f32_16x16x32_bf16(ring[j],     bw0, acc0a, 0, 0, 0);
            acc0b = __builtin_amdgcn_mfma_f32_16x16x32_bf16(ring[j + 1], bw1, acc0b, 0, 0, 0);
            acc1a = __builtin_amdgcn_mfma_f32_16x16x32_bf16(nw0,         bw0, acc1a, 0, 0, 0);
            acc1b = __builtin_amdgcn_mfma_f32_16x16x32_bf16(nw1,         bw1, acc1b, 0, 0, 0);
            ring[j] = nw0; ring[j + 1] = nw1;
        }
    }
#pragma unroll
    for (int j = 0; j < 8; j += 2) {             // taps 112..119
        const int tap = 112 + j;
        s16x8 bw0 = *(const s16x8*)(w2f + tap * 512 + lane * 8);
        s16x8 bw1 = *(const s16x8*)(w2f + (tap + 1) * 512 + lane * 8);
        s16x8 nw0 = *(const s16x8*)(aptr + (tap + 16) * 40);
        s16x8 nw1 = *(const s16x8*)(aptr + (tap + 17) * 40);
        acc0a = __builtin_amdgcn_mfma_f32_16x16x32_bf16(ring[j],     bw0, acc0a, 0, 0, 0);
        acc0b = __builtin_amdgcn_mfma_f32_16x16x32_bf16(ring[j + 1], bw1, acc0b, 0, 0, 0);
        acc1a = __builtin_amdgcn_mfma_f32_16x16x32_bf16(nw0,         bw0, acc1a, 0, 0, 0);
        acc1b = __builtin_amdgcn_mfma_f32_16x16x32_bf16(nw1,         bw1, acc1b, 0, 0, 0);
    }
    {                                            // tap 120
        s16x8 bw = *(const s16x8*)(w2f + 120 * 512 + lane * 8);
        s16x8 nw = *(const s16x8*)(aptr + 136 * 40);
        acc0a = __builtin_amdgcn_mfma_f32_16x16x32_bf16(ring[8], bw, acc0a, 0, 0, 0);
        acc1a = __builtin_amdgcn_mfma_f32_16x16x32_bf16(nw,      bw, acc1a, 0, 0, 0);
    }
    f32x4 acc0, acc1;
#pragma unroll
    for (int r = 0; r < 4; ++r) { acc0[r] = acc0a[r] + acc0b[r]; acc1[r] = acc1a[r] + acc1b[r]; }

    {
        const int e = lane & 15;
        if (e < EMB) {
            float bias = b2[e];
#pragma unroll
            for (int r = 0; r < 4; ++r) {
                int i0v = t0 + quad * 4 + r;
                if (i0v < TLEN) {
                    float v = acc0[r] + bias;
                    lat[e * 122 + i0v] = v;
                    latb[e * 136 + i0v] = (short)f2bf(v);
                }
                int i1v = t0 + 16 + quad * 4 + r;
                if (i1v < TLEN) {
                    float v = acc1[r] + bias;
                    lat[e * 122 + i1v] = v;
                    latb[e * 136 + i1v] = (short)f2bf(v);
                }
            }
        }
    }
    __syncthreads();

    // --- DFT via MFMA ---
    {
        f32x4 accR = {0,0,0,0};
        f32x4 accI = {0,0,0,0};
#pragma unroll
        for (int ch = 0; ch < 4; ++ch) {
            s16x8 a  = *(const s16x8*)(latb + (lane & 15) * 136 + quad * 8 + ch * 32);
            s16x8 br = *(const s16x8*)(w3f + (((ch * 8) + wid) * 64 + lane) * 8);
            s16x8 bi = *(const s16x8*)(w3f + (((ch * 8) + 4 + wid) * 64 + lane) * 8);
            accR = __builtin_amdgcn_mfma_f32_16x16x32_bf16(a, br, accR, 0, 0, 0);
            accI = __builtin_amdgcn_mfma_f32_16x16x32_bf16(a, bi, accI, 0, 0, 0);
        }
        const int colj = lane & 15;
        const int col  = wid * 16 + colj;
        const float fw = 0.5f * (float)(col + 1);
#pragma unroll
        for (int r = 0; r < 4; ++r) {
            float pw = (col < 60) ? (accR[r] * accR[r] + accI[r] * accI[r]) : 0.0f;
            float s1 = pw * fw;
#pragma unroll
            for (int off = 1; off < 16; off <<= 1) {
                pw += __shfl_xor(pw, off);
                s1 += __shfl_xor(s1, off);
            }
            if (colj == 0) {
                int e = quad * 4 + r;
                if (e < EMB) { atomicAdd(&S0[e], pw); atomicAdd(&S1[e], s1); }
            }
        }
    }
    // --- fc ---
    if (tid < 16) {
        int e_ = tid >> 1, kk = tid & 1;
        float accv = fcb[e_ * 2 + kk];
        const float* fr = fcw + (e_ * 2 + kk) * TLEN;
        for (int t = 0; t < TLEN; ++t) accv += lat[e_ * 122 + t] * fr[t];
        vv[tid] = accv;
    }
    if (tid >= 32 && tid < 40) {
        int e_ = tid - 32;
        float s = 0.0f;
        for (int t = 0; t < TLEN; ++t) s += lat[e_ * 122 + t];
        bm[e_] = s * (1.0f / 121.0f);
    }
    __syncthreads();

    if (tid < 8) {
        int e_ = tid;
        float fv = S1[e_] / S0[e_];
        float av = 2.0f * sqrtf(S0[e_]) * (1.0f / 121.0f);
        float pv = atan2f(vv[2 * e_ + 1], vv[2 * e_]) * 0.15915494309189535f;
        float bv = bm[e_];
        int gi = w * 8 + e_;
        pP[gi] = pv; pF[gi] = fv; pA[gi] = av; pB[gi] = bv;
        if (n == 0) {
            oP[b * 8 + e_] = pv;
            oF[b * 8 + e_] = fv;
            oA[b * 8 + e_] = av;
            oB[b * 8 + e_] = bv;
        }
    }
    if (n == 0) {
        for (int idx = tid; idx < EMB * TLEN; idx += 256) {
            int e_ = idx / TLEN, i = idx - e_ * TLEN;
            oLat[(b * EMB + e_) * TLEN + i] = lat[e_ * 122 + i];
        }
    }
}

// ---------------------------------------------------------------------------
// k_signal: sinusoid resynthesis + overlap-add, gather form.
// ---------------------------------------------------------------------------
__global__ __launch_bounds__(256) void k_signal(
    const float* __restrict__ pP, const float* __restrict__ pF,
    const float* __restrict__ pA, const float* __restrict__ pB,
    float* __restrict__ sig, float* __restrict__ oSig)
{
    const int blk = blockIdx.x;
    const int b = blk >> 3, e = blk & 7;
    const int tid = threadIdx.x;
    __shared__ float sp[FULL], sf[FULL], sa[FULL], sb[FULL];
    for (int nn = tid; nn < FULL; nn += 256) {
        int gi = (b * FULL + nn) * 8 + e;
        sp[nn] = pP[gi]; sf[nn] = pF[gi]; sa[nn] = pA[gi]; sb[nn] = pB[gi];
    }
    __syncthreads();
    for (int u = tid; u < LP; u += 256) {
        int nlo = (u - 120 > 0) ? (u - 120) : 0;
        int nhi = (u < 239) ? u : 239;
        float s = 0.0f;
        for (int nn = nlo; nn <= nhi; ++nn) {
            float tt = (float)(u - nn);
            float z = sf[nn] * (tt * (1.0f / 60.0f) - 1.0f) + sp[nn];
            z -= floorf(z);
            s += sa[nn] * sinf(6.2831853071795864f * z) + sb[nn];
        }
        float wgt = (u < TLEN) ? (float)(u + 1) : ((u > 239) ? (float)(LP - u) : 121.0f);
        float val = s / wgt;
        sig[(b * EMB + e) * LP + u] = val;
        if (u < TLEN) oSig[(b * EMB + e) * TLEN + u] = val;
    }
}

// ---------------------------------------------------------------------------
// k_dec1: decoder conv1. Block = (b,o), 384 x 256 thr; 4 waves x 2 channels,
// LDS partial-sum reduce; weights via block-uniform global reads.
// ---------------------------------------------------------------------------
__global__ __launch_bounds__(256) void k_dec1(
    const float* __restrict__ sig, const float* __restrict__ dw1, const float* __restrict__ db1,
    float* __restrict__ dbuf, float* __restrict__ bns)
{
    const int blk = blockIdx.x;            // b*24 + o
    const int b = blk / INTER, o = blk - b * INTER;
    const int tid = threadIdx.x;
    const int lane = tid & 63, wid = tid >> 6;
    __shared__ __align__(16) float ycp[EMB * 364];   // 11648 B
    __shared__ __align__(16) float part[4][240];     // 3840 B
    for (int idx = tid; idx < EMB * 364; idx += 256) {
        int c = idx / 364, q = idx - c * 364;
        float v = 0.0f;
        if (q >= 60 && q < 300) v = sig[(b * EMB + c) * LP + q];
        ycp[idx] = v;
    }
    __syncthreads();
    const int te = (lane < 60) ? lane : 59;
    float a0 = 0.0f, a1 = 0.0f, a2 = 0.0f, a3 = 0.0f;
    for (int cl = 0; cl < 2; ++cl) {
        const int c = wid * 2 + cl;
        const float* wr = dw1 + (o * EMB + c) * TLEN;
        const float* base = ycp + c * 364 + 4 * te;
        float4 cur = *(const float4*)base;
        for (int kb = 0; kb < 30; ++kb) {
            float4 nxt = *(const float4*)(base + 4 * kb + 4);
            float w0 = wr[4*kb], w1 = wr[4*kb+1], w2 = wr[4*kb+2], w3 = wr[4*kb+3];
            a0 += w0*cur.x; a1 += w0*cur.y; a2 += w0*cur.z; a3 += w0*cur.w;
            a0 += w1*cur.y; a1 += w1*cur.z; a2 += w1*cur.w; a3 += w1*nxt.x;
            a0 += w2*cur.z; a1 += w2*cur.w; a2 += w2*nxt.x; a3 += w2*nxt.y;
            a0 += w3*cur.w; a1 += w3*nxt.x; a2 += w3*nxt.y; a3 += w3*nxt.z;
            cur = nxt;
        }
        float wl = wr[120];
        a0 += wl*cur.x; a1 += wl*cur.y; a2 += wl*cur.z; a3 += wl*cur.w;
    }
    if (lane < 60) {
        float4* dst = (float4*)&part[wid][4 * lane];
        *dst = make_float4(a0, a1, a2, a3);
    }
    __syncthreads();
    float s = 0.0f, s2 = 0.0f;
    if (tid < 60) {
        const float bias = db1[o];
        float4 f;
        f.x = part[0][4*tid+0] + part[1][4*tid+0] + part[2][4*tid+0] + part[3][4*tid+0] + bias;
        f.y = part[0][4*tid+1] + part[1][4*tid+1] + part[2][4*tid+1] + part[3][4*tid+1] + bias;
        f.z = part[0][4*tid+2] + part[1][4*tid+2] + part[2][4*tid+2] + part[3][4*tid+2] + bias;
        f.w = part[0][4*tid+3] + part[1][4*tid+3] + part[2][4*tid+3] + part[3][4*tid+3] + bias;
        *(float4*)(dbuf + (b * INTER + o) * FULL + 4 * tid) = f;
        s  = f.x + f.y + f.z + f.w;
        s2 = f.x*f.x + f.y*f.y + f.z*f.z + f.w*f.w;
    }
    if (wid == 0) {
        for (int d = 32; d > 0; d >>= 1) { s += __shfl_down(s, d); s2 += __shfl_down(s2, d); }
        if (tid == 0) { atomicAdd(&bns[o], s); atomicAdd(&bns[24 + o], s2); }
    }
}

// ---------------------------------------------------------------------------
// k_dec2: decoder conv2 with fused BN+tanh staging. Block = (b,oc),
// 1152 x 256 thr; 4 waves x 6 channels, LDS partial-sum reduce.
// ---------------------------------------------------------------------------
__global__ __launch_bounds__(256) void k_dec2(
    const float* __restrict__ dbuf, const float* __restrict__ bns,
    const float* __restrict__ gma, const float* __restrict__ bta,
    const float* __restrict__ dw2, const float* __restrict__ db2,
    float* __restrict__ oY, float* __restrict__ oYp)
{
    const int blk = blockIdx.x;            // b*72 + oc
    const int b = blk / INCH, oc = blk - b * INCH;
    const int tid = threadIdx.x;
    const int lane = tid & 63, wid = tid >> 6;
    __shared__ __align__(16) float sdp[INTER * 364]; // 34944 B
    __shared__ __align__(16) float part[4][240];     // 3840 B
    __shared__ float scl[INTER], sft[INTER];
    if (tid < INTER) {
        float m  = bns[tid] * (1.0f / 3840.0f);
        float v  = bns[24 + tid] * (1.0f / 3840.0f) - m * m;
        float rs = rsqrtf(fmaxf(v, 0.0f) + 1e-5f);
        float g  = gma[tid];
        scl[tid] = rs * g;
        sft[tid] = bta[tid] - m * rs * g;
    }
    __syncthreads();
    for (int idx = tid; idx < INTER * 364; idx += 256) {
        int c = idx / 364, q = idx - c * 364;
        float v = 0.0f;
        if (q >= 60 && q < 300)
            v = tanhf(dbuf[(b * INTER + c) * FULL + (q - 60)] * scl[c] + sft[c]);
        sdp[idx] = v;
    }
    __syncthreads();
    const int te = (lane < 60) ? lane : 59;
    float a0 = 0.0f, a1 = 0.0f, a2 = 0.0f, a3 = 0.0f;
    for (int cl = 0; cl < 6; ++cl) {
        const int c = wid * 6 + cl;
        const float* wr = dw2 + (oc * INTER + c) * TLEN;
        const float* base = sdp + c * 364 + 4 * te;
        float4 cur = *(const float4*)base;
        for (int kb = 0; kb < 30; ++kb) {
            float4 nxt = *(const float4*)(base + 4 * kb + 4);
            float w0 = wr[4*kb], w1 = wr[4*kb+1], w2 = wr[4*kb+2], w3 = wr[4*kb+3];
            a0 += w0*cur.x; a1 += w0*cur.y; a2 += w0*cur.z; a3 += w0*cur.w;
            a0 += w1*cur.y; a1 += w1*cur.z; a2 += w1*cur.w; a3 += w1*nxt.x;
            a0 += w2*cur.z; a1 += w2*cur.w; a2 += w2*nxt.x; a3 += w2*nxt.y;
            a0 += w3*cur.w; a1 += w3*nxt.x; a2 += w3*nxt.y; a3 += w3*nxt.z;
            cur = nxt;
        }
        float wl = wr[120];
        a0 += wl*cur.x; a1 += wl*cur.y; a2 += wl*cur.z; a3 += wl*cur.w;
    }
    if (lane < 60) {
        float4* dst = (float4*)&part[wid][4 * lane];
        *dst = make_float4(a0, a1, a2, a3);
    }
    __syncthreads();
    if (tid < 60) {
        const float bias = db2[oc];
        float4 f;
        f.x = part[0][4*tid+0] + part[1][4*tid+0] + part[2][4*tid+0] + part[3][4*tid+0] + bias;
        f.y = part[0][4*tid+1] + part[1][4*tid+1] + part[2][4*tid+1] + part[3][4*tid+1] + bias;
        f.z = part[0][4*tid+2] + part[1][4*tid+2] + part[2][4*tid+2] + part[3][4*tid+2] + bias;
        f.w = part[0][4*tid+3] + part[1][4*tid+3] + part[2][4*tid+3] + part[3][4*tid+3] + bias;
        const int i = 4 * tid;
        *(float4*)(oY + (b * INCH + oc) * FULL + i) = f;
        float* yp = oYp + (b * INCH + oc) * TLEN;
        if (i     < TLEN) yp[i]     = f.x;
        if (i + 1 < TLEN) yp[i + 1] = f.y;
        if (i + 2 < TLEN) yp[i + 2] = f.z;
        if (i + 3 < TLEN) yp[i + 3] = f.w;
    }
}

// ---------------------------------------------------------------------------
extern "C" void kernel_launch(void* const* d_in, const int* in_sizes, int n_in,
                              void* d_out, int out_size, void* d_ws, size_t ws_size,
                              hipStream_t stream)
{
    const float* x   = (const float*)d_in[0];
    const float* w1  = (const float*)d_in[1];
    const float* b1  = (const float*)d_in[2];
    const float* lna = (const float*)d_in[3];
    const float* lnb = (const float*)d_in[4];
    const float* w2  = (const float*)d_in[5];
    const float* b2  = (const float*)d_in[6];
    const float* fcw = (const float*)d_in[7];
    const float* fcb = (const float*)d_in[8];
    const float* dw1 = (const float*)d_in[9];
    const float* db1 = (const float*)d_in[10];
    const float* gma = (const float*)d_in[11];
    const float* bta = (const float*)d_in[12];
    const float* dw2 = (const float*)d_in[13];
    const float* db2 = (const float*)d_in[14];

    // Output layout (flat fp32, reference return order):
    float* out  = (float*)d_out;
    float* oY   = out;                 // [16][72][240]
    float* oLat = out + 276480;        // [16][8][121]
    float* oSig = out + 291968;        // [16][8][121]
    float* oP   = out + 307456;
    float* oF   = out + 307584;
    float* oA   = out + 307712;
    float* oB   = out + 307840;
    float* oYp  = out + 307968;        // [16][72][121]

    // Workspace layout (bytes; ws_size >= 46,436,544 proven in round 6):
    //   [0, 123904)           w2f bf16 fragments [121][64][8]
    //   [123904, 156672)      w3f bf16 DFT fragments
    //   [156672, 900096)      w1fA bf16 A-fragments [121][2][3][64][8]
    //   [900096, 1576128)     fp32: pP/pF/pA/pB (dbuf overlay), sig, bns
    //   [1576128, 46181568)   Q [16][24][121][240] fp32 -> R in-place
    //                         -> h3 bf16 overlay after k_prefix_ln
    short* w2f  = (short*)d_ws;
    short* w3f  = (short*)((char*)d_ws + 123904);
    short* w1fA = (short*)((char*)d_ws + 156672);
    float* fb   = (float*)((char*)d_ws + 900096);
    float* pP   = fb;
    float* pF   = pP + 30720;
    float* pA   = pF + 30720;
    float* pB   = pA + 30720;
    float* dbuf = fb;                  // overlay (temporally disjoint)
    float* sig  = fb + 122880;         // 46080
    float* bns  = sig + 46080;         // 48
    float* Q    = (float*)((char*)d_ws + 1576128);

    hipMemsetAsync(bns, 0, 48 * sizeof(float), stream);
    k_prep_all<<<1758, 256, 0, stream>>>(w2, w1, w2f, w3f, w1fA);
    k_q<<<256, 256, 0, stream>>>(x, w1fA, Q);
    k_prefix_ln<<<384, 256, 0, stream>>>(Q, b1, lna, lnb);
    k_enc2<<<NWIN, 256, 0, stream>>>(Q, w2f, w3f, b2, fcw, fcb,
                                     pP, pF, pA, pB, oLat, oP, oF, oA, oB);
    k_signal<<<128, 256, 0, stream>>>(pP, pF, pA, pB, sig, oSig);
    k_dec1<<<384, 256, 0, stream>>>(sig, dw1, db1, dbuf, bns);
    k_dec2<<<16 * INCH, 256, 0, stream>>>(dbuf, bns, gma, bta, dw2, db2, oY, oYp);
}